// Round 1
// baseline (13577.333 us; speedup 1.0000x reference)
//
#include <hip/hip_runtime.h>
#include <math.h>

#define NN      50000      // N_NODES
#define NE      2400000    // N_EDGES
#define NHOPS   3
#define NG      2048       // NUM_GRAPHS
#define H       128        // HIDDEN
#define EMBD    64
#define NL      3
#define NMLP    2
#define NHEADS  4

__device__ __forceinline__ float silu_f(float v) { return v / (1.0f + expf(-v)); }

// ---------------------------------------------------------------- K0: embed + project + silu
#define NPB0 16
__global__ __launch_bounds__(128) void k_embed(
    const int* __restrict__ atom, const int* __restrict__ hc,
    const int* __restrict__ deg,  const int* __restrict__ hyb,
    const float* __restrict__ Ea, const float* __restrict__ Eh,
    const float* __restrict__ Ed, const float* __restrict__ Ey,
    const float* __restrict__ W,  const float* __restrict__ B,
    float* __restrict__ x)
{
    __shared__ float s[NPB0][4 * EMBD];
    const int base = blockIdx.x * NPB0;
    const int t = threadIdx.x;
    for (int j = 0; j < NPB0; ++j) {
        int node = base + j;
        if (node < NN) {
            int k0 = t, k1 = t + 128;
            float v0 = (k0 < 64) ? Ea[atom[node] * EMBD + k0]
                                 : Eh[hc[node] * EMBD + (k0 - 64)];
            float v1 = (k1 < 192) ? Ed[deg[node] * EMBD + (k1 - 128)]
                                  : Ey[hyb[node] * EMBD + (k1 - 192)];
            s[j][k0] = v0; s[j][k1] = v1;
        } else { s[j][t] = 0.f; s[j][t + 128] = 0.f; }
    }
    __syncthreads();
    float acc[NPB0];
#pragma unroll
    for (int j = 0; j < NPB0; ++j) acc[j] = 0.f;
    const int c = t;
    for (int k = 0; k < 4 * EMBD; ++k) {
        float w = W[k * H + c];
#pragma unroll
        for (int j = 0; j < NPB0; ++j) acc[j] += s[j][k] * w;
    }
    float bb = B[c];
    for (int j = 0; j < NPB0; ++j) {
        int node = base + j;
        if (node < NN) x[(long)node * H + c] = silu_f(acc[j] + bb);
    }
}

// ---------------------------------------------------------------- K1: edge scatter-add (atomics)
__global__ __launch_bounds__(256) void k_scatter(
    const int* __restrict__ target, const int* __restrict__ src,
    const float* __restrict__ x, float* __restrict__ agg)
{
    long tid = (long)blockIdx.x * 256 + threadIdx.x;
    long e = tid >> 5;
    if (e >= NE) return;
    int lane = (int)(tid & 31);
    int c = lane * 4;
    int s = src[e];
    if (s >= 2 * NN) s -= 2 * NN; else if (s >= NN) s -= NN;   // src % N
    int tg = target[e];
    const float4 v = *(const float4*)(x + (long)s * H + c);
    float* a = agg + (long)tg * H + c;
    atomicAdd(a + 0, v.x); atomicAdd(a + 1, v.y);
    atomicAdd(a + 2, v.z); atomicAdd(a + 3, v.w);
}

// ---------------------------------------------------------------- K2: shell_in + skip matmuls (K=512)
#define NPB1 8
__global__ __launch_bounds__(128) void k_shell(
    const float* __restrict__ x, const float* __restrict__ agg,
    const float* __restrict__ Win, const float* __restrict__ Bin,
    const float* __restrict__ Wsk, const float* __restrict__ Bsk,
    float* __restrict__ h, float* __restrict__ gskip)
{
    __shared__ float s[NPB1][4 * H];
    const int base = blockIdx.x * NPB1;
    const int t = threadIdx.x;
    for (int j = 0; j < NPB1; ++j) {
        long node = base + j;
        s[j][t]        = x[node * H + t];
        s[j][128 + t]  = agg[node * H + t];
        s[j][256 + t]  = agg[(NN + node) * H + t];
        s[j][384 + t]  = agg[(2L * NN + node) * H + t];
    }
    __syncthreads();
    float ah[NPB1], as[NPB1];
#pragma unroll
    for (int j = 0; j < NPB1; ++j) { ah[j] = 0.f; as[j] = 0.f; }
    const int c = t;
    for (int k = 0; k < 4 * H; ++k) {
        float wi = Win[k * H + c];
        float ws = Wsk[k * H + c];
#pragma unroll
        for (int j = 0; j < NPB1; ++j) { ah[j] += s[j][k] * wi; as[j] += s[j][k] * ws; }
    }
    float bi = Bin[c], bs = Bsk[c];
    for (int j = 0; j < NPB1; ++j) {
        long idx = (long)(base + j) * H + c;
        h[idx] = silu_f(ah[j] + bi);
        gskip[idx] = as[j] + bs;
    }
}

// ---------------------------------------------------------------- K3: fused residual MLP block
#define NPB2 16
__global__ __launch_bounds__(128) void k_mlp(
    const float* __restrict__ hin,
    const float* __restrict__ W1, const float* __restrict__ B1,
    const float* __restrict__ W2, const float* __restrict__ B2,
    const float* __restrict__ gskip,   // nullable; added when final MLP of layer
    float* __restrict__ hout)
{
    __shared__ float sh[NPB2][H];
    __shared__ float st[NPB2][H];
    const int base = blockIdx.x * NPB2;
    const int c = threadIdx.x;
    for (int j = 0; j < NPB2; ++j) sh[j][c] = hin[(long)(base + j) * H + c];
    __syncthreads();
    float acc[NPB2];
#pragma unroll
    for (int j = 0; j < NPB2; ++j) acc[j] = 0.f;
    for (int k = 0; k < H; ++k) {
        float w = W1[k * H + c];
#pragma unroll
        for (int j = 0; j < NPB2; ++j) acc[j] += sh[j][k] * w;
    }
    float b1 = B1[c];
    for (int j = 0; j < NPB2; ++j) st[j][c] = silu_f(acc[j] + b1);
    __syncthreads();
#pragma unroll
    for (int j = 0; j < NPB2; ++j) acc[j] = 0.f;
    for (int k = 0; k < H; ++k) {
        float w = W2[k * H + c];
#pragma unroll
        for (int j = 0; j < NPB2; ++j) acc[j] += st[j][k] * w;
    }
    float b2 = B2[c];
    for (int j = 0; j < NPB2; ++j) {
        long idx = (long)(base + j) * H + c;
        float v = acc[j] + b2 + sh[j][c];
        if (gskip) v += gskip[idx];
        hout[idx] = v;
    }
}

// ---------------------------------------------------------------- K4: attention scores (wave per node)
__global__ __launch_bounds__(256) void k_scores(
    const float* __restrict__ x, const float* __restrict__ aw,
    const float* __restrict__ ab, const float* __restrict__ temp,
    float* __restrict__ scores)
{
    int wave = threadIdx.x >> 6, lane = threadIdx.x & 63;
    int n = blockIdx.x * 4 + wave;
    if (n >= NN) return;
    float x0 = x[(long)n * H + lane];
    float x1 = x[(long)n * H + 64 + lane];
    float T = temp[0];
#pragma unroll
    for (int hh = 0; hh < NHEADS; ++hh) {
        float p = x0 * aw[hh * H + lane] + x1 * aw[hh * H + 64 + lane];
#pragma unroll
        for (int off = 32; off >= 1; off >>= 1) p += __shfl_xor(p, off, 64);
        if (lane == 0) scores[n * NHEADS + hh] = (p + ab[hh]) / T;
    }
}

// ---------------------------------------------------------------- K5: graph start offsets (batch sorted)
__global__ __launch_bounds__(256) void k_offsets(
    const int* __restrict__ batch, int* __restrict__ gstart)
{
    int n = blockIdx.x * 256 + threadIdx.x;
    if (n >= NN) return;
    int b = batch[n];
    int bp = (n == 0) ? -1 : batch[n - 1];
    for (int g = bp + 1; g <= b; ++g) gstart[g] = n;
    if (n == NN - 1) for (int g = b + 1; g <= NG; ++g) gstart[g] = NN;
}

// ---------------------------------------------------------------- K6: softmax pool (wave per graph)
__global__ __launch_bounds__(64) void k_pool(
    const float* __restrict__ x, const float* __restrict__ scores,
    const int* __restrict__ gstart, float* __restrict__ pooled)
{
    int g = blockIdx.x, lane = threadIdx.x;
    int s0 = gstart[g], s1 = gstart[g + 1];
    float m0 = -INFINITY, m1 = -INFINITY, m2 = -INFINITY, m3 = -INFINITY;
    for (int n = s0 + lane; n < s1; n += 64) {
        m0 = fmaxf(m0, scores[n * 4 + 0]); m1 = fmaxf(m1, scores[n * 4 + 1]);
        m2 = fmaxf(m2, scores[n * 4 + 2]); m3 = fmaxf(m3, scores[n * 4 + 3]);
    }
#pragma unroll
    for (int off = 32; off >= 1; off >>= 1) {
        m0 = fmaxf(m0, __shfl_xor(m0, off, 64)); m1 = fmaxf(m1, __shfl_xor(m1, off, 64));
        m2 = fmaxf(m2, __shfl_xor(m2, off, 64)); m3 = fmaxf(m3, __shfl_xor(m3, off, 64));
    }
    float d0 = 0.f, d1 = 0.f, d2 = 0.f, d3 = 0.f;
    for (int n = s0 + lane; n < s1; n += 64) {
        d0 += expf(scores[n * 4 + 0] - m0); d1 += expf(scores[n * 4 + 1] - m1);
        d2 += expf(scores[n * 4 + 2] - m2); d3 += expf(scores[n * 4 + 3] - m3);
    }
#pragma unroll
    for (int off = 32; off >= 1; off >>= 1) {
        d0 += __shfl_xor(d0, off, 64); d1 += __shfl_xor(d1, off, 64);
        d2 += __shfl_xor(d2, off, 64); d3 += __shfl_xor(d3, off, 64);
    }
    float i0 = d0 > 0.f ? 1.f / d0 : 0.f;
    float i1 = d1 > 0.f ? 1.f / d1 : 0.f;
    float i2 = d2 > 0.f ? 1.f / d2 : 0.f;
    float i3 = d3 > 0.f ? 1.f / d3 : 0.f;
    float a0 = 0.f, a1 = 0.f;
    for (int n = s0; n < s1; ++n) {
        // mean over heads commutes with the weighted sum
        float wb = expf(scores[n * 4 + 0] - m0) * i0 + expf(scores[n * 4 + 1] - m1) * i1
                 + expf(scores[n * 4 + 2] - m2) * i2 + expf(scores[n * 4 + 3] - m3) * i3;
        wb *= 0.25f;
        a0 += wb * x[(long)n * H + lane];
        a1 += wb * x[(long)n * H + 64 + lane];
    }
    pooled[g * H + lane] = a0;
    pooled[g * H + 64 + lane] = a1;
}

// ---------------------------------------------------------------- K7: FFN readout (block per graph)
__global__ __launch_bounds__(128) void k_ffn(
    const float* __restrict__ pooled,
    const float* __restrict__ W1, const float* __restrict__ B1,
    const float* __restrict__ W2, const float* __restrict__ B2,
    const float* __restrict__ W3, const float* __restrict__ B3,
    float* __restrict__ out)
{
    __shared__ float p[H], t1[H], t2[H], red[H];
    int g = blockIdx.x, c = threadIdx.x;
    p[c] = pooled[g * H + c];
    __syncthreads();
    float acc = 0.f;
    for (int k = 0; k < H; ++k) acc += p[k] * W1[k * H + c];
    t1[c] = silu_f(acc + B1[c]);
    __syncthreads();
    acc = 0.f;
    for (int k = 0; k < H; ++k) acc += t1[k] * W2[k * H + c];
    t2[c] = silu_f(acc + B2[c]);
    __syncthreads();
    red[c] = t2[c] * W3[c];
    __syncthreads();
    for (int off = 64; off >= 1; off >>= 1) {
        if (c < off) red[c] += red[c + off];
        __syncthreads();
    }
    if (c == 0) out[g] = red[0] + B3[0];
}

// ---------------------------------------------------------------- launch
extern "C" void kernel_launch(void* const* d_in, const int* in_sizes, int n_in,
                              void* d_out, int out_size, void* d_ws, size_t ws_size,
                              hipStream_t stream)
{
    const int*   atom   = (const int*)d_in[0];
    const int*   hc     = (const int*)d_in[1];
    const int*   deg    = (const int*)d_in[2];
    const int*   hyb    = (const int*)d_in[3];
    const int*   target = (const int*)d_in[4];
    const int*   src    = (const int*)d_in[5];
    const int*   batch  = (const int*)d_in[6];
    const float* Ea     = (const float*)d_in[7];
    const float* Eh     = (const float*)d_in[8];
    const float* Ed     = (const float*)d_in[9];
    const float* Ey     = (const float*)d_in[10];
    const float* projW  = (const float*)d_in[11];
    const float* projB  = (const float*)d_in[12];
    const float* sInW   = (const float*)d_in[13];
    const float* sInB   = (const float*)d_in[14];
    const float* mW1    = (const float*)d_in[15];
    const float* mB1    = (const float*)d_in[16];
    const float* mW2    = (const float*)d_in[17];
    const float* mB2    = (const float*)d_in[18];
    const float* sSkW   = (const float*)d_in[19];
    const float* sSkB   = (const float*)d_in[20];
    const float* attnW  = (const float*)d_in[21];
    const float* attnB  = (const float*)d_in[22];
    const float* temp   = (const float*)d_in[23];
    const float* fW1    = (const float*)d_in[24];
    const float* fB1    = (const float*)d_in[25];
    const float* fW2    = (const float*)d_in[26];
    const float* fB2    = (const float*)d_in[27];
    const float* fW3    = (const float*)d_in[28];
    const float* fB3    = (const float*)d_in[29];
    float* out = (float*)d_out;

    // workspace carve (~156 MB)
    char* w = (char*)d_ws;
    float* x      = (float*)w; w += sizeof(float) * (long)NN * H;
    float* agg    = (float*)w; w += sizeof(float) * 3L * NN * H;
    float* hbuf   = (float*)w; w += sizeof(float) * (long)NN * H;
    float* gskip  = (float*)w; w += sizeof(float) * (long)NN * H;
    float* scores = (float*)w; w += sizeof(float) * (long)NN * NHEADS;
    float* pooled = (float*)w; w += sizeof(float) * (long)NG * H;
    int*   gstart = (int*)w;   w += sizeof(int) * (NG + 1);

    k_embed<<<NN / NPB0, 128, 0, stream>>>(atom, hc, deg, hyb, Ea, Eh, Ed, Ey, projW, projB, x);
    k_offsets<<<(NN + 255) / 256, 256, 0, stream>>>(batch, gstart);

    for (int l = 0; l < NL; ++l) {
        hipMemsetAsync(agg, 0, sizeof(float) * 3L * NN * H, stream);
        long nthr = (long)NE * 32;
        k_scatter<<<(unsigned)((nthr + 255) / 256), 256, 0, stream>>>(target, src, x, agg);
        k_shell<<<NN / NPB1, 128, 0, stream>>>(x, agg,
            sInW + (long)l * 4 * H * H, sInB + l * H,
            sSkW + (long)l * 4 * H * H, sSkB + l * H, hbuf, gskip);
        // MLP m=0: in-place on hbuf
        k_mlp<<<NN / NPB2, 128, 0, stream>>>(hbuf,
            mW1 + (long)(l * NMLP + 0) * H * H, mB1 + (long)(l * NMLP + 0) * H,
            mW2 + (long)(l * NMLP + 0) * H * H, mB2 + (long)(l * NMLP + 0) * H,
            nullptr, hbuf);
        // MLP m=1: add gskip, write new x
        k_mlp<<<NN / NPB2, 128, 0, stream>>>(hbuf,
            mW1 + (long)(l * NMLP + 1) * H * H, mB1 + (long)(l * NMLP + 1) * H,
            mW2 + (long)(l * NMLP + 1) * H * H, mB2 + (long)(l * NMLP + 1) * H,
            gskip, x);
    }

    k_scores<<<NN / 4, 256, 0, stream>>>(x, attnW, attnB, temp, scores);
    k_pool<<<NG, 64, 0, stream>>>(x, scores, gstart, pooled);
    k_ffn<<<NG, 128, 0, stream>>>(pooled, fW1, fB1, fW2, fB2, fW3, fB3, out);
}

// Round 2
// 2214.862 us; speedup vs baseline: 6.1301x; 6.1301x over previous
//
#include <hip/hip_runtime.h>
#include <math.h>

#define NN      50000      // N_NODES
#define NE      2400000    // N_EDGES
#define NHOPS   3
#define NG      2048       // NUM_GRAPHS
#define H       128        // HIDDEN
#define EMBD    64
#define NL      3
#define NMLP    2
#define NHEADS  4
#define NROWS   (NHOPS * NN)          // 150000 aggregation rows
#define SCAN_B  256
#define NB1     ((NROWS + SCAN_B - 1) / SCAN_B)   // 586 level-1 scan blocks

__device__ __forceinline__ float silu_f(float v) { return v / (1.0f + expf(-v)); }

// ---------------------------------------------------------------- K0: embed + project + silu
#define NPB0 16
__global__ __launch_bounds__(128) void k_embed(
    const int* __restrict__ atom, const int* __restrict__ hc,
    const int* __restrict__ deg,  const int* __restrict__ hyb,
    const float* __restrict__ Ea, const float* __restrict__ Eh,
    const float* __restrict__ Ed, const float* __restrict__ Ey,
    const float* __restrict__ W,  const float* __restrict__ B,
    float* __restrict__ x)
{
    __shared__ float s[NPB0][4 * EMBD];
    const int base = blockIdx.x * NPB0;
    const int t = threadIdx.x;
    for (int j = 0; j < NPB0; ++j) {
        int node = base + j;
        if (node < NN) {
            int k0 = t, k1 = t + 128;
            float v0 = (k0 < 64) ? Ea[atom[node] * EMBD + k0]
                                 : Eh[hc[node] * EMBD + (k0 - 64)];
            float v1 = (k1 < 192) ? Ed[deg[node] * EMBD + (k1 - 128)]
                                  : Ey[hyb[node] * EMBD + (k1 - 192)];
            s[j][k0] = v0; s[j][k1] = v1;
        } else { s[j][t] = 0.f; s[j][t + 128] = 0.f; }
    }
    __syncthreads();
    float acc[NPB0];
#pragma unroll
    for (int j = 0; j < NPB0; ++j) acc[j] = 0.f;
    const int c = t;
    for (int k = 0; k < 4 * EMBD; ++k) {
        float w = W[k * H + c];
#pragma unroll
        for (int j = 0; j < NPB0; ++j) acc[j] += s[j][k] * w;
    }
    float bb = B[c];
    for (int j = 0; j < NPB0; ++j) {
        int node = base + j;
        if (node < NN) x[(long)node * H + c] = silu_f(acc[j] + bb);
    }
}

// ---------------------------------------------------------------- CSR build: histogram
__global__ __launch_bounds__(256) void k_hist(
    const int* __restrict__ target, int* __restrict__ counts)
{
    int e = blockIdx.x * 256 + threadIdx.x;
    if (e >= NE) return;
    atomicAdd(&counts[target[e]], 1);
}

// ---------------------------------------------------------------- CSR build: scan level 1
// exclusive scan within 256-chunk -> csr_start, chunk total -> blocksums
__global__ __launch_bounds__(SCAN_B) void k_scan1(
    const int* __restrict__ counts, int* __restrict__ csr_start,
    int* __restrict__ blocksums)
{
    __shared__ int s[SCAN_B];
    int tid = threadIdx.x;
    int i = blockIdx.x * SCAN_B + tid;
    int v = (i < NROWS) ? counts[i] : 0;
    s[tid] = v;
    __syncthreads();
    for (int off = 1; off < SCAN_B; off <<= 1) {
        int t = (tid >= off) ? s[tid - off] : 0;
        __syncthreads();
        s[tid] += t;
        __syncthreads();
    }
    if (i < NROWS) csr_start[i] = s[tid] - v;   // exclusive within chunk
    if (tid == SCAN_B - 1) blocksums[blockIdx.x] = s[tid];
}

// ---------------------------------------------------------------- CSR build: scan level 2 (single block)
__global__ __launch_bounds__(1024) void k_scan2(int* __restrict__ blocksums)
{
    __shared__ int s[1024];
    int tid = threadIdx.x;
    int v = (tid < NB1) ? blocksums[tid] : 0;
    s[tid] = v;
    __syncthreads();
    for (int off = 1; off < 1024; off <<= 1) {
        int t = (tid >= off) ? s[tid - off] : 0;
        __syncthreads();
        s[tid] += t;
        __syncthreads();
    }
    if (tid < NB1) blocksums[tid] = s[tid] - v;  // exclusive
}

// ---------------------------------------------------------------- CSR build: apply offsets + init cursor
__global__ __launch_bounds__(256) void k_scan3(
    int* __restrict__ csr_start, const int* __restrict__ blocksums,
    int* __restrict__ cursor)
{
    int i = blockIdx.x * 256 + threadIdx.x;
    if (i < NROWS) {
        int v = csr_start[i] + blocksums[i / SCAN_B];
        csr_start[i] = v;
        cursor[i] = v;
    }
    if (i == 0) csr_start[NROWS] = NE;
}

// ---------------------------------------------------------------- CSR build: fill edge array sorted by target
__global__ __launch_bounds__(256) void k_fill(
    const int* __restrict__ target, const int* __restrict__ src,
    int* __restrict__ cursor, int* __restrict__ esrc)
{
    int e = blockIdx.x * 256 + threadIdx.x;
    if (e >= NE) return;
    int s = src[e];
    if (s >= 2 * NN) s -= 2 * NN; else if (s >= NN) s -= NN;   // src % N
    int pos = atomicAdd(&cursor[target[e]], 1);
    esrc[pos] = s;
}

// ---------------------------------------------------------------- K1: CSR gather-aggregate (no atomics)
// one 64-lane wave per target row; lane holds float2 channels
__global__ __launch_bounds__(256) void k_gather(
    const int* __restrict__ esrc, const int* __restrict__ csr_start,
    const float* __restrict__ x, float* __restrict__ agg)
{
    int row = blockIdx.x * 4 + (threadIdx.x >> 6);
    if (row >= NROWS) return;
    int lane = threadIdx.x & 63;
    int e0 = csr_start[row], e1 = csr_start[row + 1];
    const float2* xp = (const float2*)x;
    float ax = 0.f, ay = 0.f;
    int e = e0;
    for (; e + 1 < e1; e += 2) {
        int s0 = esrc[e], s1 = esrc[e + 1];
        float2 v0 = xp[(long)s0 * 64 + lane];
        float2 v1 = xp[(long)s1 * 64 + lane];
        ax += v0.x + v1.x;
        ay += v0.y + v1.y;
    }
    if (e < e1) {
        int s0 = esrc[e];
        float2 v0 = xp[(long)s0 * 64 + lane];
        ax += v0.x; ay += v0.y;
    }
    float2 o; o.x = ax; o.y = ay;
    ((float2*)agg)[(long)row * 64 + lane] = o;
}

// ---------------------------------------------------------------- K2: shell_in + skip matmuls (K=512)
#define NPB1 8
__global__ __launch_bounds__(128) void k_shell(
    const float* __restrict__ x, const float* __restrict__ agg,
    const float* __restrict__ Win, const float* __restrict__ Bin,
    const float* __restrict__ Wsk, const float* __restrict__ Bsk,
    float* __restrict__ h, float* __restrict__ gskip)
{
    __shared__ float s[NPB1][4 * H];
    const int base = blockIdx.x * NPB1;
    const int t = threadIdx.x;
    for (int j = 0; j < NPB1; ++j) {
        long node = base + j;
        s[j][t]        = x[node * H + t];
        s[j][128 + t]  = agg[node * H + t];
        s[j][256 + t]  = agg[(NN + node) * H + t];
        s[j][384 + t]  = agg[(2L * NN + node) * H + t];
    }
    __syncthreads();
    float ah[NPB1], as[NPB1];
#pragma unroll
    for (int j = 0; j < NPB1; ++j) { ah[j] = 0.f; as[j] = 0.f; }
    const int c = t;
    for (int k = 0; k < 4 * H; ++k) {
        float wi = Win[k * H + c];
        float ws = Wsk[k * H + c];
#pragma unroll
        for (int j = 0; j < NPB1; ++j) { ah[j] += s[j][k] * wi; as[j] += s[j][k] * ws; }
    }
    float bi = Bin[c], bs = Bsk[c];
    for (int j = 0; j < NPB1; ++j) {
        long idx = (long)(base + j) * H + c;
        h[idx] = silu_f(ah[j] + bi);
        gskip[idx] = as[j] + bs;
    }
}

// ---------------------------------------------------------------- K3: fused residual MLP block
#define NPB2 16
__global__ __launch_bounds__(128) void k_mlp(
    const float* __restrict__ hin,
    const float* __restrict__ W1, const float* __restrict__ B1,
    const float* __restrict__ W2, const float* __restrict__ B2,
    const float* __restrict__ gskip,   // nullable; added when final MLP of layer
    float* __restrict__ hout)
{
    __shared__ float sh[NPB2][H];
    __shared__ float st[NPB2][H];
    const int base = blockIdx.x * NPB2;
    const int c = threadIdx.x;
    for (int j = 0; j < NPB2; ++j) sh[j][c] = hin[(long)(base + j) * H + c];
    __syncthreads();
    float acc[NPB2];
#pragma unroll
    for (int j = 0; j < NPB2; ++j) acc[j] = 0.f;
    for (int k = 0; k < H; ++k) {
        float w = W1[k * H + c];
#pragma unroll
        for (int j = 0; j < NPB2; ++j) acc[j] += sh[j][k] * w;
    }
    float b1 = B1[c];
    for (int j = 0; j < NPB2; ++j) st[j][c] = silu_f(acc[j] + b1);
    __syncthreads();
#pragma unroll
    for (int j = 0; j < NPB2; ++j) acc[j] = 0.f;
    for (int k = 0; k < H; ++k) {
        float w = W2[k * H + c];
#pragma unroll
        for (int j = 0; j < NPB2; ++j) acc[j] += st[j][k] * w;
    }
    float b2 = B2[c];
    for (int j = 0; j < NPB2; ++j) {
        long idx = (long)(base + j) * H + c;
        float v = acc[j] + b2 + sh[j][c];
        if (gskip) v += gskip[idx];
        hout[idx] = v;
    }
}

// ---------------------------------------------------------------- K4: attention scores (wave per node)
__global__ __launch_bounds__(256) void k_scores(
    const float* __restrict__ x, const float* __restrict__ aw,
    const float* __restrict__ ab, const float* __restrict__ temp,
    float* __restrict__ scores)
{
    int wave = threadIdx.x >> 6, lane = threadIdx.x & 63;
    int n = blockIdx.x * 4 + wave;
    if (n >= NN) return;
    float x0 = x[(long)n * H + lane];
    float x1 = x[(long)n * H + 64 + lane];
    float T = temp[0];
#pragma unroll
    for (int hh = 0; hh < NHEADS; ++hh) {
        float p = x0 * aw[hh * H + lane] + x1 * aw[hh * H + 64 + lane];
#pragma unroll
        for (int off = 32; off >= 1; off >>= 1) p += __shfl_xor(p, off, 64);
        if (lane == 0) scores[n * NHEADS + hh] = (p + ab[hh]) / T;
    }
}

// ---------------------------------------------------------------- K5: graph start offsets (batch sorted)
__global__ __launch_bounds__(256) void k_offsets(
    const int* __restrict__ batch, int* __restrict__ gstart)
{
    int n = blockIdx.x * 256 + threadIdx.x;
    if (n >= NN) return;
    int b = batch[n];
    int bp = (n == 0) ? -1 : batch[n - 1];
    for (int g = bp + 1; g <= b; ++g) gstart[g] = n;
    if (n == NN - 1) for (int g = b + 1; g <= NG; ++g) gstart[g] = NN;
}

// ---------------------------------------------------------------- K6: softmax pool (wave per graph)
__global__ __launch_bounds__(64) void k_pool(
    const float* __restrict__ x, const float* __restrict__ scores,
    const int* __restrict__ gstart, float* __restrict__ pooled)
{
    int g = blockIdx.x, lane = threadIdx.x;
    int s0 = gstart[g], s1 = gstart[g + 1];
    float m0 = -INFINITY, m1 = -INFINITY, m2 = -INFINITY, m3 = -INFINITY;
    for (int n = s0 + lane; n < s1; n += 64) {
        m0 = fmaxf(m0, scores[n * 4 + 0]); m1 = fmaxf(m1, scores[n * 4 + 1]);
        m2 = fmaxf(m2, scores[n * 4 + 2]); m3 = fmaxf(m3, scores[n * 4 + 3]);
    }
#pragma unroll
    for (int off = 32; off >= 1; off >>= 1) {
        m0 = fmaxf(m0, __shfl_xor(m0, off, 64)); m1 = fmaxf(m1, __shfl_xor(m1, off, 64));
        m2 = fmaxf(m2, __shfl_xor(m2, off, 64)); m3 = fmaxf(m3, __shfl_xor(m3, off, 64));
    }
    float d0 = 0.f, d1 = 0.f, d2 = 0.f, d3 = 0.f;
    for (int n = s0 + lane; n < s1; n += 64) {
        d0 += expf(scores[n * 4 + 0] - m0); d1 += expf(scores[n * 4 + 1] - m1);
        d2 += expf(scores[n * 4 + 2] - m2); d3 += expf(scores[n * 4 + 3] - m3);
    }
#pragma unroll
    for (int off = 32; off >= 1; off >>= 1) {
        d0 += __shfl_xor(d0, off, 64); d1 += __shfl_xor(d1, off, 64);
        d2 += __shfl_xor(d2, off, 64); d3 += __shfl_xor(d3, off, 64);
    }
    float i0 = d0 > 0.f ? 1.f / d0 : 0.f;
    float i1 = d1 > 0.f ? 1.f / d1 : 0.f;
    float i2 = d2 > 0.f ? 1.f / d2 : 0.f;
    float i3 = d3 > 0.f ? 1.f / d3 : 0.f;
    float a0 = 0.f, a1 = 0.f;
    for (int n = s0; n < s1; ++n) {
        float wb = expf(scores[n * 4 + 0] - m0) * i0 + expf(scores[n * 4 + 1] - m1) * i1
                 + expf(scores[n * 4 + 2] - m2) * i2 + expf(scores[n * 4 + 3] - m3) * i3;
        wb *= 0.25f;
        a0 += wb * x[(long)n * H + lane];
        a1 += wb * x[(long)n * H + 64 + lane];
    }
    pooled[g * H + lane] = a0;
    pooled[g * H + 64 + lane] = a1;
}

// ---------------------------------------------------------------- K7: FFN readout (block per graph)
__global__ __launch_bounds__(128) void k_ffn(
    const float* __restrict__ pooled,
    const float* __restrict__ W1, const float* __restrict__ B1,
    const float* __restrict__ W2, const float* __restrict__ B2,
    const float* __restrict__ W3, const float* __restrict__ B3,
    float* __restrict__ out)
{
    __shared__ float p[H], t1[H], t2[H], red[H];
    int g = blockIdx.x, c = threadIdx.x;
    p[c] = pooled[g * H + c];
    __syncthreads();
    float acc = 0.f;
    for (int k = 0; k < H; ++k) acc += p[k] * W1[k * H + c];
    t1[c] = silu_f(acc + B1[c]);
    __syncthreads();
    acc = 0.f;
    for (int k = 0; k < H; ++k) acc += t1[k] * W2[k * H + c];
    t2[c] = silu_f(acc + B2[c]);
    __syncthreads();
    red[c] = t2[c] * W3[c];
    __syncthreads();
    for (int off = 64; off >= 1; off >>= 1) {
        if (c < off) red[c] += red[c + off];
        __syncthreads();
    }
    if (c == 0) out[g] = red[0] + B3[0];
}

// ---------------------------------------------------------------- launch
extern "C" void kernel_launch(void* const* d_in, const int* in_sizes, int n_in,
                              void* d_out, int out_size, void* d_ws, size_t ws_size,
                              hipStream_t stream)
{
    const int*   atom   = (const int*)d_in[0];
    const int*   hc     = (const int*)d_in[1];
    const int*   deg    = (const int*)d_in[2];
    const int*   hyb    = (const int*)d_in[3];
    const int*   target = (const int*)d_in[4];
    const int*   src    = (const int*)d_in[5];
    const int*   batch  = (const int*)d_in[6];
    const float* Ea     = (const float*)d_in[7];
    const float* Eh     = (const float*)d_in[8];
    const float* Ed     = (const float*)d_in[9];
    const float* Ey     = (const float*)d_in[10];
    const float* projW  = (const float*)d_in[11];
    const float* projB  = (const float*)d_in[12];
    const float* sInW   = (const float*)d_in[13];
    const float* sInB   = (const float*)d_in[14];
    const float* mW1    = (const float*)d_in[15];
    const float* mB1    = (const float*)d_in[16];
    const float* mW2    = (const float*)d_in[17];
    const float* mB2    = (const float*)d_in[18];
    const float* sSkW   = (const float*)d_in[19];
    const float* sSkB   = (const float*)d_in[20];
    const float* attnW  = (const float*)d_in[21];
    const float* attnB  = (const float*)d_in[22];
    const float* temp   = (const float*)d_in[23];
    const float* fW1    = (const float*)d_in[24];
    const float* fB1    = (const float*)d_in[25];
    const float* fW2    = (const float*)d_in[26];
    const float* fB2    = (const float*)d_in[27];
    const float* fW3    = (const float*)d_in[28];
    const float* fB3    = (const float*)d_in[29];
    float* out = (float*)d_out;

    // workspace carve (~167 MB)
    char* w = (char*)d_ws;
    float* x       = (float*)w; w += sizeof(float) * (long)NN * H;
    float* agg     = (float*)w; w += sizeof(float) * (long)NROWS * H;
    float* hbuf    = (float*)w; w += sizeof(float) * (long)NN * H;
    float* gskip   = (float*)w; w += sizeof(float) * (long)NN * H;
    float* scores  = (float*)w; w += sizeof(float) * (long)NN * NHEADS;
    float* pooled  = (float*)w; w += sizeof(float) * (long)NG * H;
    int*   gstart  = (int*)w;   w += sizeof(int) * (NG + 1);
    int*   counts  = (int*)w;   w += sizeof(int) * NROWS;      // reused as cursor
    int*   csr_start = (int*)w; w += sizeof(int) * (NROWS + 1);
    int*   esrc    = (int*)w;   w += sizeof(int) * NE;
    int*   blocksums = (int*)w; w += sizeof(int) * 1024;

    // ---- CSR build (edge structure is layer-invariant: build once) ----
    hipMemsetAsync(counts, 0, sizeof(int) * NROWS, stream);
    k_hist<<<(NE + 255) / 256, 256, 0, stream>>>(target, counts);
    k_scan1<<<NB1, SCAN_B, 0, stream>>>(counts, csr_start, blocksums);
    k_scan2<<<1, 1024, 0, stream>>>(blocksums);
    k_scan3<<<(NROWS + 255) / 256, 256, 0, stream>>>(csr_start, blocksums, counts /*cursor*/);
    k_fill<<<(NE + 255) / 256, 256, 0, stream>>>(target, src, counts /*cursor*/, esrc);

    k_embed<<<NN / NPB0, 128, 0, stream>>>(atom, hc, deg, hyb, Ea, Eh, Ed, Ey, projW, projB, x);
    k_offsets<<<(NN + 255) / 256, 256, 0, stream>>>(batch, gstart);

    for (int l = 0; l < NL; ++l) {
        k_gather<<<(NROWS + 3) / 4, 256, 0, stream>>>(esrc, csr_start, x, agg);
        k_shell<<<NN / NPB1, 128, 0, stream>>>(x, agg,
            sInW + (long)l * 4 * H * H, sInB + l * H,
            sSkW + (long)l * 4 * H * H, sSkB + l * H, hbuf, gskip);
        k_mlp<<<NN / NPB2, 128, 0, stream>>>(hbuf,
            mW1 + (long)(l * NMLP + 0) * H * H, mB1 + (long)(l * NMLP + 0) * H,
            mW2 + (long)(l * NMLP + 0) * H * H, mB2 + (long)(l * NMLP + 0) * H,
            nullptr, hbuf);
        k_mlp<<<NN / NPB2, 128, 0, stream>>>(hbuf,
            mW1 + (long)(l * NMLP + 1) * H * H, mB1 + (long)(l * NMLP + 1) * H,
            mW2 + (long)(l * NMLP + 1) * H * H, mB2 + (long)(l * NMLP + 1) * H,
            gskip, x);
    }

    k_scores<<<NN / 4, 256, 0, stream>>>(x, attnW, attnB, temp, scores);
    k_pool<<<NG, 64, 0, stream>>>(x, scores, gstart, pooled);
    k_ffn<<<NG, 128, 0, stream>>>(pooled, fW1, fB1, fW2, fB2, fW3, fB3, out);
}

// Round 3
// 1313.229 us; speedup vs baseline: 10.3389x; 1.6866x over previous
//
#include <hip/hip_runtime.h>
#include <math.h>

#define NN      50000
#define NNP     50048          // padded nodes = 391*128 (exact)
#define NE      2400000
#define NHOPS   3
#define NG      2048
#define H       128
#define EMBD    64
#define NL      3
#define NMLP    2
#define NHEADS  4
#define NROWS   (NHOPS * NN)   // 150000
#define SCAN_B  256
#define NB1     ((NROWS + SCAN_B - 1) / SCAN_B)
#define LSTR    136            // LDS row stride (bf16 units): 16B-aligned, even bank spread

typedef __bf16 bf16x8 __attribute__((ext_vector_type(8)));
typedef __bf16 bf16x4 __attribute__((ext_vector_type(4)));
typedef float  f32x4  __attribute__((ext_vector_type(4)));

__device__ __forceinline__ float silu_f(float v) { return v / (1.0f + expf(-v)); }

__device__ __forceinline__ f32x4 mm(bf16x8 a, bf16x8 b, f32x4 c) {
    return __builtin_amdgcn_mfma_f32_16x16x32_bf16(a, b, c, 0, 0, 0);
}

// ---------------------------------------------------------------- weight pack: W[K][128] fp32 -> A-frag-ordered bf16
// packed idx within matrix: (((kt*8+mt)*4+q)*16+n16)*8+j  <=>  frag addr = kt*4096 + mt*512 + lane*8
__global__ __launch_bounds__(256) void k_packw(
    const float* __restrict__ W, __bf16* __restrict__ out, int K, int nmat)
{
    long tid = (long)blockIdx.x * 256 + threadIdx.x;
    long per = (long)K * 128;
    if (tid >= per * nmat) return;
    long mat = tid / per, e = tid - mat * per;
    int j = (int)(e & 7), n16 = (int)((e >> 3) & 15), q = (int)((e >> 7) & 3),
        mt = (int)((e >> 9) & 7), kt = (int)(e >> 12);
    int k = kt * 32 + q * 8 + j, n = mt * 16 + n16;
    out[tid] = (__bf16)W[mat * per + (long)k * 128 + n];
}

// ---------------------------------------------------------------- embedding tables fp32 -> bf16 (concat layout)
__global__ __launch_bounds__(256) void k_cvt_emb(
    const float* __restrict__ Ea, const float* __restrict__ Eh,
    const float* __restrict__ Ed, const float* __restrict__ Ey,
    __bf16* __restrict__ out)
{
    int t = blockIdx.x * 256 + threadIdx.x;
    if (t >= 8000) return;
    float v;
    if (t < 6400) v = Ea[t];
    else if (t < 6976) v = Eh[t - 6400];
    else if (t < 7488) v = Ed[t - 6976];
    else v = Ey[t - 7488];
    out[t] = (__bf16)v;
}

// ---------------------------------------------------------------- K0: embed + project + silu (MFMA)
__global__ __launch_bounds__(256) void k_embed_m(
    const int* __restrict__ atom, const int* __restrict__ hc,
    const int* __restrict__ deg,  const int* __restrict__ hyb,
    const __bf16* __restrict__ emb, const __bf16* __restrict__ pw,
    const float* __restrict__ pb, __bf16* __restrict__ x)
{
    const int lane = threadIdx.x & 63, wid = threadIdx.x >> 6;
    const int q = lane >> 4, l16 = lane & 15;
    const int nb = blockIdx.x * 128 + wid * 32;
    int ia[2][4];
#pragma unroll
    for (int nt = 0; nt < 2; ++nt) {
        int n = nb + nt * 16 + l16;
        if (n >= NN) n = NN - 1;
        ia[nt][0] = atom[n]; ia[nt][1] = hc[n]; ia[nt][2] = deg[n]; ia[nt][3] = hyb[n];
    }
    f32x4 acc[2][8];
#pragma unroll
    for (int nt = 0; nt < 2; ++nt)
#pragma unroll
        for (int mt = 0; mt < 8; ++mt) acc[nt][mt] = (f32x4)(0.f);
    const int tb[4] = {0, 6400, 6976, 7488};
    for (int kt = 0; kt < 8; ++kt) {
        int t = kt >> 1;
        int koff = (kt & 1) * 32 + q * 8;
        bf16x8 bfrag[2];
#pragma unroll
        for (int nt = 0; nt < 2; ++nt)
            bfrag[nt] = *(const bf16x8*)(emb + tb[t] + (long)ia[nt][t] * 64 + koff);
        const __bf16* ap = pw + (long)kt * 4096 + lane * 8;
#pragma unroll
        for (int mt = 0; mt < 8; ++mt) {
            bf16x8 a = *(const bf16x8*)(ap + mt * 512);
            acc[0][mt] = mm(a, bfrag[0], acc[0][mt]);
            acc[1][mt] = mm(a, bfrag[1], acc[1][mt]);
        }
    }
#pragma unroll
    for (int nt = 0; nt < 2; ++nt) {
        long node = nb + nt * 16 + l16;
#pragma unroll
        for (int mt = 0; mt < 8; ++mt) {
            int ch = mt * 16 + q * 4;
            float4 bb = *(const float4*)(pb + ch);
            bf16x4 o;
            o[0] = (__bf16)silu_f(acc[nt][mt][0] + bb.x);
            o[1] = (__bf16)silu_f(acc[nt][mt][1] + bb.y);
            o[2] = (__bf16)silu_f(acc[nt][mt][2] + bb.z);
            o[3] = (__bf16)silu_f(acc[nt][mt][3] + bb.w);
            *(bf16x4*)(x + node * 128 + ch) = o;
        }
    }
}

// ---------------------------------------------------------------- CSR build
__global__ __launch_bounds__(256) void k_hist(
    const int* __restrict__ target, int* __restrict__ counts)
{
    int e = blockIdx.x * 256 + threadIdx.x;
    if (e >= NE) return;
    atomicAdd(&counts[target[e]], 1);
}

__global__ __launch_bounds__(SCAN_B) void k_scan1(
    const int* __restrict__ counts, int* __restrict__ csr_start,
    int* __restrict__ blocksums)
{
    __shared__ int s[SCAN_B];
    int tid = threadIdx.x;
    int i = blockIdx.x * SCAN_B + tid;
    int v = (i < NROWS) ? counts[i] : 0;
    s[tid] = v;
    __syncthreads();
    for (int off = 1; off < SCAN_B; off <<= 1) {
        int t = (tid >= off) ? s[tid - off] : 0;
        __syncthreads();
        s[tid] += t;
        __syncthreads();
    }
    if (i < NROWS) csr_start[i] = s[tid] - v;
    if (tid == SCAN_B - 1) blocksums[blockIdx.x] = s[tid];
}

__global__ __launch_bounds__(1024) void k_scan2(int* __restrict__ blocksums)
{
    __shared__ int s[1024];
    int tid = threadIdx.x;
    int v = (tid < NB1) ? blocksums[tid] : 0;
    s[tid] = v;
    __syncthreads();
    for (int off = 1; off < 1024; off <<= 1) {
        int t = (tid >= off) ? s[tid - off] : 0;
        __syncthreads();
        s[tid] += t;
        __syncthreads();
    }
    if (tid < NB1) blocksums[tid] = s[tid] - v;
}

__global__ __launch_bounds__(256) void k_scan3(
    int* __restrict__ csr_start, const int* __restrict__ blocksums,
    int* __restrict__ cursor)
{
    int i = blockIdx.x * 256 + threadIdx.x;
    if (i < NROWS) {
        int v = csr_start[i] + blocksums[i / SCAN_B];
        csr_start[i] = v;
        cursor[i] = v;
    }
    if (i == 0) csr_start[NROWS] = NE;
}

__global__ __launch_bounds__(256) void k_fill(
    const int* __restrict__ target, const int* __restrict__ src,
    int* __restrict__ cursor, int* __restrict__ esrc)
{
    int e = blockIdx.x * 256 + threadIdx.x;
    if (e >= NE) return;
    int s = src[e];
    if (s >= 2 * NN) s -= 2 * NN; else if (s >= NN) s -= NN;
    int pos = atomicAdd(&cursor[target[e]], 1);
    esrc[pos] = s;
}

// ---------------------------------------------------------------- K1: CSR gather (bf16 x, fp32 accumulate)
__global__ __launch_bounds__(256) void k_gather(
    const int* __restrict__ esrc, const int* __restrict__ csr_start,
    const unsigned int* __restrict__ x2, unsigned int* __restrict__ agg2)
{
    int row = blockIdx.x * 4 + (threadIdx.x >> 6);
    if (row >= NROWS) return;
    int lane = threadIdx.x & 63;
    int e0 = csr_start[row], e1 = csr_start[row + 1];
    float ax = 0.f, ay = 0.f;
    int e = e0;
    for (; e + 1 < e1; e += 2) {
        int s0 = esrc[e], s1 = esrc[e + 1];
        unsigned v0 = x2[(long)s0 * 64 + lane];
        unsigned v1 = x2[(long)s1 * 64 + lane];
        ax += __builtin_bit_cast(float, v0 << 16) + __builtin_bit_cast(float, v1 << 16);
        ay += __builtin_bit_cast(float, v0 & 0xffff0000u) + __builtin_bit_cast(float, v1 & 0xffff0000u);
    }
    if (e < e1) {
        unsigned v0 = x2[(long)esrc[e] * 64 + lane];
        ax += __builtin_bit_cast(float, v0 << 16);
        ay += __builtin_bit_cast(float, v0 & 0xffff0000u);
    }
    int hop = row / NN, node = row - hop * NN;
    unsigned short ux = __builtin_bit_cast(unsigned short, (__bf16)ax);
    unsigned short uy = __builtin_bit_cast(unsigned short, (__bf16)ay);
    agg2[((long)hop * NNP + node) * 64 + lane] = (unsigned)ux | ((unsigned)uy << 16);
}

// ---------------------------------------------------------------- K2: shell_in + skip (MFMA, K=512)
__global__ __launch_bounds__(256) void k_shell_m(
    const __bf16* __restrict__ x, const __bf16* __restrict__ agg,
    const __bf16* __restrict__ pwin, const float* __restrict__ bin,
    const __bf16* __restrict__ pwsk, const float* __restrict__ bsk,
    __bf16* __restrict__ h, __bf16* __restrict__ gskip)
{
    const int lane = threadIdx.x & 63, wid = threadIdx.x >> 6;
    const int q = lane >> 4, l16 = lane & 15;
    const int nb = blockIdx.x * 128 + wid * 32;
    f32x4 aci[2][8], acs[2][8];
#pragma unroll
    for (int nt = 0; nt < 2; ++nt)
#pragma unroll
        for (int mt = 0; mt < 8; ++mt) { aci[nt][mt] = (f32x4)(0.f); acs[nt][mt] = (f32x4)(0.f); }
    const __bf16* planes[4] = {x, agg, agg + (long)NNP * 128, agg + 2L * NNP * 128};
    for (int kt = 0; kt < 16; ++kt) {
        const __bf16* src = planes[kt >> 2];
        int koff = (kt & 3) * 32 + q * 8;
        bf16x8 bfrag[2];
#pragma unroll
        for (int nt = 0; nt < 2; ++nt)
            bfrag[nt] = *(const bf16x8*)(src + (long)(nb + nt * 16 + l16) * 128 + koff);
        const __bf16* aip = pwin + (long)kt * 4096 + lane * 8;
        const __bf16* asp = pwsk + (long)kt * 4096 + lane * 8;
#pragma unroll
        for (int mt = 0; mt < 8; ++mt) {
            bf16x8 ai = *(const bf16x8*)(aip + mt * 512);
            bf16x8 as = *(const bf16x8*)(asp + mt * 512);
            aci[0][mt] = mm(ai, bfrag[0], aci[0][mt]);
            aci[1][mt] = mm(ai, bfrag[1], aci[1][mt]);
            acs[0][mt] = mm(as, bfrag[0], acs[0][mt]);
            acs[1][mt] = mm(as, bfrag[1], acs[1][mt]);
        }
    }
#pragma unroll
    for (int nt = 0; nt < 2; ++nt) {
        long node = nb + nt * 16 + l16;
#pragma unroll
        for (int mt = 0; mt < 8; ++mt) {
            int ch = mt * 16 + q * 4;
            float4 bi = *(const float4*)(bin + ch);
            float4 bs = *(const float4*)(bsk + ch);
            bf16x4 oh, og;
            oh[0] = (__bf16)silu_f(aci[nt][mt][0] + bi.x); og[0] = (__bf16)(acs[nt][mt][0] + bs.x);
            oh[1] = (__bf16)silu_f(aci[nt][mt][1] + bi.y); og[1] = (__bf16)(acs[nt][mt][1] + bs.y);
            oh[2] = (__bf16)silu_f(aci[nt][mt][2] + bi.z); og[2] = (__bf16)(acs[nt][mt][2] + bs.z);
            oh[3] = (__bf16)silu_f(aci[nt][mt][3] + bi.w); og[3] = (__bf16)(acs[nt][mt][3] + bs.w);
            *(bf16x4*)(h + node * 128 + ch) = oh;
            *(bf16x4*)(gskip + node * 128 + ch) = og;
        }
    }
}

// ---------------------------------------------------------------- K3: fused residual MLP (both halves, MFMA)
__global__ __launch_bounds__(256) void k_mlp_m(
    const __bf16* __restrict__ hin,
    const __bf16* __restrict__ pw1, const float* __restrict__ b1,
    const __bf16* __restrict__ pw2, const float* __restrict__ b2,
    const __bf16* __restrict__ gskip, __bf16* __restrict__ hout)
{
    __shared__ __bf16 lds[4][32 * LSTR];
    const int lane = threadIdx.x & 63, wid = threadIdx.x >> 6;
    const int q = lane >> 4, l16 = lane & 15;
    const int nb = blockIdx.x * 128 + wid * 32;
    __bf16* L = lds[wid];
    f32x4 acc[2][8];
#pragma unroll
    for (int nt = 0; nt < 2; ++nt)
#pragma unroll
        for (int mt = 0; mt < 8; ++mt) acc[nt][mt] = (f32x4)(0.f);
    for (int kt = 0; kt < 4; ++kt) {
        int koff = kt * 32 + q * 8;
        bf16x8 bfrag[2];
#pragma unroll
        for (int nt = 0; nt < 2; ++nt)
            bfrag[nt] = *(const bf16x8*)(hin + (long)(nb + nt * 16 + l16) * 128 + koff);
        const __bf16* ap = pw1 + (long)kt * 4096 + lane * 8;
#pragma unroll
        for (int mt = 0; mt < 8; ++mt) {
            bf16x8 a = *(const bf16x8*)(ap + mt * 512);
            acc[0][mt] = mm(a, bfrag[0], acc[0][mt]);
            acc[1][mt] = mm(a, bfrag[1], acc[1][mt]);
        }
    }
#pragma unroll
    for (int nt = 0; nt < 2; ++nt) {
        int nl = nt * 16 + l16;
#pragma unroll
        for (int mt = 0; mt < 8; ++mt) {
            int ch = mt * 16 + q * 4;
            float4 bb = *(const float4*)(b1 + ch);
            bf16x4 o;
            o[0] = (__bf16)silu_f(acc[nt][mt][0] + bb.x);
            o[1] = (__bf16)silu_f(acc[nt][mt][1] + bb.y);
            o[2] = (__bf16)silu_f(acc[nt][mt][2] + bb.z);
            o[3] = (__bf16)silu_f(acc[nt][mt][3] + bb.w);
            *(bf16x4*)(L + nl * LSTR + ch) = o;
        }
    }
    __syncthreads();
    f32x4 ac2[2][8];
#pragma unroll
    for (int nt = 0; nt < 2; ++nt)
#pragma unroll
        for (int mt = 0; mt < 8; ++mt) ac2[nt][mt] = (f32x4)(0.f);
    for (int kt = 0; kt < 4; ++kt) {
        int koff = kt * 32 + q * 8;
        bf16x8 bfrag[2];
#pragma unroll
        for (int nt = 0; nt < 2; ++nt)
            bfrag[nt] = *(const bf16x8*)(L + (nt * 16 + l16) * LSTR + koff);
        const __bf16* ap = pw2 + (long)kt * 4096 + lane * 8;
#pragma unroll
        for (int mt = 0; mt < 8; ++mt) {
            bf16x8 a = *(const bf16x8*)(ap + mt * 512);
            ac2[0][mt] = mm(a, bfrag[0], ac2[0][mt]);
            ac2[1][mt] = mm(a, bfrag[1], ac2[1][mt]);
        }
    }
#pragma unroll
    for (int nt = 0; nt < 2; ++nt) {
        long node = nb + nt * 16 + l16;
#pragma unroll
        for (int mt = 0; mt < 8; ++mt) {
            int ch = mt * 16 + q * 4;
            float4 bb = *(const float4*)(b2 + ch);
            bf16x4 sk = *(const bf16x4*)(hin + node * 128 + ch);
            float v0 = ac2[nt][mt][0] + bb.x + (float)sk[0];
            float v1 = ac2[nt][mt][1] + bb.y + (float)sk[1];
            float v2 = ac2[nt][mt][2] + bb.z + (float)sk[2];
            float v3 = ac2[nt][mt][3] + bb.w + (float)sk[3];
            if (gskip) {
                bf16x4 g = *(const bf16x4*)(gskip + node * 128 + ch);
                v0 += (float)g[0]; v1 += (float)g[1]; v2 += (float)g[2]; v3 += (float)g[3];
            }
            bf16x4 o;
            o[0] = (__bf16)v0; o[1] = (__bf16)v1; o[2] = (__bf16)v2; o[3] = (__bf16)v3;
            *(bf16x4*)(hout + node * 128 + ch) = o;
        }
    }
}

// ---------------------------------------------------------------- K4: attention scores
__global__ __launch_bounds__(256) void k_scores(
    const __bf16* __restrict__ x, const float* __restrict__ aw,
    const float* __restrict__ ab, const float* __restrict__ temp,
    float* __restrict__ scores)
{
    int wave = threadIdx.x >> 6, lane = threadIdx.x & 63;
    int n = blockIdx.x * 4 + wave;
    if (n >= NN) return;
    float x0 = (float)x[(long)n * H + lane];
    float x1 = (float)x[(long)n * H + 64 + lane];
    float T = temp[0];
#pragma unroll
    for (int hh = 0; hh < NHEADS; ++hh) {
        float p = x0 * aw[hh * H + lane] + x1 * aw[hh * H + 64 + lane];
#pragma unroll
        for (int off = 32; off >= 1; off >>= 1) p += __shfl_xor(p, off, 64);
        if (lane == 0) scores[n * NHEADS + hh] = (p + ab[hh]) / T;
    }
}

// ---------------------------------------------------------------- K5: graph offsets
__global__ __launch_bounds__(256) void k_offsets(
    const int* __restrict__ batch, int* __restrict__ gstart)
{
    int n = blockIdx.x * 256 + threadIdx.x;
    if (n >= NN) return;
    int b = batch[n];
    int bp = (n == 0) ? -1 : batch[n - 1];
    for (int g = bp + 1; g <= b; ++g) gstart[g] = n;
    if (n == NN - 1) for (int g = b + 1; g <= NG; ++g) gstart[g] = NN;
}

// ---------------------------------------------------------------- K6: softmax pool (wave per graph)
__global__ __launch_bounds__(64) void k_pool(
    const __bf16* __restrict__ x, const float* __restrict__ scores,
    const int* __restrict__ gstart, float* __restrict__ pooled)
{
    int g = blockIdx.x, lane = threadIdx.x;
    int s0 = gstart[g], s1 = gstart[g + 1];
    float m0 = -INFINITY, m1 = -INFINITY, m2 = -INFINITY, m3 = -INFINITY;
    for (int n = s0 + lane; n < s1; n += 64) {
        m0 = fmaxf(m0, scores[n * 4 + 0]); m1 = fmaxf(m1, scores[n * 4 + 1]);
        m2 = fmaxf(m2, scores[n * 4 + 2]); m3 = fmaxf(m3, scores[n * 4 + 3]);
    }
#pragma unroll
    for (int off = 32; off >= 1; off >>= 1) {
        m0 = fmaxf(m0, __shfl_xor(m0, off, 64)); m1 = fmaxf(m1, __shfl_xor(m1, off, 64));
        m2 = fmaxf(m2, __shfl_xor(m2, off, 64)); m3 = fmaxf(m3, __shfl_xor(m3, off, 64));
    }
    float d0 = 0.f, d1 = 0.f, d2 = 0.f, d3 = 0.f;
    for (int n = s0 + lane; n < s1; n += 64) {
        d0 += expf(scores[n * 4 + 0] - m0); d1 += expf(scores[n * 4 + 1] - m1);
        d2 += expf(scores[n * 4 + 2] - m2); d3 += expf(scores[n * 4 + 3] - m3);
    }
#pragma unroll
    for (int off = 32; off >= 1; off >>= 1) {
        d0 += __shfl_xor(d0, off, 64); d1 += __shfl_xor(d1, off, 64);
        d2 += __shfl_xor(d2, off, 64); d3 += __shfl_xor(d3, off, 64);
    }
    float i0 = d0 > 0.f ? 1.f / d0 : 0.f;
    float i1 = d1 > 0.f ? 1.f / d1 : 0.f;
    float i2 = d2 > 0.f ? 1.f / d2 : 0.f;
    float i3 = d3 > 0.f ? 1.f / d3 : 0.f;
    float a0 = 0.f, a1 = 0.f;
    for (int n = s0; n < s1; ++n) {
        float wb = expf(scores[n * 4 + 0] - m0) * i0 + expf(scores[n * 4 + 1] - m1) * i1
                 + expf(scores[n * 4 + 2] - m2) * i2 + expf(scores[n * 4 + 3] - m3) * i3;
        wb *= 0.25f;
        a0 += wb * (float)x[(long)n * H + lane];
        a1 += wb * (float)x[(long)n * H + 64 + lane];
    }
    pooled[g * H + lane] = a0;
    pooled[g * H + 64 + lane] = a1;
}

// ---------------------------------------------------------------- K7: FFN readout
__global__ __launch_bounds__(128) void k_ffn(
    const float* __restrict__ pooled,
    const float* __restrict__ W1, const float* __restrict__ B1,
    const float* __restrict__ W2, const float* __restrict__ B2,
    const float* __restrict__ W3, const float* __restrict__ B3,
    float* __restrict__ out)
{
    __shared__ float p[H], t1[H], t2[H], red[H];
    int g = blockIdx.x, c = threadIdx.x;
    p[c] = pooled[g * H + c];
    __syncthreads();
    float acc = 0.f;
    for (int k = 0; k < H; ++k) acc += p[k] * W1[k * H + c];
    t1[c] = silu_f(acc + B1[c]);
    __syncthreads();
    acc = 0.f;
    for (int k = 0; k < H; ++k) acc += t1[k] * W2[k * H + c];
    t2[c] = silu_f(acc + B2[c]);
    __syncthreads();
    red[c] = t2[c] * W3[c];
    __syncthreads();
    for (int off = 64; off >= 1; off >>= 1) {
        if (c < off) red[c] += red[c + off];
        __syncthreads();
    }
    if (c == 0) out[g] = red[0] + B3[0];
}

// ---------------------------------------------------------------- launch
extern "C" void kernel_launch(void* const* d_in, const int* in_sizes, int n_in,
                              void* d_out, int out_size, void* d_ws, size_t ws_size,
                              hipStream_t stream)
{
    const int*   atom   = (const int*)d_in[0];
    const int*   hc     = (const int*)d_in[1];
    const int*   deg    = (const int*)d_in[2];
    const int*   hyb    = (const int*)d_in[3];
    const int*   target = (const int*)d_in[4];
    const int*   src    = (const int*)d_in[5];
    const int*   batch  = (const int*)d_in[6];
    const float* Ea     = (const float*)d_in[7];
    const float* Eh     = (const float*)d_in[8];
    const float* Ed     = (const float*)d_in[9];
    const float* Ey     = (const float*)d_in[10];
    const float* projW  = (const float*)d_in[11];
    const float* projB  = (const float*)d_in[12];
    const float* sInW   = (const float*)d_in[13];
    const float* sInB   = (const float*)d_in[14];
    const float* mW1    = (const float*)d_in[15];
    const float* mB1    = (const float*)d_in[16];
    const float* mW2    = (const float*)d_in[17];
    const float* mB2    = (const float*)d_in[18];
    const float* sSkW   = (const float*)d_in[19];
    const float* sSkB   = (const float*)d_in[20];
    const float* attnW  = (const float*)d_in[21];
    const float* attnB  = (const float*)d_in[22];
    const float* temp   = (const float*)d_in[23];
    const float* fW1    = (const float*)d_in[24];
    const float* fB1    = (const float*)d_in[25];
    const float* fW2    = (const float*)d_in[26];
    const float* fB2    = (const float*)d_in[27];
    const float* fW3    = (const float*)d_in[28];
    const float* fB3    = (const float*)d_in[29];
    float* out = (float*)d_out;

    char* w = (char*)d_ws;
    auto take = [&](size_t bytes) { void* p = (void*)w; w += (bytes + 255) & ~(size_t)255; return p; };
    __bf16* x      = (__bf16*)take(2L * NNP * H);
    __bf16* agg    = (__bf16*)take(2L * 3 * NNP * H);
    __bf16* hbuf   = (__bf16*)take(2L * NNP * H);
    __bf16* hbuf2  = (__bf16*)take(2L * NNP * H);
    __bf16* gskip  = (__bf16*)take(2L * NNP * H);
    __bf16* pproj  = (__bf16*)take(2L * 256 * H);
    __bf16* pin    = (__bf16*)take(2L * 3 * 512 * H);
    __bf16* psk    = (__bf16*)take(2L * 3 * 512 * H);
    __bf16* pw1    = (__bf16*)take(2L * 6 * 128 * H);
    __bf16* pw2    = (__bf16*)take(2L * 6 * 128 * H);
    __bf16* embb   = (__bf16*)take(2L * 8000);
    float*  scores = (float*)take(4L * NN * NHEADS);
    float*  pooled = (float*)take(4L * NG * H);
    int*    gstart = (int*)take(4L * (NG + 1));
    int*    counts = (int*)take(4L * NROWS);
    int*    csr_start = (int*)take(4L * (NROWS + 1));
    int*    esrc   = (int*)take(4L * NE);
    int*    blocksums = (int*)take(4L * 1024);

    // ---- weight packing (weights restored each call -> pack each call) ----
    k_packw<<<(1 * 256 * 128) / 256, 256, 0, stream>>>(projW, pproj, 256, 1);
    k_packw<<<(3 * 512 * 128) / 256, 256, 0, stream>>>(sInW, pin, 512, 3);
    k_packw<<<(3 * 512 * 128) / 256, 256, 0, stream>>>(sSkW, psk, 512, 3);
    k_packw<<<(6 * 128 * 128) / 256, 256, 0, stream>>>(mW1, pw1, 128, 6);
    k_packw<<<(6 * 128 * 128) / 256, 256, 0, stream>>>(mW2, pw2, 128, 6);
    k_cvt_emb<<<32, 256, 0, stream>>>(Ea, Eh, Ed, Ey, embb);

    // ---- CSR build (layer-invariant) ----
    hipMemsetAsync(counts, 0, sizeof(int) * NROWS, stream);
    k_hist<<<(NE + 255) / 256, 256, 0, stream>>>(target, counts);
    k_scan1<<<NB1, SCAN_B, 0, stream>>>(counts, csr_start, blocksums);
    k_scan2<<<1, 1024, 0, stream>>>(blocksums);
    k_scan3<<<(NROWS + 255) / 256, 256, 0, stream>>>(csr_start, blocksums, counts);
    k_fill<<<(NE + 255) / 256, 256, 0, stream>>>(target, src, counts, esrc);

    k_embed_m<<<NNP / 128, 256, 0, stream>>>(atom, hc, deg, hyb, embb, pproj, projB, x);
    k_offsets<<<(NN + 255) / 256, 256, 0, stream>>>(batch, gstart);

    for (int l = 0; l < NL; ++l) {
        k_gather<<<(NROWS + 3) / 4, 256, 0, stream>>>(esrc, csr_start,
            (const unsigned int*)x, (unsigned int*)agg);
        k_shell_m<<<NNP / 128, 256, 0, stream>>>(x, agg,
            pin + (long)l * 512 * H, sInB + l * H,
            psk + (long)l * 512 * H, sSkB + l * H, hbuf, gskip);
        k_mlp_m<<<NNP / 128, 256, 0, stream>>>(hbuf,
            pw1 + (long)(l * NMLP + 0) * 128 * H, mB1 + (long)(l * NMLP + 0) * H,
            pw2 + (long)(l * NMLP + 0) * 128 * H, mB2 + (long)(l * NMLP + 0) * H,
            nullptr, hbuf2);
        k_mlp_m<<<NNP / 128, 256, 0, stream>>>(hbuf2,
            pw1 + (long)(l * NMLP + 1) * 128 * H, mB1 + (long)(l * NMLP + 1) * H,
            pw2 + (long)(l * NMLP + 1) * 128 * H, mB2 + (long)(l * NMLP + 1) * H,
            gskip, x);
    }

    k_scores<<<NN / 4, 256, 0, stream>>>(x, attnW, attnB, temp, scores);
    k_pool<<<NG, 64, 0, stream>>>(x, scores, gstart, pooled);
    k_ffn<<<NG, 128, 0, stream>>>(pooled, fW1, fB1, fW2, fB2, fW3, fB3, out);
}

// Round 4
// 1081.166 us; speedup vs baseline: 12.5580x; 1.2146x over previous
//
#include <hip/hip_runtime.h>
#include <math.h>

#define NN      50000
#define NNP     50048          // padded nodes = 391*128
#define NE      2400000
#define NHOPS   3
#define NG      2048
#define H       128
#define EMBD    64
#define NL      3
#define NMLP    2
#define NHEADS  4
#define NROWS   (NHOPS * NN)   // 150000
#define NBUK    (NROWS / 16)   // 9375 buckets of 16 rows
#define SCAN_B  256
#define NB1     ((NROWS + SCAN_B - 1) / SCAN_B)
#define LSTR    136

typedef __bf16 bf16x8 __attribute__((ext_vector_type(8)));
typedef __bf16 bf16x4 __attribute__((ext_vector_type(4)));
typedef float  f32x4  __attribute__((ext_vector_type(4)));

__device__ __forceinline__ float silu_f(float v) { return v / (1.0f + expf(-v)); }

__device__ __forceinline__ f32x4 mm(bf16x8 a, bf16x8 b, f32x4 c) {
    return __builtin_amdgcn_mfma_f32_16x16x32_bf16(a, b, c, 0, 0, 0);
}

__device__ __forceinline__ float blo(unsigned v) { return __builtin_bit_cast(float, v << 16); }
__device__ __forceinline__ float bhi(unsigned v) { return __builtin_bit_cast(float, v & 0xffff0000u); }

// ---------------------------------------------------------------- weight pack
__global__ __launch_bounds__(256) void k_packw(
    const float* __restrict__ W, __bf16* __restrict__ out, int K, int nmat)
{
    long tid = (long)blockIdx.x * 256 + threadIdx.x;
    long per = (long)K * 128;
    if (tid >= per * nmat) return;
    long mat = tid / per, e = tid - mat * per;
    int j = (int)(e & 7), n16 = (int)((e >> 3) & 15), q = (int)((e >> 7) & 3),
        mt = (int)((e >> 9) & 7), kt = (int)(e >> 12);
    int k = kt * 32 + q * 8 + j, n = mt * 16 + n16;
    out[tid] = (__bf16)W[mat * per + (long)k * 128 + n];
}

__global__ __launch_bounds__(256) void k_cvt_emb(
    const float* __restrict__ Ea, const float* __restrict__ Eh,
    const float* __restrict__ Ed, const float* __restrict__ Ey,
    __bf16* __restrict__ out)
{
    int t = blockIdx.x * 256 + threadIdx.x;
    if (t >= 8000) return;
    float v;
    if (t < 6400) v = Ea[t];
    else if (t < 6976) v = Eh[t - 6400];
    else if (t < 7488) v = Ed[t - 6976];
    else v = Ey[t - 7488];
    out[t] = (__bf16)v;
}

// ---------------------------------------------------------------- K0: embed + project + silu (MFMA)
__global__ __launch_bounds__(256) void k_embed_m(
    const int* __restrict__ atom, const int* __restrict__ hc,
    const int* __restrict__ deg,  const int* __restrict__ hyb,
    const __bf16* __restrict__ emb, const __bf16* __restrict__ pw,
    const float* __restrict__ pb, __bf16* __restrict__ x)
{
    const int lane = threadIdx.x & 63, wid = threadIdx.x >> 6;
    const int q = lane >> 4, l16 = lane & 15;
    const int nb = blockIdx.x * 128 + wid * 32;
    int ia[2][4];
#pragma unroll
    for (int nt = 0; nt < 2; ++nt) {
        int n = nb + nt * 16 + l16;
        if (n >= NN) n = NN - 1;
        ia[nt][0] = atom[n]; ia[nt][1] = hc[n]; ia[nt][2] = deg[n]; ia[nt][3] = hyb[n];
    }
    f32x4 acc[2][8];
#pragma unroll
    for (int nt = 0; nt < 2; ++nt)
#pragma unroll
        for (int mt = 0; mt < 8; ++mt) acc[nt][mt] = (f32x4)(0.f);
    const int tb[4] = {0, 6400, 6976, 7488};
    for (int kt = 0; kt < 8; ++kt) {
        int t = kt >> 1;
        int koff = (kt & 1) * 32 + q * 8;
        bf16x8 bfrag[2];
#pragma unroll
        for (int nt = 0; nt < 2; ++nt)
            bfrag[nt] = *(const bf16x8*)(emb + tb[t] + (long)ia[nt][t] * 64 + koff);
        const __bf16* ap = pw + (long)kt * 4096 + lane * 8;
#pragma unroll
        for (int mt = 0; mt < 8; ++mt) {
            bf16x8 a = *(const bf16x8*)(ap + mt * 512);
            acc[0][mt] = mm(a, bfrag[0], acc[0][mt]);
            acc[1][mt] = mm(a, bfrag[1], acc[1][mt]);
        }
    }
#pragma unroll
    for (int nt = 0; nt < 2; ++nt) {
        long node = nb + nt * 16 + l16;
#pragma unroll
        for (int mt = 0; mt < 8; ++mt) {
            int ch = mt * 16 + q * 4;
            float4 bb = *(const float4*)(pb + ch);
            bf16x4 o;
            o[0] = (__bf16)silu_f(acc[nt][mt][0] + bb.x);
            o[1] = (__bf16)silu_f(acc[nt][mt][1] + bb.y);
            o[2] = (__bf16)silu_f(acc[nt][mt][2] + bb.z);
            o[3] = (__bf16)silu_f(acc[nt][mt][3] + bb.w);
            *(bf16x4*)(x + node * 128 + ch) = o;
        }
    }
}

// ---------------------------------------------------------------- CSR build
__global__ __launch_bounds__(256) void k_hist(
    const int* __restrict__ target, int* __restrict__ counts)
{
    int e = blockIdx.x * 256 + threadIdx.x;
    if (e >= NE) return;
    atomicAdd(&counts[target[e]], 1);
}

__global__ __launch_bounds__(SCAN_B) void k_scan1(
    const int* __restrict__ counts, int* __restrict__ csr_start,
    int* __restrict__ blocksums)
{
    __shared__ int s[SCAN_B];
    int tid = threadIdx.x;
    int i = blockIdx.x * SCAN_B + tid;
    int v = (i < NROWS) ? counts[i] : 0;
    s[tid] = v;
    __syncthreads();
    for (int off = 1; off < SCAN_B; off <<= 1) {
        int t = (tid >= off) ? s[tid - off] : 0;
        __syncthreads();
        s[tid] += t;
        __syncthreads();
    }
    if (i < NROWS) csr_start[i] = s[tid] - v;
    if (tid == SCAN_B - 1) blocksums[blockIdx.x] = s[tid];
}

__global__ __launch_bounds__(1024) void k_scan2(int* __restrict__ blocksums)
{
    __shared__ int s[1024];
    int tid = threadIdx.x;
    int v = (tid < NB1) ? blocksums[tid] : 0;
    s[tid] = v;
    __syncthreads();
    for (int off = 1; off < 1024; off <<= 1) {
        int t = (tid >= off) ? s[tid - off] : 0;
        __syncthreads();
        s[tid] += t;
        __syncthreads();
    }
    if (tid < NB1) blocksums[tid] = s[tid] - v;
}

// apply block offsets; also init bucket cursors (bucket b starts at csr_start[16b])
__global__ __launch_bounds__(256) void k_scan3(
    int* __restrict__ csr_start, const int* __restrict__ blocksums,
    int* __restrict__ bcursor)
{
    int i = blockIdx.x * 256 + threadIdx.x;
    if (i < NROWS) {
        int v = csr_start[i] + blocksums[i / SCAN_B];
        csr_start[i] = v;
        if ((i & 15) == 0) bcursor[i >> 4] = v;
    }
    if (i == 0) csr_start[NROWS] = NE;
}

// phase A: scatter edges into 16-row bucket regions (hot tail-lines fit L2)
__global__ __launch_bounds__(256) void k_fillb(
    const int* __restrict__ target, const int* __restrict__ src,
    int* __restrict__ bcursor, unsigned int* __restrict__ packed)
{
    int e = blockIdx.x * 256 + threadIdx.x;
    if (e >= NE) return;
    int s = src[e];
    if (s >= 2 * NN) s -= 2 * NN; else if (s >= NN) s -= NN;
    int t = target[e];
    int pos = atomicAdd(&bcursor[t >> 4], 1);
    packed[pos] = (unsigned)s | ((unsigned)(t & 15) << 16);
}

// phase B: one block per bucket -> rank with LDS cursors, write target-sorted ushort esrc
__global__ __launch_bounds__(256) void k_fill2(
    const unsigned int* __restrict__ packed, const int* __restrict__ csr_start,
    unsigned short* __restrict__ esrc)
{
    __shared__ int cur[16];
    int b = blockIdx.x;
    int s0 = csr_start[b * 16], s1 = csr_start[b * 16 + 16];
    if (threadIdx.x < 16) cur[threadIdx.x] = csr_start[b * 16 + threadIdx.x];
    __syncthreads();
    for (int e = s0 + threadIdx.x; e < s1; e += 256) {
        unsigned p = packed[e];
        int tlow = (p >> 16) & 15;
        int pos = atomicAdd(&cur[tlow], 1);
        esrc[pos] = (unsigned short)(p & 0xffffu);
    }
}

// ---------------------------------------------------------------- K1: CSR gather, 2 rows/wave, shfl-broadcast indices
__global__ __launch_bounds__(256) void k_gather(
    const unsigned short* __restrict__ esrc, const int* __restrict__ csr_start,
    const uint2* __restrict__ x4, uint2* __restrict__ agg4)
{
    int pair = blockIdx.x * 4 + (threadIdx.x >> 6);   // 75000 pairs total
    int lane = threadIdx.x & 63;
    int half = lane >> 5, l5 = lane & 31;
    int row = pair * 2 + half;
    int e0 = csr_start[row], e1 = csr_start[row + 1];
    int nch = (e1 - e0 + 31) >> 5;
    int nA = __shfl(nch, 0, 64);
    int nB = __shfl(nch, 32, 64);
    int nmax = nA > nB ? nA : nB;
    float a0 = 0.f, a1 = 0.f, a2 = 0.f, a3 = 0.f;
    for (int c = 0; c < nmax; ++c) {
        int base = e0 + c * 32;
        int rem = e1 - base;                      // uniform per half
        int pre = (l5 < rem) ? (int)esrc[base + l5] : 0;
        int m = rem < 32 ? (rem < 0 ? 0 : rem) : 32;
        int sb = half << 5;
        int j = 0;
        for (; j + 1 < m; j += 2) {
            int sA = __shfl(pre, sb + j, 64);
            int sB = __shfl(pre, sb + j + 1, 64);
            uint2 v0 = x4[(long)sA * 32 + l5];
            uint2 v1 = x4[(long)sB * 32 + l5];
            a0 += blo(v0.x) + blo(v1.x);
            a1 += bhi(v0.x) + bhi(v1.x);
            a2 += blo(v0.y) + blo(v1.y);
            a3 += bhi(v0.y) + bhi(v1.y);
        }
        if (j < m) {
            int sA = __shfl(pre, sb + j, 64);
            uint2 v0 = x4[(long)sA * 32 + l5];
            a0 += blo(v0.x); a1 += bhi(v0.x);
            a2 += blo(v0.y); a3 += bhi(v0.y);
        }
    }
    int hop = row / NN, node = row - hop * NN;
    unsigned short u0 = __builtin_bit_cast(unsigned short, (__bf16)a0);
    unsigned short u1 = __builtin_bit_cast(unsigned short, (__bf16)a1);
    unsigned short u2 = __builtin_bit_cast(unsigned short, (__bf16)a2);
    unsigned short u3 = __builtin_bit_cast(unsigned short, (__bf16)a3);
    uint2 o;
    o.x = (unsigned)u0 | ((unsigned)u1 << 16);
    o.y = (unsigned)u2 | ((unsigned)u3 << 16);
    agg4[((long)hop * NNP + node) * 32 + l5] = o;
}

// ---------------------------------------------------------------- K2: shell_in + skip (MFMA, K=512)
__global__ __launch_bounds__(256) void k_shell_m(
    const __bf16* __restrict__ x, const __bf16* __restrict__ agg,
    const __bf16* __restrict__ pwin, const float* __restrict__ bin,
    const __bf16* __restrict__ pwsk, const float* __restrict__ bsk,
    __bf16* __restrict__ h, __bf16* __restrict__ gskip)
{
    const int lane = threadIdx.x & 63, wid = threadIdx.x >> 6;
    const int q = lane >> 4, l16 = lane & 15;
    const int nb = blockIdx.x * 128 + wid * 32;
    f32x4 aci[2][8], acs[2][8];
#pragma unroll
    for (int nt = 0; nt < 2; ++nt)
#pragma unroll
        for (int mt = 0; mt < 8; ++mt) { aci[nt][mt] = (f32x4)(0.f); acs[nt][mt] = (f32x4)(0.f); }
    const __bf16* planes[4] = {x, agg, agg + (long)NNP * 128, agg + 2L * NNP * 128};
    for (int kt = 0; kt < 16; ++kt) {
        const __bf16* src = planes[kt >> 2];
        int koff = (kt & 3) * 32 + q * 8;
        bf16x8 bfrag[2];
#pragma unroll
        for (int nt = 0; nt < 2; ++nt)
            bfrag[nt] = *(const bf16x8*)(src + (long)(nb + nt * 16 + l16) * 128 + koff);
        const __bf16* aip = pwin + (long)kt * 4096 + lane * 8;
        const __bf16* asp = pwsk + (long)kt * 4096 + lane * 8;
#pragma unroll
        for (int mt = 0; mt < 8; ++mt) {
            bf16x8 ai = *(const bf16x8*)(aip + mt * 512);
            bf16x8 as = *(const bf16x8*)(asp + mt * 512);
            aci[0][mt] = mm(ai, bfrag[0], aci[0][mt]);
            aci[1][mt] = mm(ai, bfrag[1], aci[1][mt]);
            acs[0][mt] = mm(as, bfrag[0], acs[0][mt]);
            acs[1][mt] = mm(as, bfrag[1], acs[1][mt]);
        }
    }
#pragma unroll
    for (int nt = 0; nt < 2; ++nt) {
        long node = nb + nt * 16 + l16;
#pragma unroll
        for (int mt = 0; mt < 8; ++mt) {
            int ch = mt * 16 + q * 4;
            float4 bi = *(const float4*)(bin + ch);
            float4 bs = *(const float4*)(bsk + ch);
            bf16x4 oh, og;
            oh[0] = (__bf16)silu_f(aci[nt][mt][0] + bi.x); og[0] = (__bf16)(acs[nt][mt][0] + bs.x);
            oh[1] = (__bf16)silu_f(aci[nt][mt][1] + bi.y); og[1] = (__bf16)(acs[nt][mt][1] + bs.y);
            oh[2] = (__bf16)silu_f(aci[nt][mt][2] + bi.z); og[2] = (__bf16)(acs[nt][mt][2] + bs.z);
            oh[3] = (__bf16)silu_f(aci[nt][mt][3] + bi.w); og[3] = (__bf16)(acs[nt][mt][3] + bs.w);
            *(bf16x4*)(h + node * 128 + ch) = oh;
            *(bf16x4*)(gskip + node * 128 + ch) = og;
        }
    }
}

// ---------------------------------------------------------------- K3: fused residual MLP (MFMA)
__global__ __launch_bounds__(256) void k_mlp_m(
    const __bf16* __restrict__ hin,
    const __bf16* __restrict__ pw1, const float* __restrict__ b1,
    const __bf16* __restrict__ pw2, const float* __restrict__ b2,
    const __bf16* __restrict__ gskip, __bf16* __restrict__ hout)
{
    __shared__ __bf16 lds[4][32 * LSTR];
    const int lane = threadIdx.x & 63, wid = threadIdx.x >> 6;
    const int q = lane >> 4, l16 = lane & 15;
    const int nb = blockIdx.x * 128 + wid * 32;
    __bf16* L = lds[wid];
    f32x4 acc[2][8];
#pragma unroll
    for (int nt = 0; nt < 2; ++nt)
#pragma unroll
        for (int mt = 0; mt < 8; ++mt) acc[nt][mt] = (f32x4)(0.f);
    for (int kt = 0; kt < 4; ++kt) {
        int koff = kt * 32 + q * 8;
        bf16x8 bfrag[2];
#pragma unroll
        for (int nt = 0; nt < 2; ++nt)
            bfrag[nt] = *(const bf16x8*)(hin + (long)(nb + nt * 16 + l16) * 128 + koff);
        const __bf16* ap = pw1 + (long)kt * 4096 + lane * 8;
#pragma unroll
        for (int mt = 0; mt < 8; ++mt) {
            bf16x8 a = *(const bf16x8*)(ap + mt * 512);
            acc[0][mt] = mm(a, bfrag[0], acc[0][mt]);
            acc[1][mt] = mm(a, bfrag[1], acc[1][mt]);
        }
    }
#pragma unroll
    for (int nt = 0; nt < 2; ++nt) {
        int nl = nt * 16 + l16;
#pragma unroll
        for (int mt = 0; mt < 8; ++mt) {
            int ch = mt * 16 + q * 4;
            float4 bb = *(const float4*)(b1 + ch);
            bf16x4 o;
            o[0] = (__bf16)silu_f(acc[nt][mt][0] + bb.x);
            o[1] = (__bf16)silu_f(acc[nt][mt][1] + bb.y);
            o[2] = (__bf16)silu_f(acc[nt][mt][2] + bb.z);
            o[3] = (__bf16)silu_f(acc[nt][mt][3] + bb.w);
            *(bf16x4*)(L + nl * LSTR + ch) = o;
        }
    }
    __syncthreads();
    f32x4 ac2[2][8];
#pragma unroll
    for (int nt = 0; nt < 2; ++nt)
#pragma unroll
        for (int mt = 0; mt < 8; ++mt) ac2[nt][mt] = (f32x4)(0.f);
    for (int kt = 0; kt < 4; ++kt) {
        int koff = kt * 32 + q * 8;
        bf16x8 bfrag[2];
#pragma unroll
        for (int nt = 0; nt < 2; ++nt)
            bfrag[nt] = *(const bf16x8*)(L + (nt * 16 + l16) * LSTR + koff);
        const __bf16* ap = pw2 + (long)kt * 4096 + lane * 8;
#pragma unroll
        for (int mt = 0; mt < 8; ++mt) {
            bf16x8 a = *(const bf16x8*)(ap + mt * 512);
            ac2[0][mt] = mm(a, bfrag[0], ac2[0][mt]);
            ac2[1][mt] = mm(a, bfrag[1], ac2[1][mt]);
        }
    }
#pragma unroll
    for (int nt = 0; nt < 2; ++nt) {
        long node = nb + nt * 16 + l16;
#pragma unroll
        for (int mt = 0; mt < 8; ++mt) {
            int ch = mt * 16 + q * 4;
            float4 bb = *(const float4*)(b2 + ch);
            bf16x4 sk = *(const bf16x4*)(hin + node * 128 + ch);
            float v0 = ac2[nt][mt][0] + bb.x + (float)sk[0];
            float v1 = ac2[nt][mt][1] + bb.y + (float)sk[1];
            float v2 = ac2[nt][mt][2] + bb.z + (float)sk[2];
            float v3 = ac2[nt][mt][3] + bb.w + (float)sk[3];
            if (gskip) {
                bf16x4 g = *(const bf16x4*)(gskip + node * 128 + ch);
                v0 += (float)g[0]; v1 += (float)g[1]; v2 += (float)g[2]; v3 += (float)g[3];
            }
            bf16x4 o;
            o[0] = (__bf16)v0; o[1] = (__bf16)v1; o[2] = (__bf16)v2; o[3] = (__bf16)v3;
            *(bf16x4*)(hout + node * 128 + ch) = o;
        }
    }
}

// ---------------------------------------------------------------- K4: attention scores
__global__ __launch_bounds__(256) void k_scores(
    const __bf16* __restrict__ x, const float* __restrict__ aw,
    const float* __restrict__ ab, const float* __restrict__ temp,
    float* __restrict__ scores)
{
    int wave = threadIdx.x >> 6, lane = threadIdx.x & 63;
    int n = blockIdx.x * 4 + wave;
    if (n >= NN) return;
    float x0 = (float)x[(long)n * H + lane];
    float x1 = (float)x[(long)n * H + 64 + lane];
    float T = temp[0];
#pragma unroll
    for (int hh = 0; hh < NHEADS; ++hh) {
        float p = x0 * aw[hh * H + lane] + x1 * aw[hh * H + 64 + lane];
#pragma unroll
        for (int off = 32; off >= 1; off >>= 1) p += __shfl_xor(p, off, 64);
        if (lane == 0) scores[n * NHEADS + hh] = (p + ab[hh]) / T;
    }
}

// ---------------------------------------------------------------- K5: graph offsets
__global__ __launch_bounds__(256) void k_offsets(
    const int* __restrict__ batch, int* __restrict__ gstart)
{
    int n = blockIdx.x * 256 + threadIdx.x;
    if (n >= NN) return;
    int b = batch[n];
    int bp = (n == 0) ? -1 : batch[n - 1];
    for (int g = bp + 1; g <= b; ++g) gstart[g] = n;
    if (n == NN - 1) for (int g = b + 1; g <= NG; ++g) gstart[g] = NN;
}

// ---------------------------------------------------------------- K6: softmax pool
__global__ __launch_bounds__(64) void k_pool(
    const __bf16* __restrict__ x, const float* __restrict__ scores,
    const int* __restrict__ gstart, float* __restrict__ pooled)
{
    int g = blockIdx.x, lane = threadIdx.x;
    int s0 = gstart[g], s1 = gstart[g + 1];
    float m0 = -INFINITY, m1 = -INFINITY, m2 = -INFINITY, m3 = -INFINITY;
    for (int n = s0 + lane; n < s1; n += 64) {
        m0 = fmaxf(m0, scores[n * 4 + 0]); m1 = fmaxf(m1, scores[n * 4 + 1]);
        m2 = fmaxf(m2, scores[n * 4 + 2]); m3 = fmaxf(m3, scores[n * 4 + 3]);
    }
#pragma unroll
    for (int off = 32; off >= 1; off >>= 1) {
        m0 = fmaxf(m0, __shfl_xor(m0, off, 64)); m1 = fmaxf(m1, __shfl_xor(m1, off, 64));
        m2 = fmaxf(m2, __shfl_xor(m2, off, 64)); m3 = fmaxf(m3, __shfl_xor(m3, off, 64));
    }
    float d0 = 0.f, d1 = 0.f, d2 = 0.f, d3 = 0.f;
    for (int n = s0 + lane; n < s1; n += 64) {
        d0 += expf(scores[n * 4 + 0] - m0); d1 += expf(scores[n * 4 + 1] - m1);
        d2 += expf(scores[n * 4 + 2] - m2); d3 += expf(scores[n * 4 + 3] - m3);
    }
#pragma unroll
    for (int off = 32; off >= 1; off >>= 1) {
        d0 += __shfl_xor(d0, off, 64); d1 += __shfl_xor(d1, off, 64);
        d2 += __shfl_xor(d2, off, 64); d3 += __shfl_xor(d3, off, 64);
    }
    float i0 = d0 > 0.f ? 1.f / d0 : 0.f;
    float i1 = d1 > 0.f ? 1.f / d1 : 0.f;
    float i2 = d2 > 0.f ? 1.f / d2 : 0.f;
    float i3 = d3 > 0.f ? 1.f / d3 : 0.f;
    float a0 = 0.f, a1 = 0.f;
    for (int n = s0; n < s1; ++n) {
        float wb = expf(scores[n * 4 + 0] - m0) * i0 + expf(scores[n * 4 + 1] - m1) * i1
                 + expf(scores[n * 4 + 2] - m2) * i2 + expf(scores[n * 4 + 3] - m3) * i3;
        wb *= 0.25f;
        a0 += wb * (float)x[(long)n * H + lane];
        a1 += wb * (float)x[(long)n * H + 64 + lane];
    }
    pooled[g * H + lane] = a0;
    pooled[g * H + 64 + lane] = a1;
}

// ---------------------------------------------------------------- K7: FFN readout
__global__ __launch_bounds__(128) void k_ffn(
    const float* __restrict__ pooled,
    const float* __restrict__ W1, const float* __restrict__ B1,
    const float* __restrict__ W2, const float* __restrict__ B2,
    const float* __restrict__ W3, const float* __restrict__ B3,
    float* __restrict__ out)
{
    __shared__ float p[H], t1[H], t2[H], red[H];
    int g = blockIdx.x, c = threadIdx.x;
    p[c] = pooled[g * H + c];
    __syncthreads();
    float acc = 0.f;
    for (int k = 0; k < H; ++k) acc += p[k] * W1[k * H + c];
    t1[c] = silu_f(acc + B1[c]);
    __syncthreads();
    acc = 0.f;
    for (int k = 0; k < H; ++k) acc += t1[k] * W2[k * H + c];
    t2[c] = silu_f(acc + B2[c]);
    __syncthreads();
    red[c] = t2[c] * W3[c];
    __syncthreads();
    for (int off = 64; off >= 1; off >>= 1) {
        if (c < off) red[c] += red[c + off];
        __syncthreads();
    }
    if (c == 0) out[g] = red[0] + B3[0];
}

// ---------------------------------------------------------------- launch
extern "C" void kernel_launch(void* const* d_in, const int* in_sizes, int n_in,
                              void* d_out, int out_size, void* d_ws, size_t ws_size,
                              hipStream_t stream)
{
    const int*   atom   = (const int*)d_in[0];
    const int*   hc     = (const int*)d_in[1];
    const int*   deg    = (const int*)d_in[2];
    const int*   hyb    = (const int*)d_in[3];
    const int*   target = (const int*)d_in[4];
    const int*   src    = (const int*)d_in[5];
    const int*   batch  = (const int*)d_in[6];
    const float* Ea     = (const float*)d_in[7];
    const float* Eh     = (const float*)d_in[8];
    const float* Ed     = (const float*)d_in[9];
    const float* Ey     = (const float*)d_in[10];
    const float* projW  = (const float*)d_in[11];
    const float* projB  = (const float*)d_in[12];
    const float* sInW   = (const float*)d_in[13];
    const float* sInB   = (const float*)d_in[14];
    const float* mW1    = (const float*)d_in[15];
    const float* mB1    = (const float*)d_in[16];
    const float* mW2    = (const float*)d_in[17];
    const float* mB2    = (const float*)d_in[18];
    const float* sSkW   = (const float*)d_in[19];
    const float* sSkB   = (const float*)d_in[20];
    const float* attnW  = (const float*)d_in[21];
    const float* attnB  = (const float*)d_in[22];
    const float* temp   = (const float*)d_in[23];
    const float* fW1    = (const float*)d_in[24];
    const float* fB1    = (const float*)d_in[25];
    const float* fW2    = (const float*)d_in[26];
    const float* fB2    = (const float*)d_in[27];
    const float* fW3    = (const float*)d_in[28];
    const float* fB3    = (const float*)d_in[29];
    float* out = (float*)d_out;

    char* w = (char*)d_ws;
    auto take = [&](size_t bytes) { void* p = (void*)w; w += (bytes + 255) & ~(size_t)255; return p; };
    __bf16* x      = (__bf16*)take(2L * NNP * H);
    __bf16* agg    = (__bf16*)take(2L * 3 * NNP * H);
    __bf16* hbuf   = (__bf16*)take(2L * NNP * H);
    __bf16* hbuf2  = (__bf16*)take(2L * NNP * H);
    __bf16* gskip  = (__bf16*)take(2L * NNP * H);
    __bf16* pproj  = (__bf16*)take(2L * 256 * H);
    __bf16* pin    = (__bf16*)take(2L * 3 * 512 * H);
    __bf16* psk    = (__bf16*)take(2L * 3 * 512 * H);
    __bf16* pw1    = (__bf16*)take(2L * 6 * 128 * H);
    __bf16* pw2    = (__bf16*)take(2L * 6 * 128 * H);
    __bf16* embb   = (__bf16*)take(2L * 8000);
    float*  scores = (float*)take(4L * NN * NHEADS);
    float*  pooled = (float*)take(4L * NG * H);
    int*    gstart = (int*)take(4L * (NG + 1));
    int*    counts = (int*)take(4L * NROWS);
    int*    csr_start = (int*)take(4L * (NROWS + 1));
    unsigned int*   packed = (unsigned int*)take(4L * NE);
    unsigned short* esrc   = (unsigned short*)take(2L * NE);
    int*    bcursor = (int*)take(4L * NBUK);
    int*    blocksums = (int*)take(4L * 1024);

    // ---- weight packing (weights restored each call -> pack each call) ----
    k_packw<<<(1 * 256 * 128) / 256, 256, 0, stream>>>(projW, pproj, 256, 1);
    k_packw<<<(3 * 512 * 128) / 256, 256, 0, stream>>>(sInW, pin, 512, 3);
    k_packw<<<(3 * 512 * 128) / 256, 256, 0, stream>>>(sSkW, psk, 512, 3);
    k_packw<<<(6 * 128 * 128) / 256, 256, 0, stream>>>(mW1, pw1, 128, 6);
    k_packw<<<(6 * 128 * 128) / 256, 256, 0, stream>>>(mW2, pw2, 128, 6);
    k_cvt_emb<<<32, 256, 0, stream>>>(Ea, Eh, Ed, Ey, embb);

    // ---- CSR build: hist -> scan -> bucket scatter -> in-bucket rank ----
    hipMemsetAsync(counts, 0, sizeof(int) * NROWS, stream);
    k_hist<<<(NE + 255) / 256, 256, 0, stream>>>(target, counts);
    k_scan1<<<NB1, SCAN_B, 0, stream>>>(counts, csr_start, blocksums);
    k_scan2<<<1, 1024, 0, stream>>>(blocksums);
    k_scan3<<<(NROWS + 255) / 256, 256, 0, stream>>>(csr_start, blocksums, bcursor);
    k_fillb<<<(NE + 255) / 256, 256, 0, stream>>>(target, src, bcursor, packed);
    k_fill2<<<NBUK, 256, 0, stream>>>(packed, csr_start, esrc);

    k_embed_m<<<NNP / 128, 256, 0, stream>>>(atom, hc, deg, hyb, embb, pproj, projB, x);
    k_offsets<<<(NN + 255) / 256, 256, 0, stream>>>(batch, gstart);

    for (int l = 0; l < NL; ++l) {
        k_gather<<<NROWS / 8, 256, 0, stream>>>(esrc, csr_start,
            (const uint2*)x, (uint2*)agg);
        k_shell_m<<<NNP / 128, 256, 0, stream>>>(x, agg,
            pin + (long)l * 512 * H, sInB + l * H,
            psk + (long)l * 512 * H, sSkB + l * H, hbuf, gskip);
        k_mlp_m<<<NNP / 128, 256, 0, stream>>>(hbuf,
            pw1 + (long)(l * NMLP + 0) * 128 * H, mB1 + (long)(l * NMLP + 0) * H,
            pw2 + (long)(l * NMLP + 0) * 128 * H, mB2 + (long)(l * NMLP + 0) * H,
            nullptr, hbuf2);
        k_mlp_m<<<NNP / 128, 256, 0, stream>>>(hbuf2,
            pw1 + (long)(l * NMLP + 1) * 128 * H, mB1 + (long)(l * NMLP + 1) * H,
            pw2 + (long)(l * NMLP + 1) * 128 * H, mB2 + (long)(l * NMLP + 1) * H,
            gskip, x);
    }

    k_scores<<<NN / 4, 256, 0, stream>>>(x, attnW, attnB, temp, scores);
    k_pool<<<NG, 64, 0, stream>>>(x, scores, gstart, pooled);
    k_ffn<<<NG, 128, 0, stream>>>(pooled, fW1, fB1, fW2, fB2, fW3, fB3, out);
}

// Round 5
// 967.067 us; speedup vs baseline: 14.0397x; 1.1180x over previous
//
#include <hip/hip_runtime.h>
#include <math.h>

#define NN      50000
#define NNP     50048          // padded nodes = 391*128
#define NE      2400000
#define NHOPS   3
#define NG      2048
#define H       128
#define EMBD    64
#define NL      3
#define NMLP    2
#define NHEADS  4
#define NROWS   (NHOPS * NN)   // 150000
#define NBUK    (NROWS / 16)   // 9375 buckets of 16 rows
#define NPART   8              // one partition per XCD slot (blockIdx & 7)
#define CAP     128            // per partition-bucket capacity (Poisson mean 32)
#define LSTR    136

typedef __bf16 bf16x8 __attribute__((ext_vector_type(8)));
typedef __bf16 bf16x4 __attribute__((ext_vector_type(4)));
typedef float  f32x4  __attribute__((ext_vector_type(4)));

__device__ __forceinline__ float silu_f(float v) { return v / (1.0f + expf(-v)); }

__device__ __forceinline__ f32x4 mm(bf16x8 a, bf16x8 b, f32x4 c) {
    return __builtin_amdgcn_mfma_f32_16x16x32_bf16(a, b, c, 0, 0, 0);
}

__device__ __forceinline__ float blo(unsigned v) { return __builtin_bit_cast(float, v << 16); }
__device__ __forceinline__ float bhi(unsigned v) { return __builtin_bit_cast(float, v & 0xffff0000u); }

// ---------------------------------------------------------------- weight pack
__global__ __launch_bounds__(256) void k_packw(
    const float* __restrict__ W, __bf16* __restrict__ out, int K, int nmat)
{
    long tid = (long)blockIdx.x * 256 + threadIdx.x;
    long per = (long)K * 128;
    if (tid >= per * nmat) return;
    long mat = tid / per, e = tid - mat * per;
    int j = (int)(e & 7), n16 = (int)((e >> 3) & 15), q = (int)((e >> 7) & 3),
        mt = (int)((e >> 9) & 7), kt = (int)(e >> 12);
    int k = kt * 32 + q * 8 + j, n = mt * 16 + n16;
    out[tid] = (__bf16)W[mat * per + (long)k * 128 + n];
}

__global__ __launch_bounds__(256) void k_cvt_emb(
    const float* __restrict__ Ea, const float* __restrict__ Eh,
    const float* __restrict__ Ed, const float* __restrict__ Ey,
    __bf16* __restrict__ out)
{
    int t = blockIdx.x * 256 + threadIdx.x;
    if (t >= 8000) return;
    float v;
    if (t < 6400) v = Ea[t];
    else if (t < 6976) v = Eh[t - 6400];
    else if (t < 7488) v = Ed[t - 6976];
    else v = Ey[t - 7488];
    out[t] = (__bf16)v;
}

// ---------------------------------------------------------------- K0: embed + project + silu (MFMA)
__global__ __launch_bounds__(256) void k_embed_m(
    const int* __restrict__ atom, const int* __restrict__ hc,
    const int* __restrict__ deg,  const int* __restrict__ hyb,
    const __bf16* __restrict__ emb, const __bf16* __restrict__ pw,
    const float* __restrict__ pb, __bf16* __restrict__ x)
{
    const int lane = threadIdx.x & 63, wid = threadIdx.x >> 6;
    const int q = lane >> 4, l16 = lane & 15;
    const int nb = blockIdx.x * 128 + wid * 32;
    int ia[2][4];
#pragma unroll
    for (int nt = 0; nt < 2; ++nt) {
        int n = nb + nt * 16 + l16;
        if (n >= NN) n = NN - 1;
        ia[nt][0] = atom[n]; ia[nt][1] = hc[n]; ia[nt][2] = deg[n]; ia[nt][3] = hyb[n];
    }
    f32x4 acc[2][8];
#pragma unroll
    for (int nt = 0; nt < 2; ++nt)
#pragma unroll
        for (int mt = 0; mt < 8; ++mt) acc[nt][mt] = (f32x4)(0.f);
    const int tb[4] = {0, 6400, 6976, 7488};
    for (int kt = 0; kt < 8; ++kt) {
        int t = kt >> 1;
        int koff = (kt & 1) * 32 + q * 8;
        bf16x8 bfrag[2];
#pragma unroll
        for (int nt = 0; nt < 2; ++nt)
            bfrag[nt] = *(const bf16x8*)(emb + tb[t] + (long)ia[nt][t] * 64 + koff);
        const __bf16* ap = pw + (long)kt * 4096 + lane * 8;
#pragma unroll
        for (int mt = 0; mt < 8; ++mt) {
            bf16x8 a = *(const bf16x8*)(ap + mt * 512);
            acc[0][mt] = mm(a, bfrag[0], acc[0][mt]);
            acc[1][mt] = mm(a, bfrag[1], acc[1][mt]);
        }
    }
#pragma unroll
    for (int nt = 0; nt < 2; ++nt) {
        long node = nb + nt * 16 + l16;
#pragma unroll
        for (int mt = 0; mt < 8; ++mt) {
            int ch = mt * 16 + q * 4;
            float4 bb = *(const float4*)(pb + ch);
            bf16x4 o;
            o[0] = (__bf16)silu_f(acc[nt][mt][0] + bb.x);
            o[1] = (__bf16)silu_f(acc[nt][mt][1] + bb.y);
            o[2] = (__bf16)silu_f(acc[nt][mt][2] + bb.z);
            o[3] = (__bf16)silu_f(acc[nt][mt][3] + bb.w);
            *(bf16x4*)(x + node * 128 + ch) = o;
        }
    }
}

// ---------------------------------------------------------------- CSR build, XCD-partitioned
// phase A: scatter edges into per-partition per-bucket segments.
// partition = blockIdx & 7 -> all writers of a segment share an XCD slot,
// so dirty lines live in ONE L2 and evict full (write amp ~1x).
__global__ __launch_bounds__(256) void k_fillp(
    const int* __restrict__ target, const int* __restrict__ src,
    int* __restrict__ pcursor, unsigned int* __restrict__ packedP)
{
    int p = blockIdx.x & (NPART - 1);
    for (int e = blockIdx.x * 256 + threadIdx.x; e < NE; e += gridDim.x * 256) {
        int s = src[e];
        if (s >= 2 * NN) s -= 2 * NN; else if (s >= NN) s -= NN;
        int t = target[e];
        int b = t >> 4;
        int cell = p * NBUK + b;
        int pos = atomicAdd(&pcursor[cell], 1);
        packedP[((long)cell << 7) + pos] = (unsigned)s | ((unsigned)(t & 15) << 16);
    }
}

// bucket totals + exclusive scan over 9375 buckets (single block)
__global__ __launch_bounds__(1024) void k_scanb(
    const int* __restrict__ pcursor, int* __restrict__ bbase)
{
    __shared__ int s[1024];
    __shared__ int carry;
    int tid = threadIdx.x;
    if (tid == 0) carry = 0;
    __syncthreads();
    const int nch = (NBUK + 1023) / 1024;
    for (int c = 0; c < nch; ++c) {
        int i = c * 1024 + tid;
        int v = 0;
        if (i < NBUK)
#pragma unroll
            for (int p = 0; p < NPART; ++p) v += pcursor[p * NBUK + i];
        s[tid] = v;
        __syncthreads();
        for (int off = 1; off < 1024; off <<= 1) {
            int t = (tid >= off) ? s[tid - off] : 0;
            __syncthreads();
            s[tid] += t;
            __syncthreads();
        }
        if (i < NBUK) bbase[i] = s[tid] - v + carry;
        __syncthreads();
        if (tid == 0) carry += s[1023];
        __syncthreads();
    }
    if (tid == 0) bbase[NBUK] = NE;
}

// phase B: one block per bucket. Stage <=1024 edges in LDS, count 16 rows,
// local scan -> csr_start rows, rank, write target-sorted ushort esrc.
__global__ __launch_bounds__(256) void k_fill2p(
    const unsigned int* __restrict__ packedP, const int* __restrict__ pcursor,
    const int* __restrict__ bbase, int* __restrict__ csr_start,
    unsigned short* __restrict__ esrc)
{
    __shared__ unsigned int stage[NPART * CAP];
    __shared__ int pbase[NPART + 1], rcnt[16], roff[16], cur[16];
    int b = blockIdx.x, tid = threadIdx.x;
    if (tid == 0) {
        int acc = 0;
#pragma unroll
        for (int p = 0; p < NPART; ++p) { pbase[p] = acc; acc += pcursor[p * NBUK + b]; }
        pbase[NPART] = acc;
    }
    if (tid < 16) rcnt[tid] = 0;
    __syncthreads();
#pragma unroll
    for (int p = 0; p < NPART; ++p) {
        int cnt = pbase[p + 1] - pbase[p];
        const unsigned int* seg = packedP + ((long)(p * NBUK + b) << 7);
        for (int i = tid; i < cnt; i += 256) stage[pbase[p] + i] = seg[i];
    }
    __syncthreads();
    int total = pbase[NPART];
    for (int i = tid; i < total; i += 256) atomicAdd(&rcnt[(stage[i] >> 16) & 15], 1);
    __syncthreads();
    if (tid == 0) {
        int acc = bbase[b];
#pragma unroll
        for (int r = 0; r < 16; ++r) { roff[r] = acc; cur[r] = acc; acc += rcnt[r]; }
    }
    __syncthreads();
    if (tid < 16) csr_start[b * 16 + tid] = roff[tid];
    if (b == 0 && tid == 0) csr_start[NROWS] = NE;
    for (int i = tid; i < total; i += 256) {
        unsigned pk = stage[i];
        int pos = atomicAdd(&cur[(pk >> 16) & 15], 1);
        esrc[pos] = (unsigned short)(pk & 0xffffu);
    }
}

// ---------------------------------------------------------------- K1: CSR gather, 2 rows/wave, shfl-broadcast indices
__global__ __launch_bounds__(256) void k_gather(
    const unsigned short* __restrict__ esrc, const int* __restrict__ csr_start,
    const uint2* __restrict__ x4, uint2* __restrict__ agg4)
{
    int pair = blockIdx.x * 4 + (threadIdx.x >> 6);
    int lane = threadIdx.x & 63;
    int half = lane >> 5, l5 = lane & 31;
    int row = pair * 2 + half;
    int e0 = csr_start[row], e1 = csr_start[row + 1];
    int nch = (e1 - e0 + 31) >> 5;
    int nA = __shfl(nch, 0, 64);
    int nB = __shfl(nch, 32, 64);
    int nmax = nA > nB ? nA : nB;
    float a0 = 0.f, a1 = 0.f, a2 = 0.f, a3 = 0.f;
    for (int c = 0; c < nmax; ++c) {
        int base = e0 + c * 32;
        int rem = e1 - base;
        int pre = (l5 < rem) ? (int)esrc[base + l5] : 0;
        int m = rem < 32 ? (rem < 0 ? 0 : rem) : 32;
        int sb = half << 5;
        int j = 0;
        for (; j + 1 < m; j += 2) {
            int sA = __shfl(pre, sb + j, 64);
            int sB = __shfl(pre, sb + j + 1, 64);
            uint2 v0 = x4[(long)sA * 32 + l5];
            uint2 v1 = x4[(long)sB * 32 + l5];
            a0 += blo(v0.x) + blo(v1.x);
            a1 += bhi(v0.x) + bhi(v1.x);
            a2 += blo(v0.y) + blo(v1.y);
            a3 += bhi(v0.y) + bhi(v1.y);
        }
        if (j < m) {
            int sA = __shfl(pre, sb + j, 64);
            uint2 v0 = x4[(long)sA * 32 + l5];
            a0 += blo(v0.x); a1 += bhi(v0.x);
            a2 += blo(v0.y); a3 += bhi(v0.y);
        }
    }
    int hop = row / NN, node = row - hop * NN;
    unsigned short u0 = __builtin_bit_cast(unsigned short, (__bf16)a0);
    unsigned short u1 = __builtin_bit_cast(unsigned short, (__bf16)a1);
    unsigned short u2 = __builtin_bit_cast(unsigned short, (__bf16)a2);
    unsigned short u3 = __builtin_bit_cast(unsigned short, (__bf16)a3);
    uint2 o;
    o.x = (unsigned)u0 | ((unsigned)u1 << 16);
    o.y = (unsigned)u2 | ((unsigned)u3 << 16);
    agg4[((long)hop * NNP + node) * 32 + l5] = o;
}

// ---------------------------------------------------------------- K2: shell_in + skip (MFMA, K=512)
__global__ __launch_bounds__(256) void k_shell_m(
    const __bf16* __restrict__ x, const __bf16* __restrict__ agg,
    const __bf16* __restrict__ pwin, const float* __restrict__ bin,
    const __bf16* __restrict__ pwsk, const float* __restrict__ bsk,
    __bf16* __restrict__ h, __bf16* __restrict__ gskip)
{
    const int lane = threadIdx.x & 63, wid = threadIdx.x >> 6;
    const int q = lane >> 4, l16 = lane & 15;
    const int nb = blockIdx.x * 128 + wid * 32;
    f32x4 aci[2][8], acs[2][8];
#pragma unroll
    for (int nt = 0; nt < 2; ++nt)
#pragma unroll
        for (int mt = 0; mt < 8; ++mt) { aci[nt][mt] = (f32x4)(0.f); acs[nt][mt] = (f32x4)(0.f); }
    const __bf16* planes[4] = {x, agg, agg + (long)NNP * 128, agg + 2L * NNP * 128};
    for (int kt = 0; kt < 16; ++kt) {
        const __bf16* src = planes[kt >> 2];
        int koff = (kt & 3) * 32 + q * 8;
        bf16x8 bfrag[2];
#pragma unroll
        for (int nt = 0; nt < 2; ++nt)
            bfrag[nt] = *(const bf16x8*)(src + (long)(nb + nt * 16 + l16) * 128 + koff);
        const __bf16* aip = pwin + (long)kt * 4096 + lane * 8;
        const __bf16* asp = pwsk + (long)kt * 4096 + lane * 8;
#pragma unroll
        for (int mt = 0; mt < 8; ++mt) {
            bf16x8 ai = *(const bf16x8*)(aip + mt * 512);
            bf16x8 as = *(const bf16x8*)(asp + mt * 512);
            aci[0][mt] = mm(ai, bfrag[0], aci[0][mt]);
            aci[1][mt] = mm(ai, bfrag[1], aci[1][mt]);
            acs[0][mt] = mm(as, bfrag[0], acs[0][mt]);
            acs[1][mt] = mm(as, bfrag[1], acs[1][mt]);
        }
    }
#pragma unroll
    for (int nt = 0; nt < 2; ++nt) {
        long node = nb + nt * 16 + l16;
#pragma unroll
        for (int mt = 0; mt < 8; ++mt) {
            int ch = mt * 16 + q * 4;
            float4 bi = *(const float4*)(bin + ch);
            float4 bs = *(const float4*)(bsk + ch);
            bf16x4 oh, og;
            oh[0] = (__bf16)silu_f(aci[nt][mt][0] + bi.x); og[0] = (__bf16)(acs[nt][mt][0] + bs.x);
            oh[1] = (__bf16)silu_f(aci[nt][mt][1] + bi.y); og[1] = (__bf16)(acs[nt][mt][1] + bs.y);
            oh[2] = (__bf16)silu_f(aci[nt][mt][2] + bi.z); og[2] = (__bf16)(acs[nt][mt][2] + bs.z);
            oh[3] = (__bf16)silu_f(aci[nt][mt][3] + bi.w); og[3] = (__bf16)(acs[nt][mt][3] + bs.w);
            *(bf16x4*)(h + node * 128 + ch) = oh;
            *(bf16x4*)(gskip + node * 128 + ch) = og;
        }
    }
}

// ---------------------------------------------------------------- K3: fused residual MLP (MFMA)
__global__ __launch_bounds__(256) void k_mlp_m(
    const __bf16* __restrict__ hin,
    const __bf16* __restrict__ pw1, const float* __restrict__ b1,
    const __bf16* __restrict__ pw2, const float* __restrict__ b2,
    const __bf16* __restrict__ gskip, __bf16* __restrict__ hout)
{
    __shared__ __bf16 lds[4][32 * LSTR];
    const int lane = threadIdx.x & 63, wid = threadIdx.x >> 6;
    const int q = lane >> 4, l16 = lane & 15;
    const int nb = blockIdx.x * 128 + wid * 32;
    __bf16* L = lds[wid];
    f32x4 acc[2][8];
#pragma unroll
    for (int nt = 0; nt < 2; ++nt)
#pragma unroll
        for (int mt = 0; mt < 8; ++mt) acc[nt][mt] = (f32x4)(0.f);
    for (int kt = 0; kt < 4; ++kt) {
        int koff = kt * 32 + q * 8;
        bf16x8 bfrag[2];
#pragma unroll
        for (int nt = 0; nt < 2; ++nt)
            bfrag[nt] = *(const bf16x8*)(hin + (long)(nb + nt * 16 + l16) * 128 + koff);
        const __bf16* ap = pw1 + (long)kt * 4096 + lane * 8;
#pragma unroll
        for (int mt = 0; mt < 8; ++mt) {
            bf16x8 a = *(const bf16x8*)(ap + mt * 512);
            acc[0][mt] = mm(a, bfrag[0], acc[0][mt]);
            acc[1][mt] = mm(a, bfrag[1], acc[1][mt]);
        }
    }
#pragma unroll
    for (int nt = 0; nt < 2; ++nt) {
        int nl = nt * 16 + l16;
#pragma unroll
        for (int mt = 0; mt < 8; ++mt) {
            int ch = mt * 16 + q * 4;
            float4 bb = *(const float4*)(b1 + ch);
            bf16x4 o;
            o[0] = (__bf16)silu_f(acc[nt][mt][0] + bb.x);
            o[1] = (__bf16)silu_f(acc[nt][mt][1] + bb.y);
            o[2] = (__bf16)silu_f(acc[nt][mt][2] + bb.z);
            o[3] = (__bf16)silu_f(acc[nt][mt][3] + bb.w);
            *(bf16x4*)(L + nl * LSTR + ch) = o;
        }
    }
    __syncthreads();
    f32x4 ac2[2][8];
#pragma unroll
    for (int nt = 0; nt < 2; ++nt)
#pragma unroll
        for (int mt = 0; mt < 8; ++mt) ac2[nt][mt] = (f32x4)(0.f);
    for (int kt = 0; kt < 4; ++kt) {
        int koff = kt * 32 + q * 8;
        bf16x8 bfrag[2];
#pragma unroll
        for (int nt = 0; nt < 2; ++nt)
            bfrag[nt] = *(const bf16x8*)(L + (nt * 16 + l16) * LSTR + koff);
        const __bf16* ap = pw2 + (long)kt * 4096 + lane * 8;
#pragma unroll
        for (int mt = 0; mt < 8; ++mt) {
            bf16x8 a = *(const bf16x8*)(ap + mt * 512);
            ac2[0][mt] = mm(a, bfrag[0], ac2[0][mt]);
            ac2[1][mt] = mm(a, bfrag[1], ac2[1][mt]);
        }
    }
#pragma unroll
    for (int nt = 0; nt < 2; ++nt) {
        long node = nb + nt * 16 + l16;
#pragma unroll
        for (int mt = 0; mt < 8; ++mt) {
            int ch = mt * 16 + q * 4;
            float4 bb = *(const float4*)(b2 + ch);
            bf16x4 sk = *(const bf16x4*)(hin + node * 128 + ch);
            float v0 = ac2[nt][mt][0] + bb.x + (float)sk[0];
            float v1 = ac2[nt][mt][1] + bb.y + (float)sk[1];
            float v2 = ac2[nt][mt][2] + bb.z + (float)sk[2];
            float v3 = ac2[nt][mt][3] + bb.w + (float)sk[3];
            if (gskip) {
                bf16x4 g = *(const bf16x4*)(gskip + node * 128 + ch);
                v0 += (float)g[0]; v1 += (float)g[1]; v2 += (float)g[2]; v3 += (float)g[3];
            }
            bf16x4 o;
            o[0] = (__bf16)v0; o[1] = (__bf16)v1; o[2] = (__bf16)v2; o[3] = (__bf16)v3;
            *(bf16x4*)(hout + node * 128 + ch) = o;
        }
    }
}

// ---------------------------------------------------------------- K4: attention scores
__global__ __launch_bounds__(256) void k_scores(
    const __bf16* __restrict__ x, const float* __restrict__ aw,
    const float* __restrict__ ab, const float* __restrict__ temp,
    float* __restrict__ scores)
{
    int wave = threadIdx.x >> 6, lane = threadIdx.x & 63;
    int n = blockIdx.x * 4 + wave;
    if (n >= NN) return;
    float x0 = (float)x[(long)n * H + lane];
    float x1 = (float)x[(long)n * H + 64 + lane];
    float T = temp[0];
#pragma unroll
    for (int hh = 0; hh < NHEADS; ++hh) {
        float p = x0 * aw[hh * H + lane] + x1 * aw[hh * H + 64 + lane];
#pragma unroll
        for (int off = 32; off >= 1; off >>= 1) p += __shfl_xor(p, off, 64);
        if (lane == 0) scores[n * NHEADS + hh] = (p + ab[hh]) / T;
    }
}

// ---------------------------------------------------------------- K5: graph offsets
__global__ __launch_bounds__(256) void k_offsets(
    const int* __restrict__ batch, int* __restrict__ gstart)
{
    int n = blockIdx.x * 256 + threadIdx.x;
    if (n >= NN) return;
    int b = batch[n];
    int bp = (n == 0) ? -1 : batch[n - 1];
    for (int g = bp + 1; g <= b; ++g) gstart[g] = n;
    if (n == NN - 1) for (int g = b + 1; g <= NG; ++g) gstart[g] = NN;
}

// ---------------------------------------------------------------- K6: softmax pool
__global__ __launch_bounds__(64) void k_pool(
    const __bf16* __restrict__ x, const float* __restrict__ scores,
    const int* __restrict__ gstart, float* __restrict__ pooled)
{
    int g = blockIdx.x, lane = threadIdx.x;
    int s0 = gstart[g], s1 = gstart[g + 1];
    float m0 = -INFINITY, m1 = -INFINITY, m2 = -INFINITY, m3 = -INFINITY;
    for (int n = s0 + lane; n < s1; n += 64) {
        m0 = fmaxf(m0, scores[n * 4 + 0]); m1 = fmaxf(m1, scores[n * 4 + 1]);
        m2 = fmaxf(m2, scores[n * 4 + 2]); m3 = fmaxf(m3, scores[n * 4 + 3]);
    }
#pragma unroll
    for (int off = 32; off >= 1; off >>= 1) {
        m0 = fmaxf(m0, __shfl_xor(m0, off, 64)); m1 = fmaxf(m1, __shfl_xor(m1, off, 64));
        m2 = fmaxf(m2, __shfl_xor(m2, off, 64)); m3 = fmaxf(m3, __shfl_xor(m3, off, 64));
    }
    float d0 = 0.f, d1 = 0.f, d2 = 0.f, d3 = 0.f;
    for (int n = s0 + lane; n < s1; n += 64) {
        d0 += expf(scores[n * 4 + 0] - m0); d1 += expf(scores[n * 4 + 1] - m1);
        d2 += expf(scores[n * 4 + 2] - m2); d3 += expf(scores[n * 4 + 3] - m3);
    }
#pragma unroll
    for (int off = 32; off >= 1; off >>= 1) {
        d0 += __shfl_xor(d0, off, 64); d1 += __shfl_xor(d1, off, 64);
        d2 += __shfl_xor(d2, off, 64); d3 += __shfl_xor(d3, off, 64);
    }
    float i0 = d0 > 0.f ? 1.f / d0 : 0.f;
    float i1 = d1 > 0.f ? 1.f / d1 : 0.f;
    float i2 = d2 > 0.f ? 1.f / d2 : 0.f;
    float i3 = d3 > 0.f ? 1.f / d3 : 0.f;
    float a0 = 0.f, a1 = 0.f;
    for (int n = s0; n < s1; ++n) {
        float wb = expf(scores[n * 4 + 0] - m0) * i0 + expf(scores[n * 4 + 1] - m1) * i1
                 + expf(scores[n * 4 + 2] - m2) * i2 + expf(scores[n * 4 + 3] - m3) * i3;
        wb *= 0.25f;
        a0 += wb * (float)x[(long)n * H + lane];
        a1 += wb * (float)x[(long)n * H + 64 + lane];
    }
    pooled[g * H + lane] = a0;
    pooled[g * H + 64 + lane] = a1;
}

// ---------------------------------------------------------------- K7: FFN readout
__global__ __launch_bounds__(128) void k_ffn(
    const float* __restrict__ pooled,
    const float* __restrict__ W1, const float* __restrict__ B1,
    const float* __restrict__ W2, const float* __restrict__ B2,
    const float* __restrict__ W3, const float* __restrict__ B3,
    float* __restrict__ out)
{
    __shared__ float p[H], t1[H], t2[H], red[H];
    int g = blockIdx.x, c = threadIdx.x;
    p[c] = pooled[g * H + c];
    __syncthreads();
    float acc = 0.f;
    for (int k = 0; k < H; ++k) acc += p[k] * W1[k * H + c];
    t1[c] = silu_f(acc + B1[c]);
    __syncthreads();
    acc = 0.f;
    for (int k = 0; k < H; ++k) acc += t1[k] * W2[k * H + c];
    t2[c] = silu_f(acc + B2[c]);
    __syncthreads();
    red[c] = t2[c] * W3[c];
    __syncthreads();
    for (int off = 64; off >= 1; off >>= 1) {
        if (c < off) red[c] += red[c + off];
        __syncthreads();
    }
    if (c == 0) out[g] = red[0] + B3[0];
}

// ---------------------------------------------------------------- launch
extern "C" void kernel_launch(void* const* d_in, const int* in_sizes, int n_in,
                              void* d_out, int out_size, void* d_ws, size_t ws_size,
                              hipStream_t stream)
{
    const int*   atom   = (const int*)d_in[0];
    const int*   hc     = (const int*)d_in[1];
    const int*   deg    = (const int*)d_in[2];
    const int*   hyb    = (const int*)d_in[3];
    const int*   target = (const int*)d_in[4];
    const int*   src    = (const int*)d_in[5];
    const int*   batch  = (const int*)d_in[6];
    const float* Ea     = (const float*)d_in[7];
    const float* Eh     = (const float*)d_in[8];
    const float* Ed     = (const float*)d_in[9];
    const float* Ey     = (const float*)d_in[10];
    const float* projW  = (const float*)d_in[11];
    const float* projB  = (const float*)d_in[12];
    const float* sInW   = (const float*)d_in[13];
    const float* sInB   = (const float*)d_in[14];
    const float* mW1    = (const float*)d_in[15];
    const float* mB1    = (const float*)d_in[16];
    const float* mW2    = (const float*)d_in[17];
    const float* mB2    = (const float*)d_in[18];
    const float* sSkW   = (const float*)d_in[19];
    const float* sSkB   = (const float*)d_in[20];
    const float* attnW  = (const float*)d_in[21];
    const float* attnB  = (const float*)d_in[22];
    const float* temp   = (const float*)d_in[23];
    const float* fW1    = (const float*)d_in[24];
    const float* fB1    = (const float*)d_in[25];
    const float* fW2    = (const float*)d_in[26];
    const float* fB2    = (const float*)d_in[27];
    const float* fW3    = (const float*)d_in[28];
    const float* fB3    = (const float*)d_in[29];
    float* out = (float*)d_out;

    char* w = (char*)d_ws;
    auto take = [&](size_t bytes) { void* p = (void*)w; w += (bytes + 255) & ~(size_t)255; return p; };
    __bf16* x      = (__bf16*)take(2L * NNP * H);
    __bf16* agg    = (__bf16*)take(2L * 3 * NNP * H);
    __bf16* hbuf   = (__bf16*)take(2L * NNP * H);
    __bf16* hbuf2  = (__bf16*)take(2L * NNP * H);
    __bf16* gskip  = (__bf16*)take(2L * NNP * H);
    __bf16* pproj  = (__bf16*)take(2L * 256 * H);
    __bf16* pin    = (__bf16*)take(2L * 3 * 512 * H);
    __bf16* psk    = (__bf16*)take(2L * 3 * 512 * H);
    __bf16* pw1    = (__bf16*)take(2L * 6 * 128 * H);
    __bf16* pw2    = (__bf16*)take(2L * 6 * 128 * H);
    __bf16* embb   = (__bf16*)take(2L * 8000);
    float*  scores = (float*)take(4L * NN * NHEADS);
    float*  pooled = (float*)take(4L * NG * H);
    int*    gstart = (int*)take(4L * (NG + 1));
    int*    csr_start = (int*)take(4L * (NROWS + 1));
    unsigned int*   packedP = (unsigned int*)take(4L * NPART * NBUK * CAP);  // 38.4 MB
    unsigned short* esrc    = (unsigned short*)take(2L * NE);
    int*    pcursor = (int*)take(4L * NPART * NBUK);
    int*    bbase   = (int*)take(4L * (NBUK + 1));

    // ---- weight packing (weights restored each call -> pack each call) ----
    k_packw<<<(1 * 256 * 128) / 256, 256, 0, stream>>>(projW, pproj, 256, 1);
    k_packw<<<(3 * 512 * 128) / 256, 256, 0, stream>>>(sInW, pin, 512, 3);
    k_packw<<<(3 * 512 * 128) / 256, 256, 0, stream>>>(sSkW, psk, 512, 3);
    k_packw<<<(6 * 128 * 128) / 256, 256, 0, stream>>>(mW1, pw1, 128, 6);
    k_packw<<<(6 * 128 * 128) / 256, 256, 0, stream>>>(mW2, pw2, 128, 6);
    k_cvt_emb<<<32, 256, 0, stream>>>(Ea, Eh, Ed, Ey, embb);

    // ---- CSR build: XCD-partitioned scatter -> bucket scan -> LDS finalize ----
    hipMemsetAsync(pcursor, 0, sizeof(int) * NPART * NBUK, stream);
    k_fillp<<<2048, 256, 0, stream>>>(target, src, pcursor, packedP);
    k_scanb<<<1, 1024, 0, stream>>>(pcursor, bbase);
    k_fill2p<<<NBUK, 256, 0, stream>>>(packedP, pcursor, bbase, csr_start, esrc);

    k_embed_m<<<NNP / 128, 256, 0, stream>>>(atom, hc, deg, hyb, embb, pproj, projB, x);
    k_offsets<<<(NN + 255) / 256, 256, 0, stream>>>(batch, gstart);

    for (int l = 0; l < NL; ++l) {
        k_gather<<<NROWS / 8, 256, 0, stream>>>(esrc, csr_start,
            (const uint2*)x, (uint2*)agg);
        k_shell_m<<<NNP / 128, 256, 0, stream>>>(x, agg,
            pin + (long)l * 512 * H, sInB + l * H,
            psk + (long)l * 512 * H, sSkB + l * H, hbuf, gskip);
        k_mlp_m<<<NNP / 128, 256, 0, stream>>>(hbuf,
            pw1 + (long)(l * NMLP + 0) * 128 * H, mB1 + (long)(l * NMLP + 0) * H,
            pw2 + (long)(l * NMLP + 0) * 128 * H, mB2 + (long)(l * NMLP + 0) * H,
            nullptr, hbuf2);
        k_mlp_m<<<NNP / 128, 256, 0, stream>>>(hbuf2,
            pw1 + (long)(l * NMLP + 1) * 128 * H, mB1 + (long)(l * NMLP + 1) * H,
            pw2 + (long)(l * NMLP + 1) * 128 * H, mB2 + (long)(l * NMLP + 1) * H,
            gskip, x);
    }

    k_scores<<<NN / 4, 256, 0, stream>>>(x, attnW, attnB, temp, scores);
    k_pool<<<NG, 64, 0, stream>>>(x, scores, gstart, pooled);
    k_ffn<<<NG, 128, 0, stream>>>(pooled, fW1, fB1, fW2, fB2, fW3, fB3, out);
}

// Round 6
// 952.588 us; speedup vs baseline: 14.2531x; 1.0152x over previous
//
#include <hip/hip_runtime.h>
#include <math.h>

#define NN      50000
#define NNP     50048          // padded nodes = 391*128
#define NE      2400000
#define NHOPS   3
#define NG      2048
#define H       128
#define EMBD    64
#define NL      3
#define NMLP    2
#define NHEADS  4
#define NROWS   (NHOPS * NN)   // 150000
#define BINSH   9              // 512 rows per coarse bin
#define NBIN    293            // ceil(150016/512)
#define CAPB    10240          // per-bin region capacity (mean 8192, +22 sigma)
#define ABLK    120            // binning blocks (edges per (block,bin) ~68 -> line combining)
#define DEPTH   32             // LDS circular buffer depth per bin
#define LSTR    136

typedef __bf16 bf16x8 __attribute__((ext_vector_type(8)));
typedef __bf16 bf16x4 __attribute__((ext_vector_type(4)));
typedef float  f32x4  __attribute__((ext_vector_type(4)));

__device__ __forceinline__ float silu_f(float v) { return v / (1.0f + expf(-v)); }

__device__ __forceinline__ f32x4 mm(bf16x8 a, bf16x8 b, f32x4 c) {
    return __builtin_amdgcn_mfma_f32_16x16x32_bf16(a, b, c, 0, 0, 0);
}

__device__ __forceinline__ float blo(unsigned v) { return __builtin_bit_cast(float, v << 16); }
__device__ __forceinline__ float bhi(unsigned v) { return __builtin_bit_cast(float, v & 0xffff0000u); }

// ---------------------------------------------------------------- fused weight pack + emb convert
__device__ __forceinline__ void packw_elem(
    const float* __restrict__ W, __bf16* __restrict__ out, int K, long idx)
{
    long per = (long)K * 128;
    long mat = idx / per, e = idx - mat * per;
    int j = (int)(e & 7), n16 = (int)((e >> 3) & 15), q = (int)((e >> 7) & 3),
        mt = (int)((e >> 9) & 7), kt = (int)(e >> 12);
    int k = kt * 32 + q * 8 + j, n = mt * 16 + n16;
    out[idx] = (__bf16)W[mat * per + (long)k * 128 + n];
}

__global__ __launch_bounds__(256) void k_packall(
    const float* __restrict__ projW, __bf16* __restrict__ pproj,
    const float* __restrict__ sInW,  __bf16* __restrict__ pin,
    const float* __restrict__ sSkW,  __bf16* __restrict__ psk,
    const float* __restrict__ mW1,   __bf16* __restrict__ pw1,
    const float* __restrict__ mW2,   __bf16* __restrict__ pw2,
    const float* __restrict__ Ea, const float* __restrict__ Eh,
    const float* __restrict__ Ed, const float* __restrict__ Ey,
    __bf16* __restrict__ embb)
{
    long tid = (long)blockIdx.x * 256 + threadIdx.x;
    if (tid < 32768) { packw_elem(projW, pproj, 256, tid); return; }
    tid -= 32768;
    if (tid < 196608) { packw_elem(sInW, pin, 512, tid); return; }
    tid -= 196608;
    if (tid < 196608) { packw_elem(sSkW, psk, 512, tid); return; }
    tid -= 196608;
    if (tid < 98304) { packw_elem(mW1, pw1, 128, tid); return; }
    tid -= 98304;
    if (tid < 98304) { packw_elem(mW2, pw2, 128, tid); return; }
    tid -= 98304;
    if (tid < 8000) {
        int t = (int)tid;
        float v;
        if (t < 6400) v = Ea[t];
        else if (t < 6976) v = Eh[t - 6400];
        else if (t < 7488) v = Ed[t - 6976];
        else v = Ey[t - 7488];
        embb[t] = (__bf16)v;
    }
}

// ---------------------------------------------------------------- K0: embed + project + silu (MFMA)
__global__ __launch_bounds__(256) void k_embed_m(
    const int* __restrict__ atom, const int* __restrict__ hc,
    const int* __restrict__ deg,  const int* __restrict__ hyb,
    const __bf16* __restrict__ emb, const __bf16* __restrict__ pw,
    const float* __restrict__ pb, __bf16* __restrict__ x)
{
    const int lane = threadIdx.x & 63, wid = threadIdx.x >> 6;
    const int q = lane >> 4, l16 = lane & 15;
    const int nb = blockIdx.x * 128 + wid * 32;
    int ia[2][4];
#pragma unroll
    for (int nt = 0; nt < 2; ++nt) {
        int n = nb + nt * 16 + l16;
        if (n >= NN) n = NN - 1;
        ia[nt][0] = atom[n]; ia[nt][1] = hc[n]; ia[nt][2] = deg[n]; ia[nt][3] = hyb[n];
    }
    f32x4 acc[2][8];
#pragma unroll
    for (int nt = 0; nt < 2; ++nt)
#pragma unroll
        for (int mt = 0; mt < 8; ++mt) acc[nt][mt] = (f32x4)(0.f);
    const int tb[4] = {0, 6400, 6976, 7488};
    for (int kt = 0; kt < 8; ++kt) {
        int t = kt >> 1;
        int koff = (kt & 1) * 32 + q * 8;
        bf16x8 bfrag[2];
#pragma unroll
        for (int nt = 0; nt < 2; ++nt)
            bfrag[nt] = *(const bf16x8*)(emb + tb[t] + (long)ia[nt][t] * 64 + koff);
        const __bf16* ap = pw + (long)kt * 4096 + lane * 8;
#pragma unroll
        for (int mt = 0; mt < 8; ++mt) {
            bf16x8 a = *(const bf16x8*)(ap + mt * 512);
            acc[0][mt] = mm(a, bfrag[0], acc[0][mt]);
            acc[1][mt] = mm(a, bfrag[1], acc[1][mt]);
        }
    }
#pragma unroll
    for (int nt = 0; nt < 2; ++nt) {
        long node = nb + nt * 16 + l16;
#pragma unroll
        for (int mt = 0; mt < 8; ++mt) {
            int ch = mt * 16 + q * 4;
            float4 bb = *(const float4*)(pb + ch);
            bf16x4 o;
            o[0] = (__bf16)silu_f(acc[nt][mt][0] + bb.x);
            o[1] = (__bf16)silu_f(acc[nt][mt][1] + bb.y);
            o[2] = (__bf16)silu_f(acc[nt][mt][2] + bb.z);
            o[3] = (__bf16)silu_f(acc[nt][mt][3] + bb.w);
            *(bf16x4*)(x + node * 128 + ch) = o;
        }
    }
}

// ---------------------------------------------------------------- CSR build pass A: LDS write-combined binning
// Full 64B lines flushed by a single wave -> write amp ~1x independent of XCD mapping.
__global__ __launch_bounds__(256) void k_binA(
    const int* __restrict__ target, const int* __restrict__ src,
    int* __restrict__ gbincur, unsigned int* __restrict__ binreg)
{
    __shared__ unsigned int buf[NBIN][DEPTH];
    __shared__ int cnt[NBIN];
    __shared__ int flushed[NBIN];
    const int tid = threadIdx.x;
    for (int i = tid; i < NBIN; i += 256) { cnt[i] = 0; flushed[i] = 0; }
    __syncthreads();
    const int per = (NE + ABLK - 1) / ABLK;   // 20000
    const int e0 = blockIdx.x * per;
    const int e1 = (e0 + per < NE) ? e0 + per : NE;
    for (int base = e0; base < e1; base += 256) {
        int e = base + tid;
        if (e < e1) {
            int s = src[e];
            if (s >= 2 * NN) s -= 2 * NN; else if (s >= NN) s -= NN;
            int t = target[e];
            int bin = t >> BINSH;
            unsigned val = (unsigned)s | ((unsigned)(t & ((1 << BINSH) - 1)) << 16);
            int slot = atomicAdd(&cnt[bin], 1);
            buf[bin][slot & (DEPTH - 1)] = val;   // depth-32 circular; carry<16 + batch adds << 16
        }
        __syncthreads();
        for (int b = tid; b < NBIN; b += 256) {
            while (cnt[b] - flushed[b] >= 16) {
                int pos = atomicAdd(&gbincur[b], 16);
                unsigned int* dst = binreg + (long)b * CAPB + pos;
                const unsigned int* sp = &buf[b][flushed[b] & (DEPTH - 1)];
                if ((pos & 3) == 0) {
                    uint4* d4 = (uint4*)dst; const uint4* s4 = (const uint4*)sp;
                    d4[0] = s4[0]; d4[1] = s4[1]; d4[2] = s4[2]; d4[3] = s4[3];
                } else {
#pragma unroll
                    for (int i = 0; i < 16; ++i) dst[i] = sp[i];
                }
                flushed[b] += 16;
            }
        }
        __syncthreads();
    }
    for (int b = tid; b < NBIN; b += 256) {
        int lvl = cnt[b] - flushed[b];
        if (lvl > 0) {
            int pos = atomicAdd(&gbincur[b], lvl);
            for (int i = 0; i < lvl; ++i)
                binreg[(long)b * CAPB + pos + i] = buf[b][(flushed[b] + i) & (DEPTH - 1)];
        }
    }
}

// ---------------------------------------------------------------- bin-base scan (293 values, one block)
__global__ __launch_bounds__(512) void k_scanc(
    const int* __restrict__ gbincur, int* __restrict__ bbase)
{
    __shared__ int s[512];
    int tid = threadIdx.x;
    int v = (tid < NBIN) ? gbincur[tid] : 0;
    s[tid] = v;
    __syncthreads();
    for (int off = 1; off < 512; off <<= 1) {
        int t = (tid >= off) ? s[tid - off] : 0;
        __syncthreads();
        s[tid] += t;
        __syncthreads();
    }
    if (tid < NBIN) bbase[tid] = s[tid] - v;
}

// ---------------------------------------------------------------- CSR build pass B: per-bin LDS finalize
// One block per bin: stage edges, count+scan 512 rows, write csr_start + target-sorted esrc.
__global__ __launch_bounds__(512) void k_fill2b(
    const unsigned int* __restrict__ binreg, const int* __restrict__ gbincur,
    const int* __restrict__ bbase, int* __restrict__ csr_start,
    unsigned short* __restrict__ esrc)
{
    __shared__ unsigned int stage[CAPB];
    __shared__ int rcnt[512], scn[512], cur[512];
    const int b = blockIdx.x, tid = threadIdx.x;
    int total = gbincur[b];
    if (total > CAPB) total = CAPB;      // sanity clamp (also guards poisoned profiler replays)
    if (total < 0) total = 0;
    const unsigned int* seg = binreg + (long)b * CAPB;
    for (int i = tid; i < total; i += 512) stage[i] = seg[i];
    rcnt[tid] = 0;
    __syncthreads();
    for (int i = tid; i < total; i += 512) atomicAdd(&rcnt[(stage[i] >> 16) & 511], 1);
    __syncthreads();
    int v = rcnt[tid];
    scn[tid] = v;
    __syncthreads();
    for (int off = 1; off < 512; off <<= 1) {
        int t = (tid >= off) ? scn[tid - off] : 0;
        __syncthreads();
        scn[tid] += t;
        __syncthreads();
    }
    int base = bbase[b] + scn[tid] - v;   // exclusive offset for row tid
    cur[tid] = base;
    int row = b * 512 + tid;
    if (row <= NROWS) csr_start[row] = base;
    // rows >= NROWS in the last bin have zero counts; csr_start[NROWS] lands on NE.
    __syncthreads();
    for (int i = tid; i < total; i += 512) {
        unsigned pk = stage[i];
        int pos = atomicAdd(&cur[(pk >> 16) & 511], 1);
        esrc[pos] = (unsigned short)(pk & 0xffffu);
    }
}

// ---------------------------------------------------------------- K1: CSR gather, 2 rows/wave, x4 unrolled loads
__global__ __launch_bounds__(256) void k_gather(
    const unsigned short* __restrict__ esrc, const int* __restrict__ csr_start,
    const uint2* __restrict__ x4, uint2* __restrict__ agg4)
{
    int pair = blockIdx.x * 4 + (threadIdx.x >> 6);
    int lane = threadIdx.x & 63;
    int half = lane >> 5, l5 = lane & 31;
    int row = pair * 2 + half;
    int e0 = csr_start[row], e1 = csr_start[row + 1];
    if ((unsigned)e0 > NE || (unsigned)e1 > NE || e1 < e0) { e0 = 0; e1 = 0; }  // replay-safety
    int nch = (e1 - e0 + 31) >> 5;
    int nA = __shfl(nch, 0, 64);
    int nB = __shfl(nch, 32, 64);
    int nmax = nA > nB ? nA : nB;
    float a0 = 0.f, a1 = 0.f, a2 = 0.f, a3 = 0.f;
    for (int c = 0; c < nmax; ++c) {
        int base = e0 + c * 32;
        int rem = e1 - base;
        int pre = (l5 < rem) ? (int)esrc[base + l5] : 0;
        int m = rem < 32 ? (rem < 0 ? 0 : rem) : 32;
        int sb = half << 5;
        int j = 0;
        for (; j + 3 < m; j += 4) {
            int sA = __shfl(pre, sb + j, 64);
            int sB = __shfl(pre, sb + j + 1, 64);
            int sC = __shfl(pre, sb + j + 2, 64);
            int sD = __shfl(pre, sb + j + 3, 64);
            uint2 v0 = x4[(long)sA * 32 + l5];
            uint2 v1 = x4[(long)sB * 32 + l5];
            uint2 v2 = x4[(long)sC * 32 + l5];
            uint2 v3 = x4[(long)sD * 32 + l5];
            a0 += blo(v0.x) + blo(v1.x) + blo(v2.x) + blo(v3.x);
            a1 += bhi(v0.x) + bhi(v1.x) + bhi(v2.x) + bhi(v3.x);
            a2 += blo(v0.y) + blo(v1.y) + blo(v2.y) + blo(v3.y);
            a3 += bhi(v0.y) + bhi(v1.y) + bhi(v2.y) + bhi(v3.y);
        }
        for (; j < m; ++j) {
            int sA = __shfl(pre, sb + j, 64);
            uint2 v0 = x4[(long)sA * 32 + l5];
            a0 += blo(v0.x); a1 += bhi(v0.x);
            a2 += blo(v0.y); a3 += bhi(v0.y);
        }
    }
    int hop = row / NN, node = row - hop * NN;
    unsigned short u0 = __builtin_bit_cast(unsigned short, (__bf16)a0);
    unsigned short u1 = __builtin_bit_cast(unsigned short, (__bf16)a1);
    unsigned short u2 = __builtin_bit_cast(unsigned short, (__bf16)a2);
    unsigned short u3 = __builtin_bit_cast(unsigned short, (__bf16)a3);
    uint2 o;
    o.x = (unsigned)u0 | ((unsigned)u1 << 16);
    o.y = (unsigned)u2 | ((unsigned)u3 << 16);
    agg4[((long)hop * NNP + node) * 32 + l5] = o;
}

// ---------------------------------------------------------------- K2: shell_in + skip (MFMA, K=512)
__global__ __launch_bounds__(256) void k_shell_m(
    const __bf16* __restrict__ x, const __bf16* __restrict__ agg,
    const __bf16* __restrict__ pwin, const float* __restrict__ bin,
    const __bf16* __restrict__ pwsk, const float* __restrict__ bsk,
    __bf16* __restrict__ h, __bf16* __restrict__ gskip)
{
    const int lane = threadIdx.x & 63, wid = threadIdx.x >> 6;
    const int q = lane >> 4, l16 = lane & 15;
    const int nb = blockIdx.x * 128 + wid * 32;
    f32x4 aci[2][8], acs[2][8];
#pragma unroll
    for (int nt = 0; nt < 2; ++nt)
#pragma unroll
        for (int mt = 0; mt < 8; ++mt) { aci[nt][mt] = (f32x4)(0.f); acs[nt][mt] = (f32x4)(0.f); }
    const __bf16* planes[4] = {x, agg, agg + (long)NNP * 128, agg + 2L * NNP * 128};
    for (int kt = 0; kt < 16; ++kt) {
        const __bf16* src = planes[kt >> 2];
        int koff = (kt & 3) * 32 + q * 8;
        bf16x8 bfrag[2];
#pragma unroll
        for (int nt = 0; nt < 2; ++nt)
            bfrag[nt] = *(const bf16x8*)(src + (long)(nb + nt * 16 + l16) * 128 + koff);
        const __bf16* aip = pwin + (long)kt * 4096 + lane * 8;
        const __bf16* asp = pwsk + (long)kt * 4096 + lane * 8;
#pragma unroll
        for (int mt = 0; mt < 8; ++mt) {
            bf16x8 ai = *(const bf16x8*)(aip + mt * 512);
            bf16x8 as = *(const bf16x8*)(asp + mt * 512);
            aci[0][mt] = mm(ai, bfrag[0], aci[0][mt]);
            aci[1][mt] = mm(ai, bfrag[1], aci[1][mt]);
            acs[0][mt] = mm(as, bfrag[0], acs[0][mt]);
            acs[1][mt] = mm(as, bfrag[1], acs[1][mt]);
        }
    }
#pragma unroll
    for (int nt = 0; nt < 2; ++nt) {
        long node = nb + nt * 16 + l16;
#pragma unroll
        for (int mt = 0; mt < 8; ++mt) {
            int ch = mt * 16 + q * 4;
            float4 bi = *(const float4*)(bin + ch);
            float4 bs = *(const float4*)(bsk + ch);
            bf16x4 oh, og;
            oh[0] = (__bf16)silu_f(aci[nt][mt][0] + bi.x); og[0] = (__bf16)(acs[nt][mt][0] + bs.x);
            oh[1] = (__bf16)silu_f(aci[nt][mt][1] + bi.y); og[1] = (__bf16)(acs[nt][mt][1] + bs.y);
            oh[2] = (__bf16)silu_f(aci[nt][mt][2] + bi.z); og[2] = (__bf16)(acs[nt][mt][2] + bs.z);
            oh[3] = (__bf16)silu_f(aci[nt][mt][3] + bi.w); og[3] = (__bf16)(acs[nt][mt][3] + bs.w);
            *(bf16x4*)(h + node * 128 + ch) = oh;
            *(bf16x4*)(gskip + node * 128 + ch) = og;
        }
    }
}

// ---------------------------------------------------------------- K3: fused residual MLP (MFMA)
__global__ __launch_bounds__(256) void k_mlp_m(
    const __bf16* __restrict__ hin,
    const __bf16* __restrict__ pw1, const float* __restrict__ b1,
    const __bf16* __restrict__ pw2, const float* __restrict__ b2,
    const __bf16* __restrict__ gskip, __bf16* __restrict__ hout)
{
    __shared__ __bf16 lds[4][32 * LSTR];
    const int lane = threadIdx.x & 63, wid = threadIdx.x >> 6;
    const int q = lane >> 4, l16 = lane & 15;
    const int nb = blockIdx.x * 128 + wid * 32;
    __bf16* L = lds[wid];
    f32x4 acc[2][8];
#pragma unroll
    for (int nt = 0; nt < 2; ++nt)
#pragma unroll
        for (int mt = 0; mt < 8; ++mt) acc[nt][mt] = (f32x4)(0.f);
    for (int kt = 0; kt < 4; ++kt) {
        int koff = kt * 32 + q * 8;
        bf16x8 bfrag[2];
#pragma unroll
        for (int nt = 0; nt < 2; ++nt)
            bfrag[nt] = *(const bf16x8*)(hin + (long)(nb + nt * 16 + l16) * 128 + koff);
        const __bf16* ap = pw1 + (long)kt * 4096 + lane * 8;
#pragma unroll
        for (int mt = 0; mt < 8; ++mt) {
            bf16x8 a = *(const bf16x8*)(ap + mt * 512);
            acc[0][mt] = mm(a, bfrag[0], acc[0][mt]);
            acc[1][mt] = mm(a, bfrag[1], acc[1][mt]);
        }
    }
#pragma unroll
    for (int nt = 0; nt < 2; ++nt) {
        int nl = nt * 16 + l16;
#pragma unroll
        for (int mt = 0; mt < 8; ++mt) {
            int ch = mt * 16 + q * 4;
            float4 bb = *(const float4*)(b1 + ch);
            bf16x4 o;
            o[0] = (__bf16)silu_f(acc[nt][mt][0] + bb.x);
            o[1] = (__bf16)silu_f(acc[nt][mt][1] + bb.y);
            o[2] = (__bf16)silu_f(acc[nt][mt][2] + bb.z);
            o[3] = (__bf16)silu_f(acc[nt][mt][3] + bb.w);
            *(bf16x4*)(L + nl * LSTR + ch) = o;
        }
    }
    __syncthreads();
    f32x4 ac2[2][8];
#pragma unroll
    for (int nt = 0; nt < 2; ++nt)
#pragma unroll
        for (int mt = 0; mt < 8; ++mt) ac2[nt][mt] = (f32x4)(0.f);
    for (int kt = 0; kt < 4; ++kt) {
        int koff = kt * 32 + q * 8;
        bf16x8 bfrag[2];
#pragma unroll
        for (int nt = 0; nt < 2; ++nt)
            bfrag[nt] = *(const bf16x8*)(L + (nt * 16 + l16) * LSTR + koff);
        const __bf16* ap = pw2 + (long)kt * 4096 + lane * 8;
#pragma unroll
        for (int mt = 0; mt < 8; ++mt) {
            bf16x8 a = *(const bf16x8*)(ap + mt * 512);
            ac2[0][mt] = mm(a, bfrag[0], ac2[0][mt]);
            ac2[1][mt] = mm(a, bfrag[1], ac2[1][mt]);
        }
    }
#pragma unroll
    for (int nt = 0; nt < 2; ++nt) {
        long node = nb + nt * 16 + l16;
#pragma unroll
        for (int mt = 0; mt < 8; ++mt) {
            int ch = mt * 16 + q * 4;
            float4 bb = *(const float4*)(b2 + ch);
            bf16x4 sk = *(const bf16x4*)(hin + node * 128 + ch);
            float v0 = ac2[nt][mt][0] + bb.x + (float)sk[0];
            float v1 = ac2[nt][mt][1] + bb.y + (float)sk[1];
            float v2 = ac2[nt][mt][2] + bb.z + (float)sk[2];
            float v3 = ac2[nt][mt][3] + bb.w + (float)sk[3];
            if (gskip) {
                bf16x4 g = *(const bf16x4*)(gskip + node * 128 + ch);
                v0 += (float)g[0]; v1 += (float)g[1]; v2 += (float)g[2]; v3 += (float)g[3];
            }
            bf16x4 o;
            o[0] = (__bf16)v0; o[1] = (__bf16)v1; o[2] = (__bf16)v2; o[3] = (__bf16)v3;
            *(bf16x4*)(hout + node * 128 + ch) = o;
        }
    }
}

// ---------------------------------------------------------------- K4: attention scores
__global__ __launch_bounds__(256) void k_scores(
    const __bf16* __restrict__ x, const float* __restrict__ aw,
    const float* __restrict__ ab, const float* __restrict__ temp,
    float* __restrict__ scores)
{
    int wave = threadIdx.x >> 6, lane = threadIdx.x & 63;
    int n = blockIdx.x * 4 + wave;
    if (n >= NN) return;
    float x0 = (float)x[(long)n * H + lane];
    float x1 = (float)x[(long)n * H + 64 + lane];
    float T = temp[0];
#pragma unroll
    for (int hh = 0; hh < NHEADS; ++hh) {
        float p = x0 * aw[hh * H + lane] + x1 * aw[hh * H + 64 + lane];
#pragma unroll
        for (int off = 32; off >= 1; off >>= 1) p += __shfl_xor(p, off, 64);
        if (lane == 0) scores[n * NHEADS + hh] = (p + ab[hh]) / T;
    }
}

// ---------------------------------------------------------------- K5: graph offsets
__global__ __launch_bounds__(256) void k_offsets(
    const int* __restrict__ batch, int* __restrict__ gstart)
{
    int n = blockIdx.x * 256 + threadIdx.x;
    if (n >= NN) return;
    int b = batch[n];
    int bp = (n == 0) ? -1 : batch[n - 1];
    for (int g = bp + 1; g <= b; ++g) gstart[g] = n;
    if (n == NN - 1) for (int g = b + 1; g <= NG; ++g) gstart[g] = NN;
}

// ---------------------------------------------------------------- K6: softmax pool
__global__ __launch_bounds__(64) void k_pool(
    const __bf16* __restrict__ x, const float* __restrict__ scores,
    const int* __restrict__ gstart, float* __restrict__ pooled)
{
    int g = blockIdx.x, lane = threadIdx.x;
    int s0 = gstart[g], s1 = gstart[g + 1];
    float m0 = -INFINITY, m1 = -INFINITY, m2 = -INFINITY, m3 = -INFINITY;
    for (int n = s0 + lane; n < s1; n += 64) {
        m0 = fmaxf(m0, scores[n * 4 + 0]); m1 = fmaxf(m1, scores[n * 4 + 1]);
        m2 = fmaxf(m2, scores[n * 4 + 2]); m3 = fmaxf(m3, scores[n * 4 + 3]);
    }
#pragma unroll
    for (int off = 32; off >= 1; off >>= 1) {
        m0 = fmaxf(m0, __shfl_xor(m0, off, 64)); m1 = fmaxf(m1, __shfl_xor(m1, off, 64));
        m2 = fmaxf(m2, __shfl_xor(m2, off, 64)); m3 = fmaxf(m3, __shfl_xor(m3, off, 64));
    }
    float d0 = 0.f, d1 = 0.f, d2 = 0.f, d3 = 0.f;
    for (int n = s0 + lane; n < s1; n += 64) {
        d0 += expf(scores[n * 4 + 0] - m0); d1 += expf(scores[n * 4 + 1] - m1);
        d2 += expf(scores[n * 4 + 2] - m2); d3 += expf(scores[n * 4 + 3] - m3);
    }
#pragma unroll
    for (int off = 32; off >= 1; off >>= 1) {
        d0 += __shfl_xor(d0, off, 64); d1 += __shfl_xor(d1, off, 64);
        d2 += __shfl_xor(d2, off, 64); d3 += __shfl_xor(d3, off, 64);
    }
    float i0 = d0 > 0.f ? 1.f / d0 : 0.f;
    float i1 = d1 > 0.f ? 1.f / d1 : 0.f;
    float i2 = d2 > 0.f ? 1.f / d2 : 0.f;
    float i3 = d3 > 0.f ? 1.f / d3 : 0.f;
    float a0 = 0.f, a1 = 0.f;
    for (int n = s0; n < s1; ++n) {
        float wb = expf(scores[n * 4 + 0] - m0) * i0 + expf(scores[n * 4 + 1] - m1) * i1
                 + expf(scores[n * 4 + 2] - m2) * i2 + expf(scores[n * 4 + 3] - m3) * i3;
        wb *= 0.25f;
        a0 += wb * (float)x[(long)n * H + lane];
        a1 += wb * (float)x[(long)n * H + 64 + lane];
    }
    pooled[g * H + lane] = a0;
    pooled[g * H + 64 + lane] = a1;
}

// ---------------------------------------------------------------- K7: FFN readout
__global__ __launch_bounds__(128) void k_ffn(
    const float* __restrict__ pooled,
    const float* __restrict__ W1, const float* __restrict__ B1,
    const float* __restrict__ W2, const float* __restrict__ B2,
    const float* __restrict__ W3, const float* __restrict__ B3,
    float* __restrict__ out)
{
    __shared__ float p[H], t1[H], t2[H], red[H];
    int g = blockIdx.x, c = threadIdx.x;
    p[c] = pooled[g * H + c];
    __syncthreads();
    float acc = 0.f;
    for (int k = 0; k < H; ++k) acc += p[k] * W1[k * H + c];
    t1[c] = silu_f(acc + B1[c]);
    __syncthreads();
    acc = 0.f;
    for (int k = 0; k < H; ++k) acc += t1[k] * W2[k * H + c];
    t2[c] = silu_f(acc + B2[c]);
    __syncthreads();
    red[c] = t2[c] * W3[c];
    __syncthreads();
    for (int off = 64; off >= 1; off >>= 1) {
        if (c < off) red[c] += red[c + off];
        __syncthreads();
    }
    if (c == 0) out[g] = red[0] + B3[0];
}

// ---------------------------------------------------------------- launch
extern "C" void kernel_launch(void* const* d_in, const int* in_sizes, int n_in,
                              void* d_out, int out_size, void* d_ws, size_t ws_size,
                              hipStream_t stream)
{
    const int*   atom   = (const int*)d_in[0];
    const int*   hc     = (const int*)d_in[1];
    const int*   deg    = (const int*)d_in[2];
    const int*   hyb    = (const int*)d_in[3];
    const int*   target = (const int*)d_in[4];
    const int*   src    = (const int*)d_in[5];
    const int*   batch  = (const int*)d_in[6];
    const float* Ea     = (const float*)d_in[7];
    const float* Eh     = (const float*)d_in[8];
    const float* Ed     = (const float*)d_in[9];
    const float* Ey     = (const float*)d_in[10];
    const float* projW  = (const float*)d_in[11];
    const float* projB  = (const float*)d_in[12];
    const float* sInW   = (const float*)d_in[13];
    const float* sInB   = (const float*)d_in[14];
    const float* mW1    = (const float*)d_in[15];
    const float* mB1    = (const float*)d_in[16];
    const float* mW2    = (const float*)d_in[17];
    const float* mB2    = (const float*)d_in[18];
    const float* sSkW   = (const float*)d_in[19];
    const float* sSkB   = (const float*)d_in[20];
    const float* attnW  = (const float*)d_in[21];
    const float* attnB  = (const float*)d_in[22];
    const float* temp   = (const float*)d_in[23];
    const float* fW1    = (const float*)d_in[24];
    const float* fB1    = (const float*)d_in[25];
    const float* fW2    = (const float*)d_in[26];
    const float* fB2    = (const float*)d_in[27];
    const float* fW3    = (const float*)d_in[28];
    const float* fB3    = (const float*)d_in[29];
    float* out = (float*)d_out;

    char* w = (char*)d_ws;
    auto take = [&](size_t bytes) { void* p = (void*)w; w += (bytes + 255) & ~(size_t)255; return p; };
    __bf16* x      = (__bf16*)take(2L * NNP * H);
    __bf16* agg    = (__bf16*)take(2L * 3 * NNP * H);
    __bf16* hbuf   = (__bf16*)take(2L * NNP * H);
    __bf16* hbuf2  = (__bf16*)take(2L * NNP * H);
    __bf16* gskip  = (__bf16*)take(2L * NNP * H);
    __bf16* pproj  = (__bf16*)take(2L * 256 * H);
    __bf16* pin    = (__bf16*)take(2L * 3 * 512 * H);
    __bf16* psk    = (__bf16*)take(2L * 3 * 512 * H);
    __bf16* pw1    = (__bf16*)take(2L * 6 * 128 * H);
    __bf16* pw2    = (__bf16*)take(2L * 6 * 128 * H);
    __bf16* embb   = (__bf16*)take(2L * 8000);
    float*  scores = (float*)take(4L * NN * NHEADS);
    float*  pooled = (float*)take(4L * NG * H);
    int*    gstart = (int*)take(4L * (NG + 1));
    int*    csr_start = (int*)take(4L * (NROWS + 1));
    unsigned int*   binreg = (unsigned int*)take(4L * NBIN * CAPB);   // 12 MB
    unsigned short* esrc   = (unsigned short*)take(2L * NE);
    int*    gbincur = (int*)take(4L * NBIN);
    int*    bbase   = (int*)take(4L * (NBIN + 1));

    // ---- fused weight pack + emb convert (weights restored each call) ----
    k_packall<<<(630592 + 255) / 256, 256, 0, stream>>>(
        projW, pproj, sInW, pin, sSkW, psk, mW1, pw1, mW2, pw2,
        Ea, Eh, Ed, Ey, embb);

    // ---- CSR build: LDS write-combined binning -> bin scan -> per-bin finalize ----
    hipMemsetAsync(gbincur, 0, sizeof(int) * NBIN, stream);
    k_binA<<<ABLK, 256, 0, stream>>>(target, src, gbincur, binreg);
    k_scanc<<<1, 512, 0, stream>>>(gbincur, bbase);
    k_fill2b<<<NBIN, 512, 0, stream>>>(binreg, gbincur, bbase, csr_start, esrc);

    k_embed_m<<<NNP / 128, 256, 0, stream>>>(atom, hc, deg, hyb, embb, pproj, projB, x);
    k_offsets<<<(NN + 255) / 256, 256, 0, stream>>>(batch, gstart);

    for (int l = 0; l < NL; ++l) {
        k_gather<<<NROWS / 8, 256, 0, stream>>>(esrc, csr_start,
            (const uint2*)x, (uint2*)agg);
        k_shell_m<<<NNP / 128, 256, 0, stream>>>(x, agg,
            pin + (long)l * 512 * H, sInB + l * H,
            psk + (long)l * 512 * H, sSkB + l * H, hbuf, gskip);
        k_mlp_m<<<NNP / 128, 256, 0, stream>>>(hbuf,
            pw1 + (long)(l * NMLP + 0) * 128 * H, mB1 + (long)(l * NMLP + 0) * H,
            pw2 + (long)(l * NMLP + 0) * 128 * H, mB2 + (long)(l * NMLP + 0) * H,
            nullptr, hbuf2);
        k_mlp_m<<<NNP / 128, 256, 0, stream>>>(hbuf2,
            pw1 + (long)(l * NMLP + 1) * 128 * H, mB1 + (long)(l * NMLP + 1) * H,
            pw2 + (long)(l * NMLP + 1) * 128 * H, mB2 + (long)(l * NMLP + 1) * H,
            gskip, x);
    }

    k_scores<<<NN / 4, 256, 0, stream>>>(x, attnW, attnB, temp, scores);
    k_pool<<<NG, 64, 0, stream>>>(x, scores, gstart, pooled);
    k_ffn<<<NG, 128, 0, stream>>>(pooled, fW1, fB1, fW2, fB2, fW3, fB3, out);
}

// Round 8
// 931.791 us; speedup vs baseline: 14.5712x; 1.0223x over previous
//
#include <hip/hip_runtime.h>
#include <math.h>

#define NN      50000
#define NNP     50048          // padded nodes = 391*128
#define NE      2400000
#define NHOPS   3
#define NG      2048
#define H       128
#define EMBD    64
#define NL      3
#define NMLP    2
#define NHEADS  4
#define NROWS   (NHOPS * NN)   // 150000
#define BINSH   9              // 512 rows per coarse bin
#define NBIN    293            // ceil(150016/512)
#define CAPB    10240          // per-bin region capacity (mean 8192 + pad + slack)
#define ABLK    480            // binning blocks: 4/CU by LDS -> latency hiding
#define DEPTH   32             // LDS circular buffer depth per bin
#define LSTR    136
#define SENT    0xFFFFFFFFu    // sentinel (src=0xFFFF impossible: src<50000)

typedef __bf16 bf16x8 __attribute__((ext_vector_type(8)));
typedef __bf16 bf16x4 __attribute__((ext_vector_type(4)));
typedef float  f32x4  __attribute__((ext_vector_type(4)));

__device__ __forceinline__ float silu_f(float v) { return v / (1.0f + expf(-v)); }

__device__ __forceinline__ f32x4 mm(bf16x8 a, bf16x8 b, f32x4 c) {
    return __builtin_amdgcn_mfma_f32_16x16x32_bf16(a, b, c, 0, 0, 0);
}

__device__ __forceinline__ float blo(unsigned v) { return __builtin_bit_cast(float, v << 16); }
__device__ __forceinline__ float bhi(unsigned v) { return __builtin_bit_cast(float, v & 0xffff0000u); }
__device__ __forceinline__ unsigned pk2(float a, float b) {
    unsigned short ua = __builtin_bit_cast(unsigned short, (__bf16)a);
    unsigned short ub = __builtin_bit_cast(unsigned short, (__bf16)b);
    return (unsigned)ua | ((unsigned)ub << 16);
}

// ---------------------------------------------------------------- fused weight pack + emb convert
__device__ __forceinline__ void packw_elem(
    const float* __restrict__ W, __bf16* __restrict__ out, int K, long idx)
{
    long per = (long)K * 128;
    long mat = idx / per, e = idx - mat * per;
    int j = (int)(e & 7), n16 = (int)((e >> 3) & 15), q = (int)((e >> 7) & 3),
        mt = (int)((e >> 9) & 7), kt = (int)(e >> 12);
    int k = kt * 32 + q * 8 + j, n = mt * 16 + n16;
    out[idx] = (__bf16)W[mat * per + (long)k * 128 + n];
}

__global__ __launch_bounds__(256) void k_packall(
    const float* __restrict__ projW, __bf16* __restrict__ pproj,
    const float* __restrict__ sInW,  __bf16* __restrict__ pin,
    const float* __restrict__ sSkW,  __bf16* __restrict__ psk,
    const float* __restrict__ mW1,   __bf16* __restrict__ pw1,
    const float* __restrict__ mW2,   __bf16* __restrict__ pw2,
    const float* __restrict__ Ea, const float* __restrict__ Eh,
    const float* __restrict__ Ed, const float* __restrict__ Ey,
    __bf16* __restrict__ embb)
{
    long tid = (long)blockIdx.x * 256 + threadIdx.x;
    if (tid < 32768) { packw_elem(projW, pproj, 256, tid); return; }
    tid -= 32768;
    if (tid < 196608) { packw_elem(sInW, pin, 512, tid); return; }
    tid -= 196608;
    if (tid < 196608) { packw_elem(sSkW, psk, 512, tid); return; }
    tid -= 196608;
    if (tid < 98304) { packw_elem(mW1, pw1, 128, tid); return; }
    tid -= 98304;
    if (tid < 98304) { packw_elem(mW2, pw2, 128, tid); return; }
    tid -= 98304;
    if (tid < 8000) {
        int t = (int)tid;
        float v;
        if (t < 6400) v = Ea[t];
        else if (t < 6976) v = Eh[t - 6400];
        else if (t < 7488) v = Ed[t - 6976];
        else v = Ey[t - 7488];
        embb[t] = (__bf16)v;
    }
}

// ---------------------------------------------------------------- K0: embed + project + silu (MFMA)
__global__ __launch_bounds__(256) void k_embed_m(
    const int* __restrict__ atom, const int* __restrict__ hc,
    const int* __restrict__ deg,  const int* __restrict__ hyb,
    const __bf16* __restrict__ emb, const __bf16* __restrict__ pw,
    const float* __restrict__ pb, __bf16* __restrict__ x)
{
    const int lane = threadIdx.x & 63, wid = threadIdx.x >> 6;
    const int q = lane >> 4, l16 = lane & 15;
    const int nb = blockIdx.x * 128 + wid * 32;
    int ia[2][4];
#pragma unroll
    for (int nt = 0; nt < 2; ++nt) {
        int n = nb + nt * 16 + l16;
        if (n >= NN) n = NN - 1;
        ia[nt][0] = atom[n]; ia[nt][1] = hc[n]; ia[nt][2] = deg[n]; ia[nt][3] = hyb[n];
    }
    f32x4 acc[2][8];
#pragma unroll
    for (int nt = 0; nt < 2; ++nt)
#pragma unroll
        for (int mt = 0; mt < 8; ++mt) acc[nt][mt] = (f32x4)(0.f);
    const int tb[4] = {0, 6400, 6976, 7488};
    for (int kt = 0; kt < 8; ++kt) {
        int t = kt >> 1;
        int koff = (kt & 1) * 32 + q * 8;
        bf16x8 bfrag[2];
#pragma unroll
        for (int nt = 0; nt < 2; ++nt)
            bfrag[nt] = *(const bf16x8*)(emb + tb[t] + (long)ia[nt][t] * 64 + koff);
        const __bf16* ap = pw + (long)kt * 4096 + lane * 8;
#pragma unroll
        for (int mt = 0; mt < 8; ++mt) {
            bf16x8 a = *(const bf16x8*)(ap + mt * 512);
            acc[0][mt] = mm(a, bfrag[0], acc[0][mt]);
            acc[1][mt] = mm(a, bfrag[1], acc[1][mt]);
        }
    }
#pragma unroll
    for (int nt = 0; nt < 2; ++nt) {
        long node = nb + nt * 16 + l16;
#pragma unroll
        for (int mt = 0; mt < 8; ++mt) {
            int ch = mt * 16 + q * 4;
            float4 bb = *(const float4*)(pb + ch);
            bf16x4 o;
            o[0] = (__bf16)silu_f(acc[nt][mt][0] + bb.x);
            o[1] = (__bf16)silu_f(acc[nt][mt][1] + bb.y);
            o[2] = (__bf16)silu_f(acc[nt][mt][2] + bb.z);
            o[3] = (__bf16)silu_f(acc[nt][mt][3] + bb.w);
            *(bf16x4*)(x + node * 128 + ch) = o;
        }
    }
}

// ---------------------------------------------------------------- CSR pass A: LDS write-combined binning
// Full 16B+ aligned flushes; sentinel-padded tails; real counts in brealc.
__global__ __launch_bounds__(256) void k_binA(
    const int* __restrict__ target, const int* __restrict__ src,
    int* __restrict__ gbincur, int* __restrict__ brealc,
    unsigned int* __restrict__ binreg)
{
    __shared__ unsigned int buf[NBIN][DEPTH];
    __shared__ int cnt[NBIN];
    __shared__ int flushed[NBIN];
    const int tid = threadIdx.x;
    for (int i = tid; i < NBIN; i += 256) { cnt[i] = 0; flushed[i] = 0; }
    __syncthreads();
    const int per = (NE + ABLK - 1) / ABLK;   // 5000
    const int e0 = blockIdx.x * per;
    const int e1 = (e0 + per < NE) ? e0 + per : NE;
    for (int base = e0; base < e1; base += 256) {
        int e = base + tid;
        if (e < e1) {
            int s = src[e];
            if (s >= 2 * NN) s -= 2 * NN; else if (s >= NN) s -= NN;
            int t = target[e];
            int bin = t >> BINSH;
            unsigned val = (unsigned)s | ((unsigned)(t & ((1 << BINSH) - 1)) << 16);
            int slot = atomicAdd(&cnt[bin], 1);
            buf[bin][slot & (DEPTH - 1)] = val;
        }
        __syncthreads();
        for (int b = tid; b < NBIN; b += 256) {
            while (cnt[b] - flushed[b] >= 16) {
                int pos = atomicAdd(&gbincur[b], 16);
                if (pos + 16 <= CAPB) {
                    uint4* d4 = (uint4*)(binreg + (long)b * CAPB + pos);
                    const uint4* s4 = (const uint4*)&buf[b][flushed[b] & (DEPTH - 1)];
                    d4[0] = s4[0]; d4[1] = s4[1]; d4[2] = s4[2]; d4[3] = s4[3];
                }
                flushed[b] += 16;
            }
        }
        __syncthreads();
    }
    // tail: pad to 4-word units with sentinels; record real counts
    for (int b = tid; b < NBIN; b += 256) {
        int lvl = cnt[b] - flushed[b];
        if (cnt[b] > 0) atomicAdd(&brealc[b], cnt[b]);
        if (lvl > 0) {
            int pad = (lvl + 3) & ~3;
            int pos = atomicAdd(&gbincur[b], pad);
            for (int i = 0; i < pad; i += 4) {
                uint4 v;
                v.x = (i + 0 < lvl) ? buf[b][(flushed[b] + i + 0) & (DEPTH - 1)] : SENT;
                v.y = (i + 1 < lvl) ? buf[b][(flushed[b] + i + 1) & (DEPTH - 1)] : SENT;
                v.z = (i + 2 < lvl) ? buf[b][(flushed[b] + i + 2) & (DEPTH - 1)] : SENT;
                v.w = (i + 3 < lvl) ? buf[b][(flushed[b] + i + 3) & (DEPTH - 1)] : SENT;
                if (pos + i + 4 <= CAPB)
                    *(uint4*)(binreg + (long)b * CAPB + pos + i) = v;
            }
        }
    }
}

// ---------------------------------------------------------------- CSR pass B: per-bin LDS finalize
__global__ __launch_bounds__(512) void k_fill2b(
    const unsigned int* __restrict__ binreg, const int* __restrict__ gbincur,
    const int* __restrict__ brealc, int* __restrict__ csr_start,
    unsigned short* __restrict__ esrc)
{
    __shared__ unsigned int stage[CAPB];
    __shared__ int pc[512], rcnt[512], scn[512], cur[512];
    const int b = blockIdx.x, tid = threadIdx.x;
    int pv = (tid < NBIN) ? brealc[tid] : 0;
    if (pv < 0) pv = 0;                      // replay-safety
    pc[tid] = pv;
    __syncthreads();
    for (int off = 1; off < 512; off <<= 1) {
        int t = (tid >= off) ? pc[tid - off] : 0;
        __syncthreads();
        pc[tid] += t;
        __syncthreads();
    }
    int bbase = (b == 0) ? 0 : pc[b - 1];
    int total = gbincur[b];
    if (total > CAPB) total = CAPB;
    if (total < 0) total = 0;
    const unsigned int* seg = binreg + (long)b * CAPB;
    for (int i = tid; i < total; i += 512) stage[i] = seg[i];
    rcnt[tid] = 0;
    __syncthreads();
    for (int i = tid; i < total; i += 512) {
        unsigned pk = stage[i];
        if (pk != SENT) atomicAdd(&rcnt[(pk >> 16) & 511], 1);
    }
    __syncthreads();
    int v = rcnt[tid];
    scn[tid] = v;
    __syncthreads();
    for (int off = 1; off < 512; off <<= 1) {
        int t = (tid >= off) ? scn[tid - off] : 0;
        __syncthreads();
        scn[tid] += t;
        __syncthreads();
    }
    int base = bbase + scn[tid] - v;
    cur[tid] = base;
    int row = b * 512 + tid;
    if (row <= NROWS) csr_start[row] = base;
    __syncthreads();
    for (int i = tid; i < total; i += 512) {
        unsigned pk = stage[i];
        if (pk != SENT) {
            int pos = atomicAdd(&cur[(pk >> 16) & 511], 1);
            if (pos >= 0 && pos < NE) esrc[pos] = (unsigned short)(pk & 0xffffu);
        }
    }
}

// ---------------------------------------------------------------- K1: CSR gather, 4 rows/wave, uint4 loads
__global__ __launch_bounds__(256) void k_gather(
    const unsigned short* __restrict__ esrc, const int* __restrict__ csr_start,
    const uint4* __restrict__ x8, uint4* __restrict__ agg8)
{
    int row = blockIdx.x * 16 + (threadIdx.x >> 4);
    int lane = threadIdx.x & 63;
    int l4 = lane & 15, qw = lane >> 4;
    int e0 = csr_start[row], e1 = csr_start[row + 1];
    if ((unsigned)e0 > NE || (unsigned)e1 > NE || e1 < e0) { e0 = 0; e1 = 0; }  // replay-safety
    int nch = (e1 - e0 + 15) >> 4;
    int n0 = __shfl(nch, 0, 64), n1 = __shfl(nch, 16, 64);
    int n2 = __shfl(nch, 32, 64), n3 = __shfl(nch, 48, 64);
    int nmax = max(max(n0, n1), max(n2, n3));
    float a0 = 0.f, a1 = 0.f, a2 = 0.f, a3 = 0.f, a4 = 0.f, a5 = 0.f, a6 = 0.f, a7 = 0.f;
    const int sb = qw << 4;
    for (int c = 0; c < nmax; ++c) {
        int base = e0 + c * 16;
        int rem = e1 - base;
        int pre = (l4 < rem) ? (int)esrc[base + l4] : 0;
        int m = rem < 16 ? (rem < 0 ? 0 : rem) : 16;
        int j = 0;
        for (; j + 3 < m; j += 4) {
            int sA = __shfl(pre, sb + j, 64);
            int sB = __shfl(pre, sb + j + 1, 64);
            int sC = __shfl(pre, sb + j + 2, 64);
            int sD = __shfl(pre, sb + j + 3, 64);
            uint4 v0 = x8[(long)sA * 16 + l4];
            uint4 v1 = x8[(long)sB * 16 + l4];
            uint4 v2 = x8[(long)sC * 16 + l4];
            uint4 v3 = x8[(long)sD * 16 + l4];
            a0 += blo(v0.x) + blo(v1.x) + blo(v2.x) + blo(v3.x);
            a1 += bhi(v0.x) + bhi(v1.x) + bhi(v2.x) + bhi(v3.x);
            a2 += blo(v0.y) + blo(v1.y) + blo(v2.y) + blo(v3.y);
            a3 += bhi(v0.y) + bhi(v1.y) + bhi(v2.y) + bhi(v3.y);
            a4 += blo(v0.z) + blo(v1.z) + blo(v2.z) + blo(v3.z);
            a5 += bhi(v0.z) + bhi(v1.z) + bhi(v2.z) + bhi(v3.z);
            a6 += blo(v0.w) + blo(v1.w) + blo(v2.w) + blo(v3.w);
            a7 += bhi(v0.w) + bhi(v1.w) + bhi(v2.w) + bhi(v3.w);
        }
        for (; j < m; ++j) {
            int sA = __shfl(pre, sb + j, 64);
            uint4 v0 = x8[(long)sA * 16 + l4];
            a0 += blo(v0.x); a1 += bhi(v0.x); a2 += blo(v0.y); a3 += bhi(v0.y);
            a4 += blo(v0.z); a5 += bhi(v0.z); a6 += blo(v0.w); a7 += bhi(v0.w);
        }
    }
    int hop = row / NN, node = row - hop * NN;
    uint4 o;
    o.x = pk2(a0, a1); o.y = pk2(a2, a3); o.z = pk2(a4, a5); o.w = pk2(a6, a7);
    agg8[((long)hop * NNP + node) * 16 + l4] = o;
}

// ---------------------------------------------------------------- K2: shell_in + skip (MFMA, K=512)
__global__ __launch_bounds__(256) void k_shell_m(
    const __bf16* __restrict__ x, const __bf16* __restrict__ agg,
    const __bf16* __restrict__ pwin, const float* __restrict__ bin,
    const __bf16* __restrict__ pwsk, const float* __restrict__ bsk,
    __bf16* __restrict__ h, __bf16* __restrict__ gskip)
{
    const int lane = threadIdx.x & 63, wid = threadIdx.x >> 6;
    const int q = lane >> 4, l16 = lane & 15;
    const int nb = blockIdx.x * 128 + wid * 32;
    f32x4 aci[2][8], acs[2][8];
#pragma unroll
    for (int nt = 0; nt < 2; ++nt)
#pragma unroll
        for (int mt = 0; mt < 8; ++mt) { aci[nt][mt] = (f32x4)(0.f); acs[nt][mt] = (f32x4)(0.f); }
    const __bf16* planes[4] = {x, agg, agg + (long)NNP * 128, agg + 2L * NNP * 128};
    for (int kt = 0; kt < 16; ++kt) {
        const __bf16* src = planes[kt >> 2];
        int koff = (kt & 3) * 32 + q * 8;
        bf16x8 bfrag[2];
#pragma unroll
        for (int nt = 0; nt < 2; ++nt)
            bfrag[nt] = *(const bf16x8*)(src + (long)(nb + nt * 16 + l16) * 128 + koff);
        const __bf16* aip = pwin + (long)kt * 4096 + lane * 8;
        const __bf16* asp = pwsk + (long)kt * 4096 + lane * 8;
#pragma unroll
        for (int mt = 0; mt < 8; ++mt) {
            bf16x8 ai = *(const bf16x8*)(aip + mt * 512);
            bf16x8 as = *(const bf16x8*)(asp + mt * 512);
            aci[0][mt] = mm(ai, bfrag[0], aci[0][mt]);
            aci[1][mt] = mm(ai, bfrag[1], aci[1][mt]);
            acs[0][mt] = mm(as, bfrag[0], acs[0][mt]);
            acs[1][mt] = mm(as, bfrag[1], acs[1][mt]);
        }
    }
#pragma unroll
    for (int nt = 0; nt < 2; ++nt) {
        long node = nb + nt * 16 + l16;
#pragma unroll
        for (int mt = 0; mt < 8; ++mt) {
            int ch = mt * 16 + q * 4;
            float4 bi = *(const float4*)(bin + ch);
            float4 bs = *(const float4*)(bsk + ch);
            bf16x4 oh, og;
            oh[0] = (__bf16)silu_f(aci[nt][mt][0] + bi.x); og[0] = (__bf16)(acs[nt][mt][0] + bs.x);
            oh[1] = (__bf16)silu_f(aci[nt][mt][1] + bi.y); og[1] = (__bf16)(acs[nt][mt][1] + bs.y);
            oh[2] = (__bf16)silu_f(aci[nt][mt][2] + bi.z); og[2] = (__bf16)(acs[nt][mt][2] + bs.z);
            oh[3] = (__bf16)silu_f(aci[nt][mt][3] + bi.w); og[3] = (__bf16)(acs[nt][mt][3] + bs.w);
            *(bf16x4*)(h + node * 128 + ch) = oh;
            *(bf16x4*)(gskip + node * 128 + ch) = og;
        }
    }
}

// ---------------------------------------------------------------- K3: fully fused 2x residual MLP (MFMA)
__global__ __launch_bounds__(256) void k_mlp2_m(
    const __bf16* __restrict__ hin,
    const __bf16* __restrict__ pw1a, const float* __restrict__ b1a,
    const __bf16* __restrict__ pw2a, const float* __restrict__ b2a,
    const __bf16* __restrict__ pw1b, const float* __restrict__ b1b,
    const __bf16* __restrict__ pw2b, const float* __restrict__ b2b,
    const __bf16* __restrict__ gskip, __bf16* __restrict__ xout)
{
    __shared__ __bf16 lds[4][32 * LSTR];
    const int lane = threadIdx.x & 63, wid = threadIdx.x >> 6;
    const int q = lane >> 4, l16 = lane & 15;
    const int nb = blockIdx.x * 128 + wid * 32;
    __bf16* L = lds[wid];
    bf16x4 skipreg[2][8];
    f32x4 acc[2][8];

    // p0: t1 = silu(hin @ W1a + b1a) -> LDS
#pragma unroll
    for (int nt = 0; nt < 2; ++nt)
#pragma unroll
        for (int mt = 0; mt < 8; ++mt) acc[nt][mt] = (f32x4)(0.f);
    for (int kt = 0; kt < 4; ++kt) {
        int koff = kt * 32 + q * 8;
        bf16x8 bfrag[2];
#pragma unroll
        for (int nt = 0; nt < 2; ++nt)
            bfrag[nt] = *(const bf16x8*)(hin + (long)(nb + nt * 16 + l16) * 128 + koff);
        const __bf16* ap = pw1a + (long)kt * 4096 + lane * 8;
#pragma unroll
        for (int mt = 0; mt < 8; ++mt) {
            bf16x8 a = *(const bf16x8*)(ap + mt * 512);
            acc[0][mt] = mm(a, bfrag[0], acc[0][mt]);
            acc[1][mt] = mm(a, bfrag[1], acc[1][mt]);
        }
    }
#pragma unroll
    for (int nt = 0; nt < 2; ++nt)
#pragma unroll
        for (int mt = 0; mt < 8; ++mt) {
            int ch = mt * 16 + q * 4;
            float4 bb = *(const float4*)(b1a + ch);
            bf16x4 o;
            o[0] = (__bf16)silu_f(acc[nt][mt][0] + bb.x);
            o[1] = (__bf16)silu_f(acc[nt][mt][1] + bb.y);
            o[2] = (__bf16)silu_f(acc[nt][mt][2] + bb.z);
            o[3] = (__bf16)silu_f(acc[nt][mt][3] + bb.w);
            *(bf16x4*)(L + (nt * 16 + l16) * LSTR + ch) = o;
        }
    __syncthreads();

    // p1: h2 = t1 @ W2a + b2a + hin -> LDS (in place) + skipreg
#pragma unroll
    for (int nt = 0; nt < 2; ++nt)
#pragma unroll
        for (int mt = 0; mt < 8; ++mt) acc[nt][mt] = (f32x4)(0.f);
    for (int kt = 0; kt < 4; ++kt) {
        int koff = kt * 32 + q * 8;
        bf16x8 bfrag[2];
#pragma unroll
        for (int nt = 0; nt < 2; ++nt)
            bfrag[nt] = *(const bf16x8*)(L + (nt * 16 + l16) * LSTR + koff);
        const __bf16* ap = pw2a + (long)kt * 4096 + lane * 8;
#pragma unroll
        for (int mt = 0; mt < 8; ++mt) {
            bf16x8 a = *(const bf16x8*)(ap + mt * 512);
            acc[0][mt] = mm(a, bfrag[0], acc[0][mt]);
            acc[1][mt] = mm(a, bfrag[1], acc[1][mt]);
        }
    }
    __syncthreads();   // all reads of t1 done before overwrite
#pragma unroll
    for (int nt = 0; nt < 2; ++nt) {
        long node = nb + nt * 16 + l16;
#pragma unroll
        for (int mt = 0; mt < 8; ++mt) {
            int ch = mt * 16 + q * 4;
            float4 bb = *(const float4*)(b2a + ch);
            bf16x4 sk = *(const bf16x4*)(hin + node * 128 + ch);
            bf16x4 o;
            o[0] = (__bf16)(acc[nt][mt][0] + bb.x + (float)sk[0]);
            o[1] = (__bf16)(acc[nt][mt][1] + bb.y + (float)sk[1]);
            o[2] = (__bf16)(acc[nt][mt][2] + bb.z + (float)sk[2]);
            o[3] = (__bf16)(acc[nt][mt][3] + bb.w + (float)sk[3]);
            skipreg[nt][mt] = o;
            *(bf16x4*)(L + (nt * 16 + l16) * LSTR + ch) = o;
        }
    }
    __syncthreads();

    // p2: t2 = silu(h2 @ W1b + b1b) -> LDS (in place)
#pragma unroll
    for (int nt = 0; nt < 2; ++nt)
#pragma unroll
        for (int mt = 0; mt < 8; ++mt) acc[nt][mt] = (f32x4)(0.f);
    for (int kt = 0; kt < 4; ++kt) {
        int koff = kt * 32 + q * 8;
        bf16x8 bfrag[2];
#pragma unroll
        for (int nt = 0; nt < 2; ++nt)
            bfrag[nt] = *(const bf16x8*)(L + (nt * 16 + l16) * LSTR + koff);
        const __bf16* ap = pw1b + (long)kt * 4096 + lane * 8;
#pragma unroll
        for (int mt = 0; mt < 8; ++mt) {
            bf16x8 a = *(const bf16x8*)(ap + mt * 512);
            acc[0][mt] = mm(a, bfrag[0], acc[0][mt]);
            acc[1][mt] = mm(a, bfrag[1], acc[1][mt]);
        }
    }
    __syncthreads();
#pragma unroll
    for (int nt = 0; nt < 2; ++nt)
#pragma unroll
        for (int mt = 0; mt < 8; ++mt) {
            int ch = mt * 16 + q * 4;
            float4 bb = *(const float4*)(b1b + ch);
            bf16x4 o;
            o[0] = (__bf16)silu_f(acc[nt][mt][0] + bb.x);
            o[1] = (__bf16)silu_f(acc[nt][mt][1] + bb.y);
            o[2] = (__bf16)silu_f(acc[nt][mt][2] + bb.z);
            o[3] = (__bf16)silu_f(acc[nt][mt][3] + bb.w);
            *(bf16x4*)(L + (nt * 16 + l16) * LSTR + ch) = o;
        }
    __syncthreads();

    // p3: x = t2 @ W2b + b2b + h2(skipreg) + gskip -> global
#pragma unroll
    for (int nt = 0; nt < 2; ++nt)
#pragma unroll
        for (int mt = 0; mt < 8; ++mt) acc[nt][mt] = (f32x4)(0.f);
    for (int kt = 0; kt < 4; ++kt) {
        int koff = kt * 32 + q * 8;
        bf16x8 bfrag[2];
#pragma unroll
        for (int nt = 0; nt < 2; ++nt)
            bfrag[nt] = *(const bf16x8*)(L + (nt * 16 + l16) * LSTR + koff);
        const __bf16* ap = pw2b + (long)kt * 4096 + lane * 8;
#pragma unroll
        for (int mt = 0; mt < 8; ++mt) {
            bf16x8 a = *(const bf16x8*)(ap + mt * 512);
            acc[0][mt] = mm(a, bfrag[0], acc[0][mt]);
            acc[1][mt] = mm(a, bfrag[1], acc[1][mt]);
        }
    }
#pragma unroll
    for (int nt = 0; nt < 2; ++nt) {
        long node = nb + nt * 16 + l16;
#pragma unroll
        for (int mt = 0; mt < 8; ++mt) {
            int ch = mt * 16 + q * 4;
            float4 bb = *(const float4*)(b2b + ch);
            bf16x4 sk = skipreg[nt][mt];
            bf16x4 g = *(const bf16x4*)(gskip + node * 128 + ch);
            bf16x4 o;
            o[0] = (__bf16)(acc[nt][mt][0] + bb.x + (float)sk[0] + (float)g[0]);
            o[1] = (__bf16)(acc[nt][mt][1] + bb.y + (float)sk[1] + (float)g[1]);
            o[2] = (__bf16)(acc[nt][mt][2] + bb.z + (float)sk[2] + (float)g[2]);
            o[3] = (__bf16)(acc[nt][mt][3] + bb.w + (float)sk[3] + (float)g[3]);
            *(bf16x4*)(xout + node * 128 + ch) = o;
        }
    }
}

// ---------------------------------------------------------------- K4: attention scores
__global__ __launch_bounds__(256) void k_scores(
    const __bf16* __restrict__ x, const float* __restrict__ aw,
    const float* __restrict__ ab, const float* __restrict__ temp,
    float* __restrict__ scores)
{
    int wave = threadIdx.x >> 6, lane = threadIdx.x & 63;
    int n = blockIdx.x * 4 + wave;
    if (n >= NN) return;
    float x0 = (float)x[(long)n * H + lane];
    float x1 = (float)x[(long)n * H + 64 + lane];
    float T = temp[0];
#pragma unroll
    for (int hh = 0; hh < NHEADS; ++hh) {
        float p = x0 * aw[hh * H + lane] + x1 * aw[hh * H + 64 + lane];
#pragma unroll
        for (int off = 32; off >= 1; off >>= 1) p += __shfl_xor(p, off, 64);
        if (lane == 0) scores[n * NHEADS + hh] = (p + ab[hh]) / T;
    }
}

// ---------------------------------------------------------------- K5: graph offsets
__global__ __launch_bounds__(256) void k_offsets(
    const int* __restrict__ batch, int* __restrict__ gstart)
{
    int n = blockIdx.x * 256 + threadIdx.x;
    if (n >= NN) return;
    int b = batch[n];
    int bp = (n == 0) ? -1 : batch[n - 1];
    for (int g = bp + 1; g <= b; ++g) gstart[g] = n;
    if (n == NN - 1) for (int g = b + 1; g <= NG; ++g) gstart[g] = NN;
}

// ---------------------------------------------------------------- K6: softmax pool
__global__ __launch_bounds__(64) void k_pool(
    const __bf16* __restrict__ x, const float* __restrict__ scores,
    const int* __restrict__ gstart, float* __restrict__ pooled)
{
    int g = blockIdx.x, lane = threadIdx.x;
    int s0 = gstart[g], s1 = gstart[g + 1];
    float m0 = -INFINITY, m1 = -INFINITY, m2 = -INFINITY, m3 = -INFINITY;
    for (int n = s0 + lane; n < s1; n += 64) {
        m0 = fmaxf(m0, scores[n * 4 + 0]); m1 = fmaxf(m1, scores[n * 4 + 1]);
        m2 = fmaxf(m2, scores[n * 4 + 2]); m3 = fmaxf(m3, scores[n * 4 + 3]);
    }
#pragma unroll
    for (int off = 32; off >= 1; off >>= 1) {
        m0 = fmaxf(m0, __shfl_xor(m0, off, 64)); m1 = fmaxf(m1, __shfl_xor(m1, off, 64));
        m2 = fmaxf(m2, __shfl_xor(m2, off, 64)); m3 = fmaxf(m3, __shfl_xor(m3, off, 64));
    }
    float d0 = 0.f, d1 = 0.f, d2 = 0.f, d3 = 0.f;
    for (int n = s0 + lane; n < s1; n += 64) {
        d0 += expf(scores[n * 4 + 0] - m0); d1 += expf(scores[n * 4 + 1] - m1);
        d2 += expf(scores[n * 4 + 2] - m2); d3 += expf(scores[n * 4 + 3] - m3);
    }
#pragma unroll
    for (int off = 32; off >= 1; off >>= 1) {
        d0 += __shfl_xor(d0, off, 64); d1 += __shfl_xor(d1, off, 64);
        d2 += __shfl_xor(d2, off, 64); d3 += __shfl_xor(d3, off, 64);
    }
    float i0 = d0 > 0.f ? 1.f / d0 : 0.f;
    float i1 = d1 > 0.f ? 1.f / d1 : 0.f;
    float i2 = d2 > 0.f ? 1.f / d2 : 0.f;
    float i3 = d3 > 0.f ? 1.f / d3 : 0.f;
    float a0 = 0.f, a1 = 0.f;
    for (int n = s0; n < s1; ++n) {
        float wb = expf(scores[n * 4 + 0] - m0) * i0 + expf(scores[n * 4 + 1] - m1) * i1
                 + expf(scores[n * 4 + 2] - m2) * i2 + expf(scores[n * 4 + 3] - m3) * i3;
        wb *= 0.25f;
        a0 += wb * (float)x[(long)n * H + lane];
        a1 += wb * (float)x[(long)n * H + 64 + lane];
    }
    pooled[g * H + lane] = a0;
    pooled[g * H + 64 + lane] = a1;
}

// ---------------------------------------------------------------- K7: FFN readout
__global__ __launch_bounds__(128) void k_ffn(
    const float* __restrict__ pooled,
    const float* __restrict__ W1, const float* __restrict__ B1,
    const float* __restrict__ W2, const float* __restrict__ B2,
    const float* __restrict__ W3, const float* __restrict__ B3,
    float* __restrict__ out)
{
    __shared__ float p[H], t1[H], t2[H], red[H];
    int g = blockIdx.x, c = threadIdx.x;
    p[c] = pooled[g * H + c];
    __syncthreads();
    float acc = 0.f;
    for (int k = 0; k < H; ++k) acc += p[k] * W1[k * H + c];
    t1[c] = silu_f(acc + B1[c]);
    __syncthreads();
    acc = 0.f;
    for (int k = 0; k < H; ++k) acc += t1[k] * W2[k * H + c];
    t2[c] = silu_f(acc + B2[c]);
    __syncthreads();
    red[c] = t2[c] * W3[c];
    __syncthreads();
    for (int off = 64; off >= 1; off >>= 1) {
        if (c < off) red[c] += red[c + off];
        __syncthreads();
    }
    if (c == 0) out[g] = red[0] + B3[0];
}

// ---------------------------------------------------------------- launch
extern "C" void kernel_launch(void* const* d_in, const int* in_sizes, int n_in,
                              void* d_out, int out_size, void* d_ws, size_t ws_size,
                              hipStream_t stream)
{
    const int*   atom   = (const int*)d_in[0];
    const int*   hc     = (const int*)d_in[1];
    const int*   deg    = (const int*)d_in[2];
    const int*   hyb    = (const int*)d_in[3];
    const int*   target = (const int*)d_in[4];
    const int*   src    = (const int*)d_in[5];
    const int*   batch  = (const int*)d_in[6];
    const float* Ea     = (const float*)d_in[7];
    const float* Eh     = (const float*)d_in[8];
    const float* Ed     = (const float*)d_in[9];
    const float* Ey     = (const float*)d_in[10];
    const float* projW  = (const float*)d_in[11];
    const float* projB  = (const float*)d_in[12];
    const float* sInW   = (const float*)d_in[13];
    const float* sInB   = (const float*)d_in[14];
    const float* mW1    = (const float*)d_in[15];
    const float* mB1    = (const float*)d_in[16];
    const float* mW2    = (const float*)d_in[17];
    const float* mB2    = (const float*)d_in[18];
    const float* sSkW   = (const float*)d_in[19];
    const float* sSkB   = (const float*)d_in[20];
    const float* attnW  = (const float*)d_in[21];
    const float* attnB  = (const float*)d_in[22];
    const float* temp   = (const float*)d_in[23];
    const float* fW1    = (const float*)d_in[24];
    const float* fB1    = (const float*)d_in[25];
    const float* fW2    = (const float*)d_in[26];
    const float* fB2    = (const float*)d_in[27];
    const float* fW3    = (const float*)d_in[28];
    const float* fB3    = (const float*)d_in[29];
    float* out = (float*)d_out;

    char* w = (char*)d_ws;
    auto take = [&](size_t bytes) { void* p = (void*)w; w += (bytes + 255) & ~(size_t)255; return p; };
    __bf16* x      = (__bf16*)take(2L * NNP * H);
    __bf16* agg    = (__bf16*)take(2L * 3 * NNP * H);
    __bf16* hbuf   = (__bf16*)take(2L * NNP * H);
    __bf16* gskip  = (__bf16*)take(2L * NNP * H);
    __bf16* pproj  = (__bf16*)take(2L * 256 * H);
    __bf16* pin    = (__bf16*)take(2L * 3 * 512 * H);
    __bf16* psk    = (__bf16*)take(2L * 3 * 512 * H);
    __bf16* pw1    = (__bf16*)take(2L * 6 * 128 * H);
    __bf16* pw2    = (__bf16*)take(2L * 6 * 128 * H);
    __bf16* embb   = (__bf16*)take(2L * 8000);
    float*  scores = (float*)take(4L * NN * NHEADS);
    float*  pooled = (float*)take(4L * NG * H);
    int*    gstart = (int*)take(4L * (NG + 1));
    int*    csr_start = (int*)take(4L * (NROWS + 1));
    unsigned int*   binreg = (unsigned int*)take(4L * NBIN * CAPB);   // 12 MB
    unsigned short* esrc   = (unsigned short*)take(2L * NE);
    // gbincur + brealc in ONE contiguous allocation so a single memset covers both
    // (separate take()s are 256B-rounded -> R6's fused memset left brealc[266..292] poisoned)
    int*    gbincur = (int*)take(4L * 2 * NBIN);
    int*    brealc  = gbincur + NBIN;

    // ---- fused weight pack + emb convert (weights restored each call) ----
    k_packall<<<(630592 + 255) / 256, 256, 0, stream>>>(
        projW, pproj, sInW, pin, sSkW, psk, mW1, pw1, mW2, pw2,
        Ea, Eh, Ed, Ey, embb);

    // ---- CSR build: write-combined binning -> per-bin finalize ----
    hipMemsetAsync(gbincur, 0, sizeof(int) * 2 * NBIN, stream);
    k_binA<<<ABLK, 256, 0, stream>>>(target, src, gbincur, brealc, binreg);
    k_fill2b<<<NBIN, 512, 0, stream>>>(binreg, gbincur, brealc, csr_start, esrc);

    k_embed_m<<<NNP / 128, 256, 0, stream>>>(atom, hc, deg, hyb, embb, pproj, projB, x);
    k_offsets<<<(NN + 255) / 256, 256, 0, stream>>>(batch, gstart);

    for (int l = 0; l < NL; ++l) {
        k_gather<<<NROWS / 16, 256, 0, stream>>>(esrc, csr_start,
            (const uint4*)x, (uint4*)agg);
        k_shell_m<<<NNP / 128, 256, 0, stream>>>(x, agg,
            pin + (long)l * 512 * H, sInB + l * H,
            psk + (long)l * 512 * H, sSkB + l * H, hbuf, gskip);
        k_mlp2_m<<<NNP / 128, 256, 0, stream>>>(hbuf,
            pw1 + (long)(l * NMLP + 0) * 128 * H, mB1 + (long)(l * NMLP + 0) * H,
            pw2 + (long)(l * NMLP + 0) * 128 * H, mB2 + (long)(l * NMLP + 0) * H,
            pw1 + (long)(l * NMLP + 1) * 128 * H, mB1 + (long)(l * NMLP + 1) * H,
            pw2 + (long)(l * NMLP + 1) * 128 * H, mB2 + (long)(l * NMLP + 1) * H,
            gskip, x);
    }

    k_scores<<<NN / 4, 256, 0, stream>>>(x, attnW, attnB, temp, scores);
    k_pool<<<NG, 64, 0, stream>>>(x, scores, gstart, pooled);
    k_ffn<<<NG, 128, 0, stream>>>(pooled, fW1, fB1, fW2, fB2, fW3, fB3, out);
}

// Round 9
// 845.617 us; speedup vs baseline: 16.0561x; 1.1019x over previous
//
#include <hip/hip_runtime.h>
#include <math.h>

#define NN      50000
#define NNP     50048          // padded nodes = 391*128
#define NE      2400000
#define NHOPS   3
#define NG      2048
#define H       128
#define EMBD    64
#define NL      3
#define NMLP    2
#define NHEADS  4
#define NROWS   (NHOPS * NN)   // 150000
#define BINSH   9              // 512 rows per coarse bin
#define NBIN    293            // ceil(150016/512)
#define CAPB    10240          // per-bin region capacity
#define ABLK    480            // binning blocks
#define DEPTH   32             // LDS circular buffer depth per bin
#define LSTR    136
#define SENT    0xFFFFFFFFu

typedef __bf16 bf16x8 __attribute__((ext_vector_type(8)));
typedef __bf16 bf16x4 __attribute__((ext_vector_type(4)));
typedef float  f32x4  __attribute__((ext_vector_type(4)));

__device__ __forceinline__ float silu_f(float v) { return v / (1.0f + expf(-v)); }

__device__ __forceinline__ f32x4 mm(bf16x8 a, bf16x8 b, f32x4 c) {
    return __builtin_amdgcn_mfma_f32_16x16x32_bf16(a, b, c, 0, 0, 0);
}

__device__ __forceinline__ float blo(unsigned v) { return __builtin_bit_cast(float, v << 16); }
__device__ __forceinline__ float bhi(unsigned v) { return __builtin_bit_cast(float, v & 0xffff0000u); }
__device__ __forceinline__ unsigned pk2(float a, float b) {
    unsigned short ua = __builtin_bit_cast(unsigned short, (__bf16)a);
    unsigned short ub = __builtin_bit_cast(unsigned short, (__bf16)b);
    return (unsigned)ua | ((unsigned)ub << 16);
}

// ---------------------------------------------------------------- fused weight pack + emb convert
__device__ __forceinline__ void packw_elem(
    const float* __restrict__ W, __bf16* __restrict__ out, int K, long idx)
{
    long per = (long)K * 128;
    long mat = idx / per, e = idx - mat * per;
    int j = (int)(e & 7), n16 = (int)((e >> 3) & 15), q = (int)((e >> 7) & 3),
        mt = (int)((e >> 9) & 7), kt = (int)(e >> 12);
    int k = kt * 32 + q * 8 + j, n = mt * 16 + n16;
    out[idx] = (__bf16)W[mat * per + (long)k * 128 + n];
}

__global__ __launch_bounds__(256) void k_packall(
    const float* __restrict__ projW, __bf16* __restrict__ pproj,
    const float* __restrict__ sInW,  __bf16* __restrict__ pin,
    const float* __restrict__ sSkW,  __bf16* __restrict__ psk,
    const float* __restrict__ mW1,   __bf16* __restrict__ pw1,
    const float* __restrict__ mW2,   __bf16* __restrict__ pw2,
    const float* __restrict__ Ea, const float* __restrict__ Eh,
    const float* __restrict__ Ed, const float* __restrict__ Ey,
    __bf16* __restrict__ embb)
{
    long tid = (long)blockIdx.x * 256 + threadIdx.x;
    if (tid < 32768) { packw_elem(projW, pproj, 256, tid); return; }
    tid -= 32768;
    if (tid < 196608) { packw_elem(sInW, pin, 512, tid); return; }
    tid -= 196608;
    if (tid < 196608) { packw_elem(sSkW, psk, 512, tid); return; }
    tid -= 196608;
    if (tid < 98304) { packw_elem(mW1, pw1, 128, tid); return; }
    tid -= 98304;
    if (tid < 98304) { packw_elem(mW2, pw2, 128, tid); return; }
    tid -= 98304;
    if (tid < 8000) {
        int t = (int)tid;
        float v;
        if (t < 6400) v = Ea[t];
        else if (t < 6976) v = Eh[t - 6400];
        else if (t < 7488) v = Ed[t - 6976];
        else v = Ey[t - 7488];
        embb[t] = (__bf16)v;
    }
}

// ---------------------------------------------------------------- K0: embed + project + silu (MFMA)
__global__ __launch_bounds__(256) void k_embed_m(
    const int* __restrict__ atom, const int* __restrict__ hc,
    const int* __restrict__ deg,  const int* __restrict__ hyb,
    const __bf16* __restrict__ emb, const __bf16* __restrict__ pw,
    const float* __restrict__ pb, __bf16* __restrict__ x)
{
    const int lane = threadIdx.x & 63, wid = threadIdx.x >> 6;
    const int q = lane >> 4, l16 = lane & 15;
    const int nb = blockIdx.x * 128 + wid * 32;
    int ia[2][4];
#pragma unroll
    for (int nt = 0; nt < 2; ++nt) {
        int n = nb + nt * 16 + l16;
        if (n >= NN) n = NN - 1;
        ia[nt][0] = atom[n]; ia[nt][1] = hc[n]; ia[nt][2] = deg[n]; ia[nt][3] = hyb[n];
    }
    f32x4 acc[2][8];
#pragma unroll
    for (int nt = 0; nt < 2; ++nt)
#pragma unroll
        for (int mt = 0; mt < 8; ++mt) acc[nt][mt] = (f32x4)(0.f);
    const int tb[4] = {0, 6400, 6976, 7488};
    for (int kt = 0; kt < 8; ++kt) {
        int t = kt >> 1;
        int koff = (kt & 1) * 32 + q * 8;
        bf16x8 bfrag[2];
#pragma unroll
        for (int nt = 0; nt < 2; ++nt)
            bfrag[nt] = *(const bf16x8*)(emb + tb[t] + (long)ia[nt][t] * 64 + koff);
        const __bf16* ap = pw + (long)kt * 4096 + lane * 8;
#pragma unroll
        for (int mt = 0; mt < 8; ++mt) {
            bf16x8 a = *(const bf16x8*)(ap + mt * 512);
            acc[0][mt] = mm(a, bfrag[0], acc[0][mt]);
            acc[1][mt] = mm(a, bfrag[1], acc[1][mt]);
        }
    }
#pragma unroll
    for (int nt = 0; nt < 2; ++nt) {
        long node = nb + nt * 16 + l16;
#pragma unroll
        for (int mt = 0; mt < 8; ++mt) {
            int ch = mt * 16 + q * 4;
            float4 bb = *(const float4*)(pb + ch);
            bf16x4 o;
            o[0] = (__bf16)silu_f(acc[nt][mt][0] + bb.x);
            o[1] = (__bf16)silu_f(acc[nt][mt][1] + bb.y);
            o[2] = (__bf16)silu_f(acc[nt][mt][2] + bb.z);
            o[3] = (__bf16)silu_f(acc[nt][mt][3] + bb.w);
            *(bf16x4*)(x + node * 128 + ch) = o;
        }
    }
}

// ---------------------------------------------------------------- CSR pass A: LDS write-combined binning
__global__ __launch_bounds__(256) void k_binA(
    const int* __restrict__ target, const int* __restrict__ src,
    int* __restrict__ gbincur, int* __restrict__ brealc,
    unsigned int* __restrict__ binreg)
{
    __shared__ unsigned int buf[NBIN][DEPTH];
    __shared__ int cnt[NBIN];
    __shared__ int flushed[NBIN];
    const int tid = threadIdx.x;
    for (int i = tid; i < NBIN; i += 256) { cnt[i] = 0; flushed[i] = 0; }
    __syncthreads();
    const int per = (NE + ABLK - 1) / ABLK;   // 5000
    const int e0 = blockIdx.x * per;
    const int e1 = (e0 + per < NE) ? e0 + per : NE;
    for (int base = e0; base < e1; base += 256) {
        int e = base + tid;
        if (e < e1) {
            int s = src[e];
            if (s >= 2 * NN) s -= 2 * NN; else if (s >= NN) s -= NN;
            int t = target[e];
            int bin = t >> BINSH;
            unsigned val = (unsigned)s | ((unsigned)(t & ((1 << BINSH) - 1)) << 16);
            int slot = atomicAdd(&cnt[bin], 1);
            buf[bin][slot & (DEPTH - 1)] = val;
        }
        __syncthreads();
        for (int b = tid; b < NBIN; b += 256) {
            while (cnt[b] - flushed[b] >= 16) {
                int pos = atomicAdd(&gbincur[b], 16);
                if (pos + 16 <= CAPB) {
                    uint4* d4 = (uint4*)(binreg + (long)b * CAPB + pos);
                    const uint4* s4 = (const uint4*)&buf[b][flushed[b] & (DEPTH - 1)];
                    d4[0] = s4[0]; d4[1] = s4[1]; d4[2] = s4[2]; d4[3] = s4[3];
                }
                flushed[b] += 16;
            }
        }
        __syncthreads();
    }
    for (int b = tid; b < NBIN; b += 256) {
        int lvl = cnt[b] - flushed[b];
        if (cnt[b] > 0) atomicAdd(&brealc[b], cnt[b]);
        if (lvl > 0) {
            int pad = (lvl + 3) & ~3;
            int pos = atomicAdd(&gbincur[b], pad);
            for (int i = 0; i < pad; i += 4) {
                uint4 v;
                v.x = (i + 0 < lvl) ? buf[b][(flushed[b] + i + 0) & (DEPTH - 1)] : SENT;
                v.y = (i + 1 < lvl) ? buf[b][(flushed[b] + i + 1) & (DEPTH - 1)] : SENT;
                v.z = (i + 2 < lvl) ? buf[b][(flushed[b] + i + 2) & (DEPTH - 1)] : SENT;
                v.w = (i + 3 < lvl) ? buf[b][(flushed[b] + i + 3) & (DEPTH - 1)] : SENT;
                if (pos + i + 4 <= CAPB)
                    *(uint4*)(binreg + (long)b * CAPB + pos + i) = v;
            }
        }
    }
}

// ---------------------------------------------------------------- CSR pass B: per-bin LDS finalize
__global__ __launch_bounds__(512) void k_fill2b(
    const unsigned int* __restrict__ binreg, const int* __restrict__ gbincur,
    const int* __restrict__ brealc, int* __restrict__ csr_start,
    unsigned short* __restrict__ esrc)
{
    __shared__ unsigned int stage[CAPB];
    __shared__ int pc[512], rcnt[512], scn[512], cur[512];
    const int b = blockIdx.x, tid = threadIdx.x;
    int pv = (tid < NBIN) ? brealc[tid] : 0;
    if (pv < 0) pv = 0;
    pc[tid] = pv;
    __syncthreads();
    for (int off = 1; off < 512; off <<= 1) {
        int t = (tid >= off) ? pc[tid - off] : 0;
        __syncthreads();
        pc[tid] += t;
        __syncthreads();
    }
    int bbase = (b == 0) ? 0 : pc[b - 1];
    int total = gbincur[b];
    if (total > CAPB) total = CAPB;
    if (total < 0) total = 0;
    const unsigned int* seg = binreg + (long)b * CAPB;
    for (int i = tid; i < total; i += 512) stage[i] = seg[i];
    rcnt[tid] = 0;
    __syncthreads();
    for (int i = tid; i < total; i += 512) {
        unsigned pk = stage[i];
        if (pk != SENT) atomicAdd(&rcnt[(pk >> 16) & 511], 1);
    }
    __syncthreads();
    int v = rcnt[tid];
    scn[tid] = v;
    __syncthreads();
    for (int off = 1; off < 512; off <<= 1) {
        int t = (tid >= off) ? scn[tid - off] : 0;
        __syncthreads();
        scn[tid] += t;
        __syncthreads();
    }
    int base = bbase + scn[tid] - v;
    cur[tid] = base;
    int row = b * 512 + tid;
    if (row <= NROWS) csr_start[row] = base;
    __syncthreads();
    for (int i = tid; i < total; i += 512) {
        unsigned pk = stage[i];
        if (pk != SENT) {
            int pos = atomicAdd(&cur[(pk >> 16) & 511], 1);
            if (pos >= 0 && pos < NE) esrc[pos] = (unsigned short)(pk & 0xffffu);
        }
    }
}

// ---------------------------------------------------------------- K1: CSR gather, 4 rows/wave, uint4 loads
__global__ __launch_bounds__(256) void k_gather(
    const unsigned short* __restrict__ esrc, const int* __restrict__ csr_start,
    const uint4* __restrict__ x8, uint4* __restrict__ agg8)
{
    int row = blockIdx.x * 16 + (threadIdx.x >> 4);
    int lane = threadIdx.x & 63;
    int l4 = lane & 15, qw = lane >> 4;
    int e0 = csr_start[row], e1 = csr_start[row + 1];
    if ((unsigned)e0 > NE || (unsigned)e1 > NE || e1 < e0) { e0 = 0; e1 = 0; }
    int nch = (e1 - e0 + 15) >> 4;
    int n0 = __shfl(nch, 0, 64), n1 = __shfl(nch, 16, 64);
    int n2 = __shfl(nch, 32, 64), n3 = __shfl(nch, 48, 64);
    int nmax = max(max(n0, n1), max(n2, n3));
    float a0 = 0.f, a1 = 0.f, a2 = 0.f, a3 = 0.f, a4 = 0.f, a5 = 0.f, a6 = 0.f, a7 = 0.f;
    const int sb = qw << 4;
    for (int c = 0; c < nmax; ++c) {
        int base = e0 + c * 16;
        int rem = e1 - base;
        int pre = (l4 < rem) ? (int)esrc[base + l4] : 0;
        int m = rem < 16 ? (rem < 0 ? 0 : rem) : 16;
        int j = 0;
        for (; j + 3 < m; j += 4) {
            int sA = __shfl(pre, sb + j, 64);
            int sB = __shfl(pre, sb + j + 1, 64);
            int sC = __shfl(pre, sb + j + 2, 64);
            int sD = __shfl(pre, sb + j + 3, 64);
            uint4 v0 = x8[(long)sA * 16 + l4];
            uint4 v1 = x8[(long)sB * 16 + l4];
            uint4 v2 = x8[(long)sC * 16 + l4];
            uint4 v3 = x8[(long)sD * 16 + l4];
            a0 += blo(v0.x) + blo(v1.x) + blo(v2.x) + blo(v3.x);
            a1 += bhi(v0.x) + bhi(v1.x) + bhi(v2.x) + bhi(v3.x);
            a2 += blo(v0.y) + blo(v1.y) + blo(v2.y) + blo(v3.y);
            a3 += bhi(v0.y) + bhi(v1.y) + bhi(v2.y) + bhi(v3.y);
            a4 += blo(v0.z) + blo(v1.z) + blo(v2.z) + blo(v3.z);
            a5 += bhi(v0.z) + bhi(v1.z) + bhi(v2.z) + bhi(v3.z);
            a6 += blo(v0.w) + blo(v1.w) + blo(v2.w) + blo(v3.w);
            a7 += bhi(v0.w) + bhi(v1.w) + bhi(v2.w) + bhi(v3.w);
        }
        for (; j < m; ++j) {
            int sA = __shfl(pre, sb + j, 64);
            uint4 v0 = x8[(long)sA * 16 + l4];
            a0 += blo(v0.x); a1 += bhi(v0.x); a2 += blo(v0.y); a3 += bhi(v0.y);
            a4 += blo(v0.z); a5 += bhi(v0.z); a6 += blo(v0.w); a7 += bhi(v0.w);
        }
    }
    int hop = row / NN, node = row - hop * NN;
    uint4 o;
    o.x = pk2(a0, a1); o.y = pk2(a2, a3); o.z = pk2(a4, a5); o.w = pk2(a6, a7);
    agg8[((long)hop * NNP + node) * 16 + l4] = o;
}

// ---------------------------------------------------------------- K2: FUSED layer (shell + skip + 2x residual MLP)
// Shell B-frags software-pipelined depth-8 (HBM latency); h/gskip never hit global.
__global__ __launch_bounds__(256) void k_layer(
    const __bf16* __restrict__ x, const __bf16* __restrict__ agg,
    const __bf16* __restrict__ pwin, const float* __restrict__ bin,
    const __bf16* __restrict__ pwsk, const float* __restrict__ bsk,
    const __bf16* __restrict__ pw1a, const float* __restrict__ b1a,
    const __bf16* __restrict__ pw2a, const float* __restrict__ b2a,
    const __bf16* __restrict__ pw1b, const float* __restrict__ b1b,
    const __bf16* __restrict__ pw2b, const float* __restrict__ b2b,
    __bf16* __restrict__ xout)
{
    __shared__ __bf16 lds[4][32 * LSTR];
    const int lane = threadIdx.x & 63, wid = threadIdx.x >> 6;
    const int q = lane >> 4, l16 = lane & 15;
    const int nb = blockIdx.x * 128 + wid * 32;
    const int la = lane * 8;
    __bf16* L = lds[wid];
    const long r0 = (long)(nb + l16) * 128;
    const long r1 = (long)(nb + 16 + l16) * 128;
    const __bf16* planes[4] = {x, agg, agg + (long)NNP * 128, agg + 2L * NNP * 128};

    // ---- shell phase: [x|hop0|hop1|hop2] @ {Win,Wsk}, K=512, B-ring depth 8 ----
    bf16x8 ring[8][2];
#pragma unroll
    for (int k = 0; k < 8; ++k) {
        const __bf16* sp = planes[k >> 2] + (k & 3) * 32 + q * 8;
        ring[k][0] = *(const bf16x8*)(sp + r0);
        ring[k][1] = *(const bf16x8*)(sp + r1);
    }
    f32x4 aci[2][8], acs[2][8];
#pragma unroll
    for (int nt = 0; nt < 2; ++nt)
#pragma unroll
        for (int mt = 0; mt < 8; ++mt) { aci[nt][mt] = (f32x4)(0.f); acs[nt][mt] = (f32x4)(0.f); }
#pragma unroll
    for (int kt = 0; kt < 16; ++kt) {
        bf16x8 b0 = ring[kt & 7][0];
        bf16x8 b1v = ring[kt & 7][1];
        if (kt < 8) {
            int k2 = kt + 8;
            const __bf16* sp = planes[k2 >> 2] + (k2 & 3) * 32 + q * 8;
            ring[kt & 7][0] = *(const bf16x8*)(sp + r0);
            ring[kt & 7][1] = *(const bf16x8*)(sp + r1);
        }
        const __bf16* aip = pwin + (long)kt * 4096 + la;
        const __bf16* asp = pwsk + (long)kt * 4096 + la;
#pragma unroll
        for (int mt = 0; mt < 8; ++mt) {
            bf16x8 ai = *(const bf16x8*)(aip + mt * 512);
            bf16x8 as = *(const bf16x8*)(asp + mt * 512);
            aci[0][mt] = mm(ai, b0, aci[0][mt]);
            aci[1][mt] = mm(ai, b1v, aci[1][mt]);
            acs[0][mt] = mm(as, b0, acs[0][mt]);
            acs[1][mt] = mm(as, b1v, acs[1][mt]);
        }
    }
    bf16x4 gk[2][8];     // gskip in registers
    bf16x4 hs[2][8];     // h in registers (skip for p1)
#pragma unroll
    for (int nt = 0; nt < 2; ++nt)
#pragma unroll
        for (int mt = 0; mt < 8; ++mt) {
            int ch = mt * 16 + q * 4;
            float4 bi = *(const float4*)(bin + ch);
            float4 bs = *(const float4*)(bsk + ch);
            bf16x4 oh;
            oh[0] = (__bf16)silu_f(aci[nt][mt][0] + bi.x);
            oh[1] = (__bf16)silu_f(aci[nt][mt][1] + bi.y);
            oh[2] = (__bf16)silu_f(aci[nt][mt][2] + bi.z);
            oh[3] = (__bf16)silu_f(aci[nt][mt][3] + bi.w);
            bf16x4 og;
            og[0] = (__bf16)(acs[nt][mt][0] + bs.x);
            og[1] = (__bf16)(acs[nt][mt][1] + bs.y);
            og[2] = (__bf16)(acs[nt][mt][2] + bs.z);
            og[3] = (__bf16)(acs[nt][mt][3] + bs.w);
            hs[nt][mt] = oh; gk[nt][mt] = og;
            *(bf16x4*)(L + (nt * 16 + l16) * LSTR + ch) = oh;
        }
    __syncthreads();

    f32x4 acc[2][8];
    bf16x4 skipreg[2][8];

    // ---- p0: t1 = silu(h @ W1a + b1a) -> LDS ----
#pragma unroll
    for (int nt = 0; nt < 2; ++nt)
#pragma unroll
        for (int mt = 0; mt < 8; ++mt) acc[nt][mt] = (f32x4)(0.f);
#pragma unroll
    for (int kt = 0; kt < 4; ++kt) {
        int koff = kt * 32 + q * 8;
        bf16x8 f0 = *(const bf16x8*)(L + l16 * LSTR + koff);
        bf16x8 f1 = *(const bf16x8*)(L + (16 + l16) * LSTR + koff);
        const __bf16* ap = pw1a + (long)kt * 4096 + la;
#pragma unroll
        for (int mt = 0; mt < 8; ++mt) {
            bf16x8 a = *(const bf16x8*)(ap + mt * 512);
            acc[0][mt] = mm(a, f0, acc[0][mt]);
            acc[1][mt] = mm(a, f1, acc[1][mt]);
        }
    }
    __syncthreads();
#pragma unroll
    for (int nt = 0; nt < 2; ++nt)
#pragma unroll
        for (int mt = 0; mt < 8; ++mt) {
            int ch = mt * 16 + q * 4;
            float4 bb = *(const float4*)(b1a + ch);
            bf16x4 o;
            o[0] = (__bf16)silu_f(acc[nt][mt][0] + bb.x);
            o[1] = (__bf16)silu_f(acc[nt][mt][1] + bb.y);
            o[2] = (__bf16)silu_f(acc[nt][mt][2] + bb.z);
            o[3] = (__bf16)silu_f(acc[nt][mt][3] + bb.w);
            *(bf16x4*)(L + (nt * 16 + l16) * LSTR + ch) = o;
        }
    __syncthreads();

    // ---- p1: h2 = t1 @ W2a + b2a + h -> LDS + skipreg ----
#pragma unroll
    for (int nt = 0; nt < 2; ++nt)
#pragma unroll
        for (int mt = 0; mt < 8; ++mt) acc[nt][mt] = (f32x4)(0.f);
#pragma unroll
    for (int kt = 0; kt < 4; ++kt) {
        int koff = kt * 32 + q * 8;
        bf16x8 f0 = *(const bf16x8*)(L + l16 * LSTR + koff);
        bf16x8 f1 = *(const bf16x8*)(L + (16 + l16) * LSTR + koff);
        const __bf16* ap = pw2a + (long)kt * 4096 + la;
#pragma unroll
        for (int mt = 0; mt < 8; ++mt) {
            bf16x8 a = *(const bf16x8*)(ap + mt * 512);
            acc[0][mt] = mm(a, f0, acc[0][mt]);
            acc[1][mt] = mm(a, f1, acc[1][mt]);
        }
    }
    __syncthreads();
#pragma unroll
    for (int nt = 0; nt < 2; ++nt)
#pragma unroll
        for (int mt = 0; mt < 8; ++mt) {
            int ch = mt * 16 + q * 4;
            float4 bb = *(const float4*)(b2a + ch);
            bf16x4 sk = hs[nt][mt];
            bf16x4 o;
            o[0] = (__bf16)(acc[nt][mt][0] + bb.x + (float)sk[0]);
            o[1] = (__bf16)(acc[nt][mt][1] + bb.y + (float)sk[1]);
            o[2] = (__bf16)(acc[nt][mt][2] + bb.z + (float)sk[2]);
            o[3] = (__bf16)(acc[nt][mt][3] + bb.w + (float)sk[3]);
            skipreg[nt][mt] = o;
            *(bf16x4*)(L + (nt * 16 + l16) * LSTR + ch) = o;
        }
    __syncthreads();

    // ---- p2: t2 = silu(h2 @ W1b + b1b) -> LDS ----
#pragma unroll
    for (int nt = 0; nt < 2; ++nt)
#pragma unroll
        for (int mt = 0; mt < 8; ++mt) acc[nt][mt] = (f32x4)(0.f);
#pragma unroll
    for (int kt = 0; kt < 4; ++kt) {
        int koff = kt * 32 + q * 8;
        bf16x8 f0 = *(const bf16x8*)(L + l16 * LSTR + koff);
        bf16x8 f1 = *(const bf16x8*)(L + (16 + l16) * LSTR + koff);
        const __bf16* ap = pw1b + (long)kt * 4096 + la;
#pragma unroll
        for (int mt = 0; mt < 8; ++mt) {
            bf16x8 a = *(const bf16x8*)(ap + mt * 512);
            acc[0][mt] = mm(a, f0, acc[0][mt]);
            acc[1][mt] = mm(a, f1, acc[1][mt]);
        }
    }
    __syncthreads();
#pragma unroll
    for (int nt = 0; nt < 2; ++nt)
#pragma unroll
        for (int mt = 0; mt < 8; ++mt) {
            int ch = mt * 16 + q * 4;
            float4 bb = *(const float4*)(b1b + ch);
            bf16x4 o;
            o[0] = (__bf16)silu_f(acc[nt][mt][0] + bb.x);
            o[1] = (__bf16)silu_f(acc[nt][mt][1] + bb.y);
            o[2] = (__bf16)silu_f(acc[nt][mt][2] + bb.z);
            o[3] = (__bf16)silu_f(acc[nt][mt][3] + bb.w);
            *(bf16x4*)(L + (nt * 16 + l16) * LSTR + ch) = o;
        }
    __syncthreads();

    // ---- p3: x = t2 @ W2b + b2b + h2 + gskip -> global ----
#pragma unroll
    for (int nt = 0; nt < 2; ++nt)
#pragma unroll
        for (int mt = 0; mt < 8; ++mt) acc[nt][mt] = (f32x4)(0.f);
#pragma unroll
    for (int kt = 0; kt < 4; ++kt) {
        int koff = kt * 32 + q * 8;
        bf16x8 f0 = *(const bf16x8*)(L + l16 * LSTR + koff);
        bf16x8 f1 = *(const bf16x8*)(L + (16 + l16) * LSTR + koff);
        const __bf16* ap = pw2b + (long)kt * 4096 + la;
#pragma unroll
        for (int mt = 0; mt < 8; ++mt) {
            bf16x8 a = *(const bf16x8*)(ap + mt * 512);
            acc[0][mt] = mm(a, f0, acc[0][mt]);
            acc[1][mt] = mm(a, f1, acc[1][mt]);
        }
    }
#pragma unroll
    for (int nt = 0; nt < 2; ++nt) {
        long node = nb + nt * 16 + l16;
#pragma unroll
        for (int mt = 0; mt < 8; ++mt) {
            int ch = mt * 16 + q * 4;
            float4 bb = *(const float4*)(b2b + ch);
            bf16x4 sk = skipreg[nt][mt];
            bf16x4 g = gk[nt][mt];
            bf16x4 o;
            o[0] = (__bf16)(acc[nt][mt][0] + bb.x + (float)sk[0] + (float)g[0]);
            o[1] = (__bf16)(acc[nt][mt][1] + bb.y + (float)sk[1] + (float)g[1]);
            o[2] = (__bf16)(acc[nt][mt][2] + bb.z + (float)sk[2] + (float)g[2]);
            o[3] = (__bf16)(acc[nt][mt][3] + bb.w + (float)sk[3] + (float)g[3]);
            *(bf16x4*)(xout + node * 128 + ch) = o;
        }
    }
}

// ---------------------------------------------------------------- K4: attention scores
__global__ __launch_bounds__(256) void k_scores(
    const __bf16* __restrict__ x, const float* __restrict__ aw,
    const float* __restrict__ ab, const float* __restrict__ temp,
    float* __restrict__ scores)
{
    int wave = threadIdx.x >> 6, lane = threadIdx.x & 63;
    int n = blockIdx.x * 4 + wave;
    if (n >= NN) return;
    float x0 = (float)x[(long)n * H + lane];
    float x1 = (float)x[(long)n * H + 64 + lane];
    float T = temp[0];
#pragma unroll
    for (int hh = 0; hh < NHEADS; ++hh) {
        float p = x0 * aw[hh * H + lane] + x1 * aw[hh * H + 64 + lane];
#pragma unroll
        for (int off = 32; off >= 1; off >>= 1) p += __shfl_xor(p, off, 64);
        if (lane == 0) scores[n * NHEADS + hh] = (p + ab[hh]) / T;
    }
}

// ---------------------------------------------------------------- K5: graph offsets
__global__ __launch_bounds__(256) void k_offsets(
    const int* __restrict__ batch, int* __restrict__ gstart)
{
    int n = blockIdx.x * 256 + threadIdx.x;
    if (n >= NN) return;
    int b = batch[n];
    int bp = (n == 0) ? -1 : batch[n - 1];
    for (int g = bp + 1; g <= b; ++g) gstart[g] = n;
    if (n == NN - 1) for (int g = b + 1; g <= NG; ++g) gstart[g] = NN;
}

// ---------------------------------------------------------------- K6: softmax pool
__global__ __launch_bounds__(64) void k_pool(
    const __bf16* __restrict__ x, const float* __restrict__ scores,
    const int* __restrict__ gstart, float* __restrict__ pooled)
{
    int g = blockIdx.x, lane = threadIdx.x;
    int s0 = gstart[g], s1 = gstart[g + 1];
    float m0 = -INFINITY, m1 = -INFINITY, m2 = -INFINITY, m3 = -INFINITY;
    for (int n = s0 + lane; n < s1; n += 64) {
        m0 = fmaxf(m0, scores[n * 4 + 0]); m1 = fmaxf(m1, scores[n * 4 + 1]);
        m2 = fmaxf(m2, scores[n * 4 + 2]); m3 = fmaxf(m3, scores[n * 4 + 3]);
    }
#pragma unroll
    for (int off = 32; off >= 1; off >>= 1) {
        m0 = fmaxf(m0, __shfl_xor(m0, off, 64)); m1 = fmaxf(m1, __shfl_xor(m1, off, 64));
        m2 = fmaxf(m2, __shfl_xor(m2, off, 64)); m3 = fmaxf(m3, __shfl_xor(m3, off, 64));
    }
    float d0 = 0.f, d1 = 0.f, d2 = 0.f, d3 = 0.f;
    for (int n = s0 + lane; n < s1; n += 64) {
        d0 += expf(scores[n * 4 + 0] - m0); d1 += expf(scores[n * 4 + 1] - m1);
        d2 += expf(scores[n * 4 + 2] - m2); d3 += expf(scores[n * 4 + 3] - m3);
    }
#pragma unroll
    for (int off = 32; off >= 1; off >>= 1) {
        d0 += __shfl_xor(d0, off, 64); d1 += __shfl_xor(d1, off, 64);
        d2 += __shfl_xor(d2, off, 64); d3 += __shfl_xor(d3, off, 64);
    }
    float i0 = d0 > 0.f ? 1.f / d0 : 0.f;
    float i1 = d1 > 0.f ? 1.f / d1 : 0.f;
    float i2 = d2 > 0.f ? 1.f / d2 : 0.f;
    float i3 = d3 > 0.f ? 1.f / d3 : 0.f;
    float a0 = 0.f, a1 = 0.f;
    for (int n = s0; n < s1; ++n) {
        float wb = expf(scores[n * 4 + 0] - m0) * i0 + expf(scores[n * 4 + 1] - m1) * i1
                 + expf(scores[n * 4 + 2] - m2) * i2 + expf(scores[n * 4 + 3] - m3) * i3;
        wb *= 0.25f;
        a0 += wb * (float)x[(long)n * H + lane];
        a1 += wb * (float)x[(long)n * H + 64 + lane];
    }
    pooled[g * H + lane] = a0;
    pooled[g * H + 64 + lane] = a1;
}

// ---------------------------------------------------------------- K7: FFN readout
__global__ __launch_bounds__(128) void k_ffn(
    const float* __restrict__ pooled,
    const float* __restrict__ W1, const float* __restrict__ B1,
    const float* __restrict__ W2, const float* __restrict__ B2,
    const float* __restrict__ W3, const float* __restrict__ B3,
    float* __restrict__ out)
{
    __shared__ float p[H], t1[H], t2[H], red[H];
    int g = blockIdx.x, c = threadIdx.x;
    p[c] = pooled[g * H + c];
    __syncthreads();
    float acc = 0.f;
    for (int k = 0; k < H; ++k) acc += p[k] * W1[k * H + c];
    t1[c] = silu_f(acc + B1[c]);
    __syncthreads();
    acc = 0.f;
    for (int k = 0; k < H; ++k) acc += t1[k] * W2[k * H + c];
    t2[c] = silu_f(acc + B2[c]);
    __syncthreads();
    red[c] = t2[c] * W3[c];
    __syncthreads();
    for (int off = 64; off >= 1; off >>= 1) {
        if (c < off) red[c] += red[c + off];
        __syncthreads();
    }
    if (c == 0) out[g] = red[0] + B3[0];
}

// ---------------------------------------------------------------- launch
extern "C" void kernel_launch(void* const* d_in, const int* in_sizes, int n_in,
                              void* d_out, int out_size, void* d_ws, size_t ws_size,
                              hipStream_t stream)
{
    const int*   atom   = (const int*)d_in[0];
    const int*   hc     = (const int*)d_in[1];
    const int*   deg    = (const int*)d_in[2];
    const int*   hyb    = (const int*)d_in[3];
    const int*   target = (const int*)d_in[4];
    const int*   src    = (const int*)d_in[5];
    const int*   batch  = (const int*)d_in[6];
    const float* Ea     = (const float*)d_in[7];
    const float* Eh     = (const float*)d_in[8];
    const float* Ed     = (const float*)d_in[9];
    const float* Ey     = (const float*)d_in[10];
    const float* projW  = (const float*)d_in[11];
    const float* projB  = (const float*)d_in[12];
    const float* sInW   = (const float*)d_in[13];
    const float* sInB   = (const float*)d_in[14];
    const float* mW1    = (const float*)d_in[15];
    const float* mB1    = (const float*)d_in[16];
    const float* mW2    = (const float*)d_in[17];
    const float* mB2    = (const float*)d_in[18];
    const float* sSkW   = (const float*)d_in[19];
    const float* sSkB   = (const float*)d_in[20];
    const float* attnW  = (const float*)d_in[21];
    const float* attnB  = (const float*)d_in[22];
    const float* temp   = (const float*)d_in[23];
    const float* fW1    = (const float*)d_in[24];
    const float* fB1    = (const float*)d_in[25];
    const float* fW2    = (const float*)d_in[26];
    const float* fB2    = (const float*)d_in[27];
    const float* fW3    = (const float*)d_in[28];
    const float* fB3    = (const float*)d_in[29];
    float* out = (float*)d_out;

    char* w = (char*)d_ws;
    auto take = [&](size_t bytes) { void* p = (void*)w; w += (bytes + 255) & ~(size_t)255; return p; };
    __bf16* x      = (__bf16*)take(2L * NNP * H);
    __bf16* agg    = (__bf16*)take(2L * 3 * NNP * H);
    __bf16* pproj  = (__bf16*)take(2L * 256 * H);
    __bf16* pin    = (__bf16*)take(2L * 3 * 512 * H);
    __bf16* psk    = (__bf16*)take(2L * 3 * 512 * H);
    __bf16* pw1    = (__bf16*)take(2L * 6 * 128 * H);
    __bf16* pw2    = (__bf16*)take(2L * 6 * 128 * H);
    __bf16* embb   = (__bf16*)take(2L * 8000);
    float*  scores = (float*)take(4L * NN * NHEADS);
    float*  pooled = (float*)take(4L * NG * H);
    int*    gstart = (int*)take(4L * (NG + 1));
    int*    csr_start = (int*)take(4L * (NROWS + 1));
    unsigned int*   binreg = (unsigned int*)take(4L * NBIN * CAPB);   // 12 MB
    unsigned short* esrc   = (unsigned short*)take(2L * NE);
    // gbincur + brealc in ONE contiguous allocation (one memset covers both)
    int*    gbincur = (int*)take(4L * 2 * NBIN);
    int*    brealc  = gbincur + NBIN;

    // ---- fused weight pack + emb convert (weights restored each call) ----
    k_packall<<<(630592 + 255) / 256, 256, 0, stream>>>(
        projW, pproj, sInW, pin, sSkW, psk, mW1, pw1, mW2, pw2,
        Ea, Eh, Ed, Ey, embb);

    // ---- CSR build: write-combined binning -> per-bin finalize ----
    hipMemsetAsync(gbincur, 0, sizeof(int) * 2 * NBIN, stream);
    k_binA<<<ABLK, 256, 0, stream>>>(target, src, gbincur, brealc, binreg);
    k_fill2b<<<NBIN, 512, 0, stream>>>(binreg, gbincur, brealc, csr_start, esrc);

    k_embed_m<<<NNP / 128, 256, 0, stream>>>(atom, hc, deg, hyb, embb, pproj, projB, x);
    k_offsets<<<(NN + 255) / 256, 256, 0, stream>>>(batch, gstart);

    for (int l = 0; l < NL; ++l) {
        k_gather<<<NROWS / 16, 256, 0, stream>>>(esrc, csr_start,
            (const uint4*)x, (uint4*)agg);
        k_layer<<<NNP / 128, 256, 0, stream>>>(x, agg,
            pin + (long)l * 512 * H, sInB + l * H,
            psk + (long)l * 512 * H, sSkB + l * H,
            pw1 + (long)(l * NMLP + 0) * 128 * H, mB1 + (long)(l * NMLP + 0) * H,
            pw2 + (long)(l * NMLP + 0) * 128 * H, mB2 + (long)(l * NMLP + 0) * H,
            pw1 + (long)(l * NMLP + 1) * 128 * H, mB1 + (long)(l * NMLP + 1) * H,
            pw2 + (long)(l * NMLP + 1) * 128 * H, mB2 + (long)(l * NMLP + 1) * H,
            x);
    }

    k_scores<<<NN / 4, 256, 0, stream>>>(x, attnW, attnB, temp, scores);
    k_pool<<<NG, 64, 0, stream>>>(x, scores, gstart, pooled);
    k_ffn<<<NG, 128, 0, stream>>>(pooled, fW1, fB1, fW2, fB2, fW3, fB3, out);
}

// Round 10
// 772.291 us; speedup vs baseline: 17.5806x; 1.0949x over previous
//
#include <hip/hip_runtime.h>
#include <math.h>

#define NN      50000
#define NNP     50048          // padded nodes = 391*128
#define NE      2400000
#define NHOPS   3
#define NG      2048
#define H       128
#define EMBD    64
#define NL      3
#define NMLP    2
#define NHEADS  4
#define NROWS   (NHOPS * NN)   // 150000
#define BINSH   9              // 512 rows per coarse bin
#define NBIN    293            // ceil(150016/512)
#define CAPB    10240          // per-bin region capacity
#define ABLK    480            // binning blocks
#define DEPTH   32             // LDS circular buffer depth per bin
#define LSTR    136
#define SENT    0xFFFFFFFFu

typedef __bf16 bf16x8 __attribute__((ext_vector_type(8)));
typedef __bf16 bf16x4 __attribute__((ext_vector_type(4)));
typedef float  f32x4  __attribute__((ext_vector_type(4)));

__device__ __forceinline__ float silu_f(float v) { return v / (1.0f + expf(-v)); }

__device__ __forceinline__ f32x4 mm(bf16x8 a, bf16x8 b, f32x4 c) {
    return __builtin_amdgcn_mfma_f32_16x16x32_bf16(a, b, c, 0, 0, 0);
}

__device__ __forceinline__ float blo(unsigned v) { return __builtin_bit_cast(float, v << 16); }
__device__ __forceinline__ float bhi(unsigned v) { return __builtin_bit_cast(float, v & 0xffff0000u); }
__device__ __forceinline__ unsigned pk2(float a, float b) {
    unsigned short ua = __builtin_bit_cast(unsigned short, (__bf16)a);
    unsigned short ub = __builtin_bit_cast(unsigned short, (__bf16)b);
    return (unsigned)ua | ((unsigned)ub << 16);
}

// ---------------------------------------------------------------- fused weight pack + emb convert
__device__ __forceinline__ void packw_elem(
    const float* __restrict__ W, __bf16* __restrict__ out, int K, long idx)
{
    long per = (long)K * 128;
    long mat = idx / per, e = idx - mat * per;
    int j = (int)(e & 7), n16 = (int)((e >> 3) & 15), q = (int)((e >> 7) & 3),
        mt = (int)((e >> 9) & 7), kt = (int)(e >> 12);
    int k = kt * 32 + q * 8 + j, n = mt * 16 + n16;
    out[idx] = (__bf16)W[mat * per + (long)k * 128 + n];
}

__global__ __launch_bounds__(256) void k_packall(
    const float* __restrict__ projW, __bf16* __restrict__ pproj,
    const float* __restrict__ sInW,  __bf16* __restrict__ pin,
    const float* __restrict__ sSkW,  __bf16* __restrict__ psk,
    const float* __restrict__ mW1,   __bf16* __restrict__ pw1,
    const float* __restrict__ mW2,   __bf16* __restrict__ pw2,
    const float* __restrict__ Ea, const float* __restrict__ Eh,
    const float* __restrict__ Ed, const float* __restrict__ Ey,
    __bf16* __restrict__ embb)
{
    long tid = (long)blockIdx.x * 256 + threadIdx.x;
    if (tid < 32768) { packw_elem(projW, pproj, 256, tid); return; }
    tid -= 32768;
    if (tid < 196608) { packw_elem(sInW, pin, 512, tid); return; }
    tid -= 196608;
    if (tid < 196608) { packw_elem(sSkW, psk, 512, tid); return; }
    tid -= 196608;
    if (tid < 98304) { packw_elem(mW1, pw1, 128, tid); return; }
    tid -= 98304;
    if (tid < 98304) { packw_elem(mW2, pw2, 128, tid); return; }
    tid -= 98304;
    if (tid < 8000) {
        int t = (int)tid;
        float v;
        if (t < 6400) v = Ea[t];
        else if (t < 6976) v = Eh[t - 6400];
        else if (t < 7488) v = Ed[t - 6976];
        else v = Ey[t - 7488];
        embb[t] = (__bf16)v;
    }
}

// ---------------------------------------------------------------- K0: embed + project + silu (MFMA)
__global__ __launch_bounds__(256) void k_embed_m(
    const int* __restrict__ atom, const int* __restrict__ hc,
    const int* __restrict__ deg,  const int* __restrict__ hyb,
    const __bf16* __restrict__ emb, const __bf16* __restrict__ pw,
    const float* __restrict__ pb, __bf16* __restrict__ x)
{
    const int lane = threadIdx.x & 63, wid = threadIdx.x >> 6;
    const int q = lane >> 4, l16 = lane & 15;
    const int nb = blockIdx.x * 128 + wid * 32;
    int ia[2][4];
#pragma unroll
    for (int nt = 0; nt < 2; ++nt) {
        int n = nb + nt * 16 + l16;
        if (n >= NN) n = NN - 1;
        ia[nt][0] = atom[n]; ia[nt][1] = hc[n]; ia[nt][2] = deg[n]; ia[nt][3] = hyb[n];
    }
    f32x4 acc[2][8];
#pragma unroll
    for (int nt = 0; nt < 2; ++nt)
#pragma unroll
        for (int mt = 0; mt < 8; ++mt) acc[nt][mt] = (f32x4)(0.f);
    const int tb[4] = {0, 6400, 6976, 7488};
    for (int kt = 0; kt < 8; ++kt) {
        int t = kt >> 1;
        int koff = (kt & 1) * 32 + q * 8;
        bf16x8 bfrag[2];
#pragma unroll
        for (int nt = 0; nt < 2; ++nt)
            bfrag[nt] = *(const bf16x8*)(emb + tb[t] + (long)ia[nt][t] * 64 + koff);
        const __bf16* ap = pw + (long)kt * 4096 + lane * 8;
#pragma unroll
        for (int mt = 0; mt < 8; ++mt) {
            bf16x8 a = *(const bf16x8*)(ap + mt * 512);
            acc[0][mt] = mm(a, bfrag[0], acc[0][mt]);
            acc[1][mt] = mm(a, bfrag[1], acc[1][mt]);
        }
    }
#pragma unroll
    for (int nt = 0; nt < 2; ++nt) {
        long node = nb + nt * 16 + l16;
#pragma unroll
        for (int mt = 0; mt < 8; ++mt) {
            int ch = mt * 16 + q * 4;
            float4 bb = *(const float4*)(pb + ch);
            bf16x4 o;
            o[0] = (__bf16)silu_f(acc[nt][mt][0] + bb.x);
            o[1] = (__bf16)silu_f(acc[nt][mt][1] + bb.y);
            o[2] = (__bf16)silu_f(acc[nt][mt][2] + bb.z);
            o[3] = (__bf16)silu_f(acc[nt][mt][3] + bb.w);
            *(bf16x4*)(x + node * 128 + ch) = o;
        }
    }
}

// ---------------------------------------------------------------- CSR pass A: LDS write-combined binning
__global__ __launch_bounds__(256) void k_binA(
    const int* __restrict__ target, const int* __restrict__ src,
    int* __restrict__ gbincur, int* __restrict__ brealc,
    unsigned int* __restrict__ binreg)
{
    __shared__ unsigned int buf[NBIN][DEPTH];
    __shared__ int cnt[NBIN];
    __shared__ int flushed[NBIN];
    const int tid = threadIdx.x;
    for (int i = tid; i < NBIN; i += 256) { cnt[i] = 0; flushed[i] = 0; }
    __syncthreads();
    const int per = (NE + ABLK - 1) / ABLK;   // 5000
    const int e0 = blockIdx.x * per;
    const int e1 = (e0 + per < NE) ? e0 + per : NE;
    for (int base = e0; base < e1; base += 256) {
        int e = base + tid;
        if (e < e1) {
            int s = src[e];
            if (s >= 2 * NN) s -= 2 * NN; else if (s >= NN) s -= NN;
            int t = target[e];
            int bin = t >> BINSH;
            unsigned val = (unsigned)s | ((unsigned)(t & ((1 << BINSH) - 1)) << 16);
            int slot = atomicAdd(&cnt[bin], 1);
            buf[bin][slot & (DEPTH - 1)] = val;
        }
        __syncthreads();
        for (int b = tid; b < NBIN; b += 256) {
            while (cnt[b] - flushed[b] >= 16) {
                int pos = atomicAdd(&gbincur[b], 16);
                if (pos + 16 <= CAPB) {
                    uint4* d4 = (uint4*)(binreg + (long)b * CAPB + pos);
                    const uint4* s4 = (const uint4*)&buf[b][flushed[b] & (DEPTH - 1)];
                    d4[0] = s4[0]; d4[1] = s4[1]; d4[2] = s4[2]; d4[3] = s4[3];
                }
                flushed[b] += 16;
            }
        }
        __syncthreads();
    }
    for (int b = tid; b < NBIN; b += 256) {
        int lvl = cnt[b] - flushed[b];
        if (cnt[b] > 0) atomicAdd(&brealc[b], cnt[b]);
        if (lvl > 0) {
            int pad = (lvl + 3) & ~3;
            int pos = atomicAdd(&gbincur[b], pad);
            for (int i = 0; i < pad; i += 4) {
                uint4 v;
                v.x = (i + 0 < lvl) ? buf[b][(flushed[b] + i + 0) & (DEPTH - 1)] : SENT;
                v.y = (i + 1 < lvl) ? buf[b][(flushed[b] + i + 1) & (DEPTH - 1)] : SENT;
                v.z = (i + 2 < lvl) ? buf[b][(flushed[b] + i + 2) & (DEPTH - 1)] : SENT;
                v.w = (i + 3 < lvl) ? buf[b][(flushed[b] + i + 3) & (DEPTH - 1)] : SENT;
                if (pos + i + 4 <= CAPB)
                    *(uint4*)(binreg + (long)b * CAPB + pos + i) = v;
            }
        }
    }
}

// ---------------------------------------------------------------- CSR pass B: per-bin LDS finalize
__global__ __launch_bounds__(512) void k_fill2b(
    const unsigned int* __restrict__ binreg, const int* __restrict__ gbincur,
    const int* __restrict__ brealc, int* __restrict__ csr_start,
    unsigned short* __restrict__ esrc)
{
    __shared__ unsigned int stage[CAPB];
    __shared__ int pc[512], rcnt[512], scn[512], cur[512];
    const int b = blockIdx.x, tid = threadIdx.x;
    int pv = (tid < NBIN) ? brealc[tid] : 0;
    if (pv < 0) pv = 0;
    pc[tid] = pv;
    __syncthreads();
    for (int off = 1; off < 512; off <<= 1) {
        int t = (tid >= off) ? pc[tid - off] : 0;
        __syncthreads();
        pc[tid] += t;
        __syncthreads();
    }
    int bbase = (b == 0) ? 0 : pc[b - 1];
    int total = gbincur[b];
    if (total > CAPB) total = CAPB;
    if (total < 0) total = 0;
    const unsigned int* seg = binreg + (long)b * CAPB;
    for (int i = tid; i < total; i += 512) stage[i] = seg[i];
    rcnt[tid] = 0;
    __syncthreads();
    for (int i = tid; i < total; i += 512) {
        unsigned pk = stage[i];
        if (pk != SENT) atomicAdd(&rcnt[(pk >> 16) & 511], 1);
    }
    __syncthreads();
    int v = rcnt[tid];
    scn[tid] = v;
    __syncthreads();
    for (int off = 1; off < 512; off <<= 1) {
        int t = (tid >= off) ? scn[tid - off] : 0;
        __syncthreads();
        scn[tid] += t;
        __syncthreads();
    }
    int base = bbase + scn[tid] - v;
    cur[tid] = base;
    int row = b * 512 + tid;
    if (row <= NROWS) csr_start[row] = base;
    __syncthreads();
    for (int i = tid; i < total; i += 512) {
        unsigned pk = stage[i];
        if (pk != SENT) {
            int pos = atomicAdd(&cur[(pk >> 16) & 511], 1);
            if (pos >= 0 && pos < NE) esrc[pos] = (unsigned short)(pk & 0xffffu);
        }
    }
}

// ---------------------------------------------------------------- K1: CSR gather, 4 rows/wave, uint4 loads
__global__ __launch_bounds__(256) void k_gather(
    const unsigned short* __restrict__ esrc, const int* __restrict__ csr_start,
    const uint4* __restrict__ x8, uint4* __restrict__ agg8)
{
    int row = blockIdx.x * 16 + (threadIdx.x >> 4);
    int lane = threadIdx.x & 63;
    int l4 = lane & 15, qw = lane >> 4;
    int e0 = csr_start[row], e1 = csr_start[row + 1];
    if ((unsigned)e0 > NE || (unsigned)e1 > NE || e1 < e0) { e0 = 0; e1 = 0; }
    int nch = (e1 - e0 + 15) >> 4;
    int n0 = __shfl(nch, 0, 64), n1 = __shfl(nch, 16, 64);
    int n2 = __shfl(nch, 32, 64), n3 = __shfl(nch, 48, 64);
    int nmax = max(max(n0, n1), max(n2, n3));
    float a0 = 0.f, a1 = 0.f, a2 = 0.f, a3 = 0.f, a4 = 0.f, a5 = 0.f, a6 = 0.f, a7 = 0.f;
    const int sb = qw << 4;
    for (int c = 0; c < nmax; ++c) {
        int base = e0 + c * 16;
        int rem = e1 - base;
        int pre = (l4 < rem) ? (int)esrc[base + l4] : 0;
        int m = rem < 16 ? (rem < 0 ? 0 : rem) : 16;
        int j = 0;
        for (; j + 3 < m; j += 4) {
            int sA = __shfl(pre, sb + j, 64);
            int sB = __shfl(pre, sb + j + 1, 64);
            int sC = __shfl(pre, sb + j + 2, 64);
            int sD = __shfl(pre, sb + j + 3, 64);
            uint4 v0 = x8[(long)sA * 16 + l4];
            uint4 v1 = x8[(long)sB * 16 + l4];
            uint4 v2 = x8[(long)sC * 16 + l4];
            uint4 v3 = x8[(long)sD * 16 + l4];
            a0 += blo(v0.x) + blo(v1.x) + blo(v2.x) + blo(v3.x);
            a1 += bhi(v0.x) + bhi(v1.x) + bhi(v2.x) + bhi(v3.x);
            a2 += blo(v0.y) + blo(v1.y) + blo(v2.y) + blo(v3.y);
            a3 += bhi(v0.y) + bhi(v1.y) + bhi(v2.y) + bhi(v3.y);
            a4 += blo(v0.z) + blo(v1.z) + blo(v2.z) + blo(v3.z);
            a5 += bhi(v0.z) + bhi(v1.z) + bhi(v2.z) + bhi(v3.z);
            a6 += blo(v0.w) + blo(v1.w) + blo(v2.w) + blo(v3.w);
            a7 += bhi(v0.w) + bhi(v1.w) + bhi(v2.w) + bhi(v3.w);
        }
        for (; j < m; ++j) {
            int sA = __shfl(pre, sb + j, 64);
            uint4 v0 = x8[(long)sA * 16 + l4];
            a0 += blo(v0.x); a1 += bhi(v0.x); a2 += blo(v0.y); a3 += bhi(v0.y);
            a4 += blo(v0.z); a5 += bhi(v0.z); a6 += blo(v0.w); a7 += bhi(v0.w);
        }
    }
    int hop = row / NN, node = row - hop * NN;
    uint4 o;
    o.x = pk2(a0, a1); o.y = pk2(a2, a3); o.z = pk2(a4, a5); o.w = pk2(a6, a7);
    agg8[((long)hop * NNP + node) * 16 + l4] = o;
}

// ---------------------------------------------------------------- K2: FUSED layer, 16 nodes/wave (64/block, 782 blocks)
// Grid was the occupancy limiter at 32 nodes/wave (1.5 waves/SIMD); halving the
// tile doubles resident waves (~3/SIMD) for latency hiding.
__global__ __launch_bounds__(256) void k_layer(
    const __bf16* __restrict__ x, const __bf16* __restrict__ agg,
    const __bf16* __restrict__ pwin, const float* __restrict__ bin,
    const __bf16* __restrict__ pwsk, const float* __restrict__ bsk,
    const __bf16* __restrict__ pw1a, const float* __restrict__ b1a,
    const __bf16* __restrict__ pw2a, const float* __restrict__ b2a,
    const __bf16* __restrict__ pw1b, const float* __restrict__ b1b,
    const __bf16* __restrict__ pw2b, const float* __restrict__ b2b,
    __bf16* __restrict__ xout)
{
    __shared__ __bf16 lds[4][16 * LSTR];
    const int lane = threadIdx.x & 63, wid = threadIdx.x >> 6;
    const int q = lane >> 4, l16 = lane & 15;
    const int nb = blockIdx.x * 64 + wid * 16;
    const int la = lane * 8;
    __bf16* L = lds[wid];
    const long r0 = (long)(nb + l16) * 128;
    const __bf16* planes[4] = {x, agg, agg + (long)NNP * 128, agg + 2L * NNP * 128};

    // ---- shell phase: [x|hop0|hop1|hop2] @ {Win,Wsk}, K=512, B-ring depth 8 ----
    bf16x8 ring[8];
#pragma unroll
    for (int k = 0; k < 8; ++k)
        ring[k] = *(const bf16x8*)(planes[k >> 2] + (k & 3) * 32 + q * 8 + r0);
    f32x4 aci[8], acs[8];
#pragma unroll
    for (int mt = 0; mt < 8; ++mt) { aci[mt] = (f32x4)(0.f); acs[mt] = (f32x4)(0.f); }
#pragma unroll
    for (int kt = 0; kt < 16; ++kt) {
        bf16x8 b0 = ring[kt & 7];
        if (kt < 8) {
            int k2 = kt + 8;
            ring[kt & 7] = *(const bf16x8*)(planes[k2 >> 2] + (k2 & 3) * 32 + q * 8 + r0);
        }
        const __bf16* aip = pwin + (long)kt * 4096 + la;
        const __bf16* asp = pwsk + (long)kt * 4096 + la;
#pragma unroll
        for (int mt = 0; mt < 8; ++mt) {
            aci[mt] = mm(*(const bf16x8*)(aip + mt * 512), b0, aci[mt]);
            acs[mt] = mm(*(const bf16x8*)(asp + mt * 512), b0, acs[mt]);
        }
    }
    bf16x4 gk[8];     // gskip in registers
    bf16x4 hs[8];     // h in registers (skip for p1)
#pragma unroll
    for (int mt = 0; mt < 8; ++mt) {
        int ch = mt * 16 + q * 4;
        float4 bi = *(const float4*)(bin + ch);
        float4 bs = *(const float4*)(bsk + ch);
        bf16x4 oh, og;
        oh[0] = (__bf16)silu_f(aci[mt][0] + bi.x);
        oh[1] = (__bf16)silu_f(aci[mt][1] + bi.y);
        oh[2] = (__bf16)silu_f(aci[mt][2] + bi.z);
        oh[3] = (__bf16)silu_f(aci[mt][3] + bi.w);
        og[0] = (__bf16)(acs[mt][0] + bs.x);
        og[1] = (__bf16)(acs[mt][1] + bs.y);
        og[2] = (__bf16)(acs[mt][2] + bs.z);
        og[3] = (__bf16)(acs[mt][3] + bs.w);
        hs[mt] = oh; gk[mt] = og;
        *(bf16x4*)(L + l16 * LSTR + ch) = oh;
    }
    __syncthreads();

    f32x4 acc[8];
    bf16x4 skipreg[8];

    // ---- p0: t1 = silu(h @ W1a + b1a) -> LDS ----
#pragma unroll
    for (int mt = 0; mt < 8; ++mt) acc[mt] = (f32x4)(0.f);
#pragma unroll
    for (int kt = 0; kt < 4; ++kt) {
        int koff = kt * 32 + q * 8;
        bf16x8 f0 = *(const bf16x8*)(L + l16 * LSTR + koff);
        const __bf16* ap = pw1a + (long)kt * 4096 + la;
#pragma unroll
        for (int mt = 0; mt < 8; ++mt)
            acc[mt] = mm(*(const bf16x8*)(ap + mt * 512), f0, acc[mt]);
    }
    __syncthreads();
#pragma unroll
    for (int mt = 0; mt < 8; ++mt) {
        int ch = mt * 16 + q * 4;
        float4 bb = *(const float4*)(b1a + ch);
        bf16x4 o;
        o[0] = (__bf16)silu_f(acc[mt][0] + bb.x);
        o[1] = (__bf16)silu_f(acc[mt][1] + bb.y);
        o[2] = (__bf16)silu_f(acc[mt][2] + bb.z);
        o[3] = (__bf16)silu_f(acc[mt][3] + bb.w);
        *(bf16x4*)(L + l16 * LSTR + ch) = o;
    }
    __syncthreads();

    // ---- p1: h2 = t1 @ W2a + b2a + h -> LDS + skipreg ----
#pragma unroll
    for (int mt = 0; mt < 8; ++mt) acc[mt] = (f32x4)(0.f);
#pragma unroll
    for (int kt = 0; kt < 4; ++kt) {
        int koff = kt * 32 + q * 8;
        bf16x8 f0 = *(const bf16x8*)(L + l16 * LSTR + koff);
        const __bf16* ap = pw2a + (long)kt * 4096 + la;
#pragma unroll
        for (int mt = 0; mt < 8; ++mt)
            acc[mt] = mm(*(const bf16x8*)(ap + mt * 512), f0, acc[mt]);
    }
    __syncthreads();
#pragma unroll
    for (int mt = 0; mt < 8; ++mt) {
        int ch = mt * 16 + q * 4;
        float4 bb = *(const float4*)(b2a + ch);
        bf16x4 sk = hs[mt];
        bf16x4 o;
        o[0] = (__bf16)(acc[mt][0] + bb.x + (float)sk[0]);
        o[1] = (__bf16)(acc[mt][1] + bb.y + (float)sk[1]);
        o[2] = (__bf16)(acc[mt][2] + bb.z + (float)sk[2]);
        o[3] = (__bf16)(acc[mt][3] + bb.w + (float)sk[3]);
        skipreg[mt] = o;
        *(bf16x4*)(L + l16 * LSTR + ch) = o;
    }
    __syncthreads();

    // ---- p2: t2 = silu(h2 @ W1b + b1b) -> LDS ----
#pragma unroll
    for (int mt = 0; mt < 8; ++mt) acc[mt] = (f32x4)(0.f);
#pragma unroll
    for (int kt = 0; kt < 4; ++kt) {
        int koff = kt * 32 + q * 8;
        bf16x8 f0 = *(const bf16x8*)(L + l16 * LSTR + koff);
        const __bf16* ap = pw1b + (long)kt * 4096 + la;
#pragma unroll
        for (int mt = 0; mt < 8; ++mt)
            acc[mt] = mm(*(const bf16x8*)(ap + mt * 512), f0, acc[mt]);
    }
    __syncthreads();
#pragma unroll
    for (int mt = 0; mt < 8; ++mt) {
        int ch = mt * 16 + q * 4;
        float4 bb = *(const float4*)(b1b + ch);
        bf16x4 o;
        o[0] = (__bf16)silu_f(acc[mt][0] + bb.x);
        o[1] = (__bf16)silu_f(acc[mt][1] + bb.y);
        o[2] = (__bf16)silu_f(acc[mt][2] + bb.z);
        o[3] = (__bf16)silu_f(acc[mt][3] + bb.w);
        *(bf16x4*)(L + l16 * LSTR + ch) = o;
    }
    __syncthreads();

    // ---- p3: x = t2 @ W2b + b2b + h2 + gskip -> global ----
#pragma unroll
    for (int mt = 0; mt < 8; ++mt) acc[mt] = (f32x4)(0.f);
#pragma unroll
    for (int kt = 0; kt < 4; ++kt) {
        int koff = kt * 32 + q * 8;
        bf16x8 f0 = *(const bf16x8*)(L + l16 * LSTR + koff);
        const __bf16* ap = pw2b + (long)kt * 4096 + la;
#pragma unroll
        for (int mt = 0; mt < 8; ++mt)
            acc[mt] = mm(*(const bf16x8*)(ap + mt * 512), f0, acc[mt]);
    }
    long node = nb + l16;
#pragma unroll
    for (int mt = 0; mt < 8; ++mt) {
        int ch = mt * 16 + q * 4;
        float4 bb = *(const float4*)(b2b + ch);
        bf16x4 sk = skipreg[mt];
        bf16x4 g = gk[mt];
        bf16x4 o;
        o[0] = (__bf16)(acc[mt][0] + bb.x + (float)sk[0] + (float)g[0]);
        o[1] = (__bf16)(acc[mt][1] + bb.y + (float)sk[1] + (float)g[1]);
        o[2] = (__bf16)(acc[mt][2] + bb.z + (float)sk[2] + (float)g[2]);
        o[3] = (__bf16)(acc[mt][3] + bb.w + (float)sk[3] + (float)g[3]);
        *(bf16x4*)(xout + node * 128 + ch) = o;
    }
}

// ---------------------------------------------------------------- K4: attention scores
__global__ __launch_bounds__(256) void k_scores(
    const __bf16* __restrict__ x, const float* __restrict__ aw,
    const float* __restrict__ ab, const float* __restrict__ temp,
    float* __restrict__ scores)
{
    int wave = threadIdx.x >> 6, lane = threadIdx.x & 63;
    int n = blockIdx.x * 4 + wave;
    if (n >= NN) return;
    float x0 = (float)x[(long)n * H + lane];
    float x1 = (float)x[(long)n * H + 64 + lane];
    float T = temp[0];
#pragma unroll
    for (int hh = 0; hh < NHEADS; ++hh) {
        float p = x0 * aw[hh * H + lane] + x1 * aw[hh * H + 64 + lane];
#pragma unroll
        for (int off = 32; off >= 1; off >>= 1) p += __shfl_xor(p, off, 64);
        if (lane == 0) scores[n * NHEADS + hh] = (p + ab[hh]) / T;
    }
}

// ---------------------------------------------------------------- K5: graph offsets
__global__ __launch_bounds__(256) void k_offsets(
    const int* __restrict__ batch, int* __restrict__ gstart)
{
    int n = blockIdx.x * 256 + threadIdx.x;
    if (n >= NN) return;
    int b = batch[n];
    int bp = (n == 0) ? -1 : batch[n - 1];
    for (int g = bp + 1; g <= b; ++g) gstart[g] = n;
    if (n == NN - 1) for (int g = b + 1; g <= NG; ++g) gstart[g] = NN;
}

// ---------------------------------------------------------------- K6: softmax pool
__global__ __launch_bounds__(64) void k_pool(
    const __bf16* __restrict__ x, const float* __restrict__ scores,
    const int* __restrict__ gstart, float* __restrict__ pooled)
{
    int g = blockIdx.x, lane = threadIdx.x;
    int s0 = gstart[g], s1 = gstart[g + 1];
    float m0 = -INFINITY, m1 = -INFINITY, m2 = -INFINITY, m3 = -INFINITY;
    for (int n = s0 + lane; n < s1; n += 64) {
        m0 = fmaxf(m0, scores[n * 4 + 0]); m1 = fmaxf(m1, scores[n * 4 + 1]);
        m2 = fmaxf(m2, scores[n * 4 + 2]); m3 = fmaxf(m3, scores[n * 4 + 3]);
    }
#pragma unroll
    for (int off = 32; off >= 1; off >>= 1) {
        m0 = fmaxf(m0, __shfl_xor(m0, off, 64)); m1 = fmaxf(m1, __shfl_xor(m1, off, 64));
        m2 = fmaxf(m2, __shfl_xor(m2, off, 64)); m3 = fmaxf(m3, __shfl_xor(m3, off, 64));
    }
    float d0 = 0.f, d1 = 0.f, d2 = 0.f, d3 = 0.f;
    for (int n = s0 + lane; n < s1; n += 64) {
        d0 += expf(scores[n * 4 + 0] - m0); d1 += expf(scores[n * 4 + 1] - m1);
        d2 += expf(scores[n * 4 + 2] - m2); d3 += expf(scores[n * 4 + 3] - m3);
    }
#pragma unroll
    for (int off = 32; off >= 1; off >>= 1) {
        d0 += __shfl_xor(d0, off, 64); d1 += __shfl_xor(d1, off, 64);
        d2 += __shfl_xor(d2, off, 64); d3 += __shfl_xor(d3, off, 64);
    }
    float i0 = d0 > 0.f ? 1.f / d0 : 0.f;
    float i1 = d1 > 0.f ? 1.f / d1 : 0.f;
    float i2 = d2 > 0.f ? 1.f / d2 : 0.f;
    float i3 = d3 > 0.f ? 1.f / d3 : 0.f;
    float a0 = 0.f, a1 = 0.f;
    for (int n = s0; n < s1; ++n) {
        float wb = expf(scores[n * 4 + 0] - m0) * i0 + expf(scores[n * 4 + 1] - m1) * i1
                 + expf(scores[n * 4 + 2] - m2) * i2 + expf(scores[n * 4 + 3] - m3) * i3;
        wb *= 0.25f;
        a0 += wb * (float)x[(long)n * H + lane];
        a1 += wb * (float)x[(long)n * H + 64 + lane];
    }
    pooled[g * H + lane] = a0;
    pooled[g * H + 64 + lane] = a1;
}

// ---------------------------------------------------------------- K7: FFN readout
__global__ __launch_bounds__(128) void k_ffn(
    const float* __restrict__ pooled,
    const float* __restrict__ W1, const float* __restrict__ B1,
    const float* __restrict__ W2, const float* __restrict__ B2,
    const float* __restrict__ W3, const float* __restrict__ B3,
    float* __restrict__ out)
{
    __shared__ float p[H], t1[H], t2[H], red[H];
    int g = blockIdx.x, c = threadIdx.x;
    p[c] = pooled[g * H + c];
    __syncthreads();
    float acc = 0.f;
    for (int k = 0; k < H; ++k) acc += p[k] * W1[k * H + c];
    t1[c] = silu_f(acc + B1[c]);
    __syncthreads();
    acc = 0.f;
    for (int k = 0; k < H; ++k) acc += t1[k] * W2[k * H + c];
    t2[c] = silu_f(acc + B2[c]);
    __syncthreads();
    red[c] = t2[c] * W3[c];
    __syncthreads();
    for (int off = 64; off >= 1; off >>= 1) {
        if (c < off) red[c] += red[c + off];
        __syncthreads();
    }
    if (c == 0) out[g] = red[0] + B3[0];
}

// ---------------------------------------------------------------- launch
extern "C" void kernel_launch(void* const* d_in, const int* in_sizes, int n_in,
                              void* d_out, int out_size, void* d_ws, size_t ws_size,
                              hipStream_t stream)
{
    const int*   atom   = (const int*)d_in[0];
    const int*   hc     = (const int*)d_in[1];
    const int*   deg    = (const int*)d_in[2];
    const int*   hyb    = (const int*)d_in[3];
    const int*   target = (const int*)d_in[4];
    const int*   src    = (const int*)d_in[5];
    const int*   batch  = (const int*)d_in[6];
    const float* Ea     = (const float*)d_in[7];
    const float* Eh     = (const float*)d_in[8];
    const float* Ed     = (const float*)d_in[9];
    const float* Ey     = (const float*)d_in[10];
    const float* projW  = (const float*)d_in[11];
    const float* projB  = (const float*)d_in[12];
    const float* sInW   = (const float*)d_in[13];
    const float* sInB   = (const float*)d_in[14];
    const float* mW1    = (const float*)d_in[15];
    const float* mB1    = (const float*)d_in[16];
    const float* mW2    = (const float*)d_in[17];
    const float* mB2    = (const float*)d_in[18];
    const float* sSkW   = (const float*)d_in[19];
    const float* sSkB   = (const float*)d_in[20];
    const float* attnW  = (const float*)d_in[21];
    const float* attnB  = (const float*)d_in[22];
    const float* temp   = (const float*)d_in[23];
    const float* fW1    = (const float*)d_in[24];
    const float* fB1    = (const float*)d_in[25];
    const float* fW2    = (const float*)d_in[26];
    const float* fB2    = (const float*)d_in[27];
    const float* fW3    = (const float*)d_in[28];
    const float* fB3    = (const float*)d_in[29];
    float* out = (float*)d_out;

    char* w = (char*)d_ws;
    auto take = [&](size_t bytes) { void* p = (void*)w; w += (bytes + 255) & ~(size_t)255; return p; };
    __bf16* x      = (__bf16*)take(2L * NNP * H);
    __bf16* agg    = (__bf16*)take(2L * 3 * NNP * H);
    __bf16* pproj  = (__bf16*)take(2L * 256 * H);
    __bf16* pin    = (__bf16*)take(2L * 3 * 512 * H);
    __bf16* psk    = (__bf16*)take(2L * 3 * 512 * H);
    __bf16* pw1    = (__bf16*)take(2L * 6 * 128 * H);
    __bf16* pw2    = (__bf16*)take(2L * 6 * 128 * H);
    __bf16* embb   = (__bf16*)take(2L * 8000);
    float*  scores = (float*)take(4L * NN * NHEADS);
    float*  pooled = (float*)take(4L * NG * H);
    int*    gstart = (int*)take(4L * (NG + 1));
    int*    csr_start = (int*)take(4L * (NROWS + 1));
    unsigned int*   binreg = (unsigned int*)take(4L * NBIN * CAPB);   // 12 MB
    unsigned short* esrc   = (unsigned short*)take(2L * NE);
    // gbincur + brealc in ONE contiguous allocation (one memset covers both)
    int*    gbincur = (int*)take(4L * 2 * NBIN);
    int*    brealc  = gbincur + NBIN;

    // ---- fused weight pack + emb convert (weights restored each call) ----
    k_packall<<<(630592 + 255) / 256, 256, 0, stream>>>(
        projW, pproj, sInW, pin, sSkW, psk, mW1, pw1, mW2, pw2,
        Ea, Eh, Ed, Ey, embb);

    // ---- CSR build: write-combined binning -> per-bin finalize ----
    hipMemsetAsync(gbincur, 0, sizeof(int) * 2 * NBIN, stream);
    k_binA<<<ABLK, 256, 0, stream>>>(target, src, gbincur, brealc, binreg);
    k_fill2b<<<NBIN, 512, 0, stream>>>(binreg, gbincur, brealc, csr_start, esrc);

    k_embed_m<<<NNP / 128, 256, 0, stream>>>(atom, hc, deg, hyb, embb, pproj, projB, x);
    k_offsets<<<(NN + 255) / 256, 256, 0, stream>>>(batch, gstart);

    for (int l = 0; l < NL; ++l) {
        k_gather<<<NROWS / 16, 256, 0, stream>>>(esrc, csr_start,
            (const uint4*)x, (uint4*)agg);
        k_layer<<<NNP / 64, 256, 0, stream>>>(x, agg,
            pin + (long)l * 512 * H, sInB + l * H,
            psk + (long)l * 512 * H, sSkB + l * H,
            pw1 + (long)(l * NMLP + 0) * 128 * H, mB1 + (long)(l * NMLP + 0) * H,
            pw2 + (long)(l * NMLP + 0) * 128 * H, mB2 + (long)(l * NMLP + 0) * H,
            pw1 + (long)(l * NMLP + 1) * 128 * H, mB1 + (long)(l * NMLP + 1) * H,
            pw2 + (long)(l * NMLP + 1) * 128 * H, mB2 + (long)(l * NMLP + 1) * H,
            x);
    }

    k_scores<<<NN / 4, 256, 0, stream>>>(x, attnW, attnB, temp, scores);
    k_pool<<<NG, 64, 0, stream>>>(x, scores, gstart, pooled);
    k_ffn<<<NG, 128, 0, stream>>>(pooled, fW1, fB1, fW2, fB2, fW3, fB3, out);
}

// Round 11
// 696.776 us; speedup vs baseline: 19.4859x; 1.1084x over previous
//
#include <hip/hip_runtime.h>
#include <math.h>

#define NN      50000
#define NNP     50048          // padded nodes = 391*128
#define NE      2400000
#define NHOPS   3
#define NG      2048
#define H       128
#define EMBD    64
#define NL      3
#define NMLP    2
#define NHEADS  4
#define NROWS   (NHOPS * NN)   // 150000
#define BINSH   9              // 512 rows per coarse bin
#define NBIN    293            // ceil(150016/512)
#define CAPB    10240          // per-bin region capacity
#define ABLK    480            // binning blocks
#define DEPTH   32             // LDS circular buffer depth per bin
#define LSTR    136
#define SENT    0xFFFFFFFFu

typedef __bf16 bf16x8 __attribute__((ext_vector_type(8)));
typedef __bf16 bf16x4 __attribute__((ext_vector_type(4)));
typedef float  f32x4  __attribute__((ext_vector_type(4)));

__device__ __forceinline__ float silu_f(float v) { return v / (1.0f + expf(-v)); }

__device__ __forceinline__ f32x4 mm(bf16x8 a, bf16x8 b, f32x4 c) {
    return __builtin_amdgcn_mfma_f32_16x16x32_bf16(a, b, c, 0, 0, 0);
}

__device__ __forceinline__ float blo(unsigned v) { return __builtin_bit_cast(float, v << 16); }
__device__ __forceinline__ float bhi(unsigned v) { return __builtin_bit_cast(float, v & 0xffff0000u); }
__device__ __forceinline__ unsigned pk2(float a, float b) {
    unsigned short ua = __builtin_bit_cast(unsigned short, (__bf16)a);
    unsigned short ub = __builtin_bit_cast(unsigned short, (__bf16)b);
    return (unsigned)ua | ((unsigned)ub << 16);
}

// ---------------------------------------------------------------- fused weight pack + emb convert
__device__ __forceinline__ void packw_elem(
    const float* __restrict__ W, __bf16* __restrict__ out, int K, long idx)
{
    long per = (long)K * 128;
    long mat = idx / per, e = idx - mat * per;
    int j = (int)(e & 7), n16 = (int)((e >> 3) & 15), q = (int)((e >> 7) & 3),
        mt = (int)((e >> 9) & 7), kt = (int)(e >> 12);
    int k = kt * 32 + q * 8 + j, n = mt * 16 + n16;
    out[idx] = (__bf16)W[mat * per + (long)k * 128 + n];
}

__global__ __launch_bounds__(256) void k_packall(
    const float* __restrict__ projW, __bf16* __restrict__ pproj,
    const float* __restrict__ sInW,  __bf16* __restrict__ pin,
    const float* __restrict__ sSkW,  __bf16* __restrict__ psk,
    const float* __restrict__ mW1,   __bf16* __restrict__ pw1,
    const float* __restrict__ mW2,   __bf16* __restrict__ pw2,
    const float* __restrict__ Ea, const float* __restrict__ Eh,
    const float* __restrict__ Ed, const float* __restrict__ Ey,
    __bf16* __restrict__ embb)
{
    long tid = (long)blockIdx.x * 256 + threadIdx.x;
    if (tid < 32768) { packw_elem(projW, pproj, 256, tid); return; }
    tid -= 32768;
    if (tid < 196608) { packw_elem(sInW, pin, 512, tid); return; }
    tid -= 196608;
    if (tid < 196608) { packw_elem(sSkW, psk, 512, tid); return; }
    tid -= 196608;
    if (tid < 98304) { packw_elem(mW1, pw1, 128, tid); return; }
    tid -= 98304;
    if (tid < 98304) { packw_elem(mW2, pw2, 128, tid); return; }
    tid -= 98304;
    if (tid < 8000) {
        int t = (int)tid;
        float v;
        if (t < 6400) v = Ea[t];
        else if (t < 6976) v = Eh[t - 6400];
        else if (t < 7488) v = Ed[t - 6976];
        else v = Ey[t - 7488];
        embb[t] = (__bf16)v;
    }
}

// ---------------------------------------------------------------- K0: embed + project + silu (MFMA)
__global__ __launch_bounds__(256) void k_embed_m(
    const int* __restrict__ atom, const int* __restrict__ hc,
    const int* __restrict__ deg,  const int* __restrict__ hyb,
    const __bf16* __restrict__ emb, const __bf16* __restrict__ pw,
    const float* __restrict__ pb, __bf16* __restrict__ x)
{
    const int lane = threadIdx.x & 63, wid = threadIdx.x >> 6;
    const int q = lane >> 4, l16 = lane & 15;
    const int nb = blockIdx.x * 128 + wid * 32;
    int ia[2][4];
#pragma unroll
    for (int nt = 0; nt < 2; ++nt) {
        int n = nb + nt * 16 + l16;
        if (n >= NN) n = NN - 1;
        ia[nt][0] = atom[n]; ia[nt][1] = hc[n]; ia[nt][2] = deg[n]; ia[nt][3] = hyb[n];
    }
    f32x4 acc[2][8];
#pragma unroll
    for (int nt = 0; nt < 2; ++nt)
#pragma unroll
        for (int mt = 0; mt < 8; ++mt) acc[nt][mt] = (f32x4)(0.f);
    const int tb[4] = {0, 6400, 6976, 7488};
    for (int kt = 0; kt < 8; ++kt) {
        int t = kt >> 1;
        int koff = (kt & 1) * 32 + q * 8;
        bf16x8 bfrag[2];
#pragma unroll
        for (int nt = 0; nt < 2; ++nt)
            bfrag[nt] = *(const bf16x8*)(emb + tb[t] + (long)ia[nt][t] * 64 + koff);
        const __bf16* ap = pw + (long)kt * 4096 + lane * 8;
#pragma unroll
        for (int mt = 0; mt < 8; ++mt) {
            bf16x8 a = *(const bf16x8*)(ap + mt * 512);
            acc[0][mt] = mm(a, bfrag[0], acc[0][mt]);
            acc[1][mt] = mm(a, bfrag[1], acc[1][mt]);
        }
    }
#pragma unroll
    for (int nt = 0; nt < 2; ++nt) {
        long node = nb + nt * 16 + l16;
#pragma unroll
        for (int mt = 0; mt < 8; ++mt) {
            int ch = mt * 16 + q * 4;
            float4 bb = *(const float4*)(pb + ch);
            bf16x4 o;
            o[0] = (__bf16)silu_f(acc[nt][mt][0] + bb.x);
            o[1] = (__bf16)silu_f(acc[nt][mt][1] + bb.y);
            o[2] = (__bf16)silu_f(acc[nt][mt][2] + bb.z);
            o[3] = (__bf16)silu_f(acc[nt][mt][3] + bb.w);
            *(bf16x4*)(x + node * 128 + ch) = o;
        }
    }
}

// ---------------------------------------------------------------- CSR pass A: LDS write-combined binning
__global__ __launch_bounds__(256) void k_binA(
    const int* __restrict__ target, const int* __restrict__ src,
    int* __restrict__ gbincur, int* __restrict__ brealc,
    unsigned int* __restrict__ binreg)
{
    __shared__ unsigned int buf[NBIN][DEPTH];
    __shared__ int cnt[NBIN];
    __shared__ int flushed[NBIN];
    const int tid = threadIdx.x;
    for (int i = tid; i < NBIN; i += 256) { cnt[i] = 0; flushed[i] = 0; }
    __syncthreads();
    const int per = (NE + ABLK - 1) / ABLK;   // 5000
    const int e0 = blockIdx.x * per;
    const int e1 = (e0 + per < NE) ? e0 + per : NE;
    for (int base = e0; base < e1; base += 256) {
        int e = base + tid;
        if (e < e1) {
            int s = src[e];
            if (s >= 2 * NN) s -= 2 * NN; else if (s >= NN) s -= NN;
            int t = target[e];
            int bin = t >> BINSH;
            unsigned val = (unsigned)s | ((unsigned)(t & ((1 << BINSH) - 1)) << 16);
            int slot = atomicAdd(&cnt[bin], 1);
            buf[bin][slot & (DEPTH - 1)] = val;
        }
        __syncthreads();
        for (int b = tid; b < NBIN; b += 256) {
            while (cnt[b] - flushed[b] >= 16) {
                int pos = atomicAdd(&gbincur[b], 16);
                if (pos + 16 <= CAPB) {
                    uint4* d4 = (uint4*)(binreg + (long)b * CAPB + pos);
                    const uint4* s4 = (const uint4*)&buf[b][flushed[b] & (DEPTH - 1)];
                    d4[0] = s4[0]; d4[1] = s4[1]; d4[2] = s4[2]; d4[3] = s4[3];
                }
                flushed[b] += 16;
            }
        }
        __syncthreads();
    }
    for (int b = tid; b < NBIN; b += 256) {
        int lvl = cnt[b] - flushed[b];
        if (cnt[b] > 0) atomicAdd(&brealc[b], cnt[b]);
        if (lvl > 0) {
            int pad = (lvl + 3) & ~3;
            int pos = atomicAdd(&gbincur[b], pad);
            for (int i = 0; i < pad; i += 4) {
                uint4 v;
                v.x = (i + 0 < lvl) ? buf[b][(flushed[b] + i + 0) & (DEPTH - 1)] : SENT;
                v.y = (i + 1 < lvl) ? buf[b][(flushed[b] + i + 1) & (DEPTH - 1)] : SENT;
                v.z = (i + 2 < lvl) ? buf[b][(flushed[b] + i + 2) & (DEPTH - 1)] : SENT;
                v.w = (i + 3 < lvl) ? buf[b][(flushed[b] + i + 3) & (DEPTH - 1)] : SENT;
                if (pos + i + 4 <= CAPB)
                    *(uint4*)(binreg + (long)b * CAPB + pos + i) = v;
            }
        }
    }
}

// ---------------------------------------------------------------- CSR pass B: per-bin LDS finalize
__global__ __launch_bounds__(512) void k_fill2b(
    const unsigned int* __restrict__ binreg, const int* __restrict__ gbincur,
    const int* __restrict__ brealc, int* __restrict__ csr_start,
    unsigned short* __restrict__ esrc)
{
    __shared__ unsigned int stage[CAPB];
    __shared__ int pc[512], rcnt[512], scn[512], cur[512];
    const int b = blockIdx.x, tid = threadIdx.x;
    int pv = (tid < NBIN) ? brealc[tid] : 0;
    if (pv < 0) pv = 0;
    pc[tid] = pv;
    __syncthreads();
    for (int off = 1; off < 512; off <<= 1) {
        int t = (tid >= off) ? pc[tid - off] : 0;
        __syncthreads();
        pc[tid] += t;
        __syncthreads();
    }
    int bbase = (b == 0) ? 0 : pc[b - 1];
    int total = gbincur[b];
    if (total > CAPB) total = CAPB;
    if (total < 0) total = 0;
    const unsigned int* seg = binreg + (long)b * CAPB;
    for (int i = tid; i < total; i += 512) stage[i] = seg[i];
    rcnt[tid] = 0;
    __syncthreads();
    for (int i = tid; i < total; i += 512) {
        unsigned pk = stage[i];
        if (pk != SENT) atomicAdd(&rcnt[(pk >> 16) & 511], 1);
    }
    __syncthreads();
    int v = rcnt[tid];
    scn[tid] = v;
    __syncthreads();
    for (int off = 1; off < 512; off <<= 1) {
        int t = (tid >= off) ? scn[tid - off] : 0;
        __syncthreads();
        scn[tid] += t;
        __syncthreads();
    }
    int base = bbase + scn[tid] - v;
    cur[tid] = base;
    int row = b * 512 + tid;
    if (row <= NROWS) csr_start[row] = base;
    __syncthreads();
    for (int i = tid; i < total; i += 512) {
        unsigned pk = stage[i];
        if (pk != SENT) {
            int pos = atomicAdd(&cur[(pk >> 16) & 511], 1);
            if (pos >= 0 && pos < NE) esrc[pos] = (unsigned short)(pk & 0xffffu);
        }
    }
}

// ---------------------------------------------------------------- K1: CSR gather, 4 rows/wave, uint4 loads
__global__ __launch_bounds__(256) void k_gather(
    const unsigned short* __restrict__ esrc, const int* __restrict__ csr_start,
    const uint4* __restrict__ x8, uint4* __restrict__ agg8)
{
    int row = blockIdx.x * 16 + (threadIdx.x >> 4);
    int lane = threadIdx.x & 63;
    int l4 = lane & 15, qw = lane >> 4;
    int e0 = csr_start[row], e1 = csr_start[row + 1];
    if ((unsigned)e0 > NE || (unsigned)e1 > NE || e1 < e0) { e0 = 0; e1 = 0; }
    int nch = (e1 - e0 + 15) >> 4;
    int n0 = __shfl(nch, 0, 64), n1 = __shfl(nch, 16, 64);
    int n2 = __shfl(nch, 32, 64), n3 = __shfl(nch, 48, 64);
    int nmax = max(max(n0, n1), max(n2, n3));
    float a0 = 0.f, a1 = 0.f, a2 = 0.f, a3 = 0.f, a4 = 0.f, a5 = 0.f, a6 = 0.f, a7 = 0.f;
    const int sb = qw << 4;
    for (int c = 0; c < nmax; ++c) {
        int base = e0 + c * 16;
        int rem = e1 - base;
        int pre = (l4 < rem) ? (int)esrc[base + l4] : 0;
        int m = rem < 16 ? (rem < 0 ? 0 : rem) : 16;
        int j = 0;
        for (; j + 3 < m; j += 4) {
            int sA = __shfl(pre, sb + j, 64);
            int sB = __shfl(pre, sb + j + 1, 64);
            int sC = __shfl(pre, sb + j + 2, 64);
            int sD = __shfl(pre, sb + j + 3, 64);
            uint4 v0 = x8[(long)sA * 16 + l4];
            uint4 v1 = x8[(long)sB * 16 + l4];
            uint4 v2 = x8[(long)sC * 16 + l4];
            uint4 v3 = x8[(long)sD * 16 + l4];
            a0 += blo(v0.x) + blo(v1.x) + blo(v2.x) + blo(v3.x);
            a1 += bhi(v0.x) + bhi(v1.x) + bhi(v2.x) + bhi(v3.x);
            a2 += blo(v0.y) + blo(v1.y) + blo(v2.y) + blo(v3.y);
            a3 += bhi(v0.y) + bhi(v1.y) + bhi(v2.y) + bhi(v3.y);
            a4 += blo(v0.z) + blo(v1.z) + blo(v2.z) + blo(v3.z);
            a5 += bhi(v0.z) + bhi(v1.z) + bhi(v2.z) + bhi(v3.z);
            a6 += blo(v0.w) + blo(v1.w) + blo(v2.w) + blo(v3.w);
            a7 += bhi(v0.w) + bhi(v1.w) + bhi(v2.w) + bhi(v3.w);
        }
        for (; j < m; ++j) {
            int sA = __shfl(pre, sb + j, 64);
            uint4 v0 = x8[(long)sA * 16 + l4];
            a0 += blo(v0.x); a1 += bhi(v0.x); a2 += blo(v0.y); a3 += bhi(v0.y);
            a4 += blo(v0.z); a5 += bhi(v0.z); a6 += blo(v0.w); a7 += bhi(v0.w);
        }
    }
    int hop = row / NN, node = row - hop * NN;
    uint4 o;
    o.x = pk2(a0, a1); o.y = pk2(a2, a3); o.z = pk2(a4, a5); o.w = pk2(a6, a7);
    agg8[((long)hop * NNP + node) * 16 + l4] = o;
}

// ---------------------------------------------------------------- K2: FUSED layer, channel-split wave pairs
// 16 nodes per wave PAIR; wave covers 64 output channels (mt half). Grid 2x R9
// (1564 blocks, ~6 waves/SIMD); per-wave A-traffic mt-partitioned (total const).
__global__ __launch_bounds__(256) void k_layer(
    const __bf16* __restrict__ x, const __bf16* __restrict__ agg,
    const __bf16* __restrict__ pwin, const float* __restrict__ bin,
    const __bf16* __restrict__ pwsk, const float* __restrict__ bsk,
    const __bf16* __restrict__ pw1a, const float* __restrict__ b1a,
    const __bf16* __restrict__ pw2a, const float* __restrict__ b2a,
    const __bf16* __restrict__ pw1b, const float* __restrict__ b1b,
    const __bf16* __restrict__ pw2b, const float* __restrict__ b2b,
    __bf16* __restrict__ xout)
{
    __shared__ __bf16 lds[2][16 * LSTR];
    const int lane = threadIdx.x & 63, wid = threadIdx.x >> 6;
    const int pair = wid >> 1, half = wid & 1;
    const int q = lane >> 4, l16 = lane & 15;
    const int nb = blockIdx.x * 32 + pair * 16;
    const int mtoff = half * 4 * 512;        // A-frag offset for this wave's mt half
    const int chb = half * 64;               // channel base
    const int la = lane * 8;
    __bf16* L = lds[pair];
    const long r0 = (long)(nb + l16) * 128;
    const __bf16* planes[4] = {x, agg, agg + (long)NNP * 128, agg + 2L * NNP * 128};

    // ---- shell phase: [x|hop0|hop1|hop2] @ {Win,Wsk}, K=512, B-ring depth 8 ----
    bf16x8 ring[8];
#pragma unroll
    for (int k = 0; k < 8; ++k)
        ring[k] = *(const bf16x8*)(planes[k >> 2] + (k & 3) * 32 + q * 8 + r0);
    f32x4 aci[4], acs[4];
#pragma unroll
    for (int mt = 0; mt < 4; ++mt) { aci[mt] = (f32x4)(0.f); acs[mt] = (f32x4)(0.f); }
#pragma unroll
    for (int kt = 0; kt < 16; ++kt) {
        bf16x8 b0 = ring[kt & 7];
        if (kt < 8) {
            int k2 = kt + 8;
            ring[kt & 7] = *(const bf16x8*)(planes[k2 >> 2] + (k2 & 3) * 32 + q * 8 + r0);
        }
        const __bf16* aip = pwin + (long)kt * 4096 + mtoff + la;
        const __bf16* asp = pwsk + (long)kt * 4096 + mtoff + la;
#pragma unroll
        for (int mt = 0; mt < 4; ++mt) {
            aci[mt] = mm(*(const bf16x8*)(aip + mt * 512), b0, aci[mt]);
            acs[mt] = mm(*(const bf16x8*)(asp + mt * 512), b0, acs[mt]);
        }
    }
    bf16x4 gk[4];     // gskip in registers
    bf16x4 hs[4];     // h in registers (skip for p1)
#pragma unroll
    for (int mt = 0; mt < 4; ++mt) {
        int ch = chb + mt * 16 + q * 4;
        float4 bi = *(const float4*)(bin + ch);
        float4 bs = *(const float4*)(bsk + ch);
        bf16x4 oh, og;
        oh[0] = (__bf16)silu_f(aci[mt][0] + bi.x);
        oh[1] = (__bf16)silu_f(aci[mt][1] + bi.y);
        oh[2] = (__bf16)silu_f(aci[mt][2] + bi.z);
        oh[3] = (__bf16)silu_f(aci[mt][3] + bi.w);
        og[0] = (__bf16)(acs[mt][0] + bs.x);
        og[1] = (__bf16)(acs[mt][1] + bs.y);
        og[2] = (__bf16)(acs[mt][2] + bs.z);
        og[3] = (__bf16)(acs[mt][3] + bs.w);
        hs[mt] = oh; gk[mt] = og;
        *(bf16x4*)(L + l16 * LSTR + ch) = oh;
    }
    __syncthreads();

    f32x4 acc[4];
    bf16x4 skipreg[4];

    // ---- p0: t1 = silu(h @ W1a + b1a) -> LDS ----
#pragma unroll
    for (int mt = 0; mt < 4; ++mt) acc[mt] = (f32x4)(0.f);
#pragma unroll
    for (int kt = 0; kt < 4; ++kt) {
        int koff = kt * 32 + q * 8;
        bf16x8 f0 = *(const bf16x8*)(L + l16 * LSTR + koff);
        const __bf16* ap = pw1a + (long)kt * 4096 + mtoff + la;
#pragma unroll
        for (int mt = 0; mt < 4; ++mt)
            acc[mt] = mm(*(const bf16x8*)(ap + mt * 512), f0, acc[mt]);
    }
    __syncthreads();
#pragma unroll
    for (int mt = 0; mt < 4; ++mt) {
        int ch = chb + mt * 16 + q * 4;
        float4 bb = *(const float4*)(b1a + ch);
        bf16x4 o;
        o[0] = (__bf16)silu_f(acc[mt][0] + bb.x);
        o[1] = (__bf16)silu_f(acc[mt][1] + bb.y);
        o[2] = (__bf16)silu_f(acc[mt][2] + bb.z);
        o[3] = (__bf16)silu_f(acc[mt][3] + bb.w);
        *(bf16x4*)(L + l16 * LSTR + ch) = o;
    }
    __syncthreads();

    // ---- p1: h2 = t1 @ W2a + b2a + h -> LDS + skipreg ----
#pragma unroll
    for (int mt = 0; mt < 4; ++mt) acc[mt] = (f32x4)(0.f);
#pragma unroll
    for (int kt = 0; kt < 4; ++kt) {
        int koff = kt * 32 + q * 8;
        bf16x8 f0 = *(const bf16x8*)(L + l16 * LSTR + koff);
        const __bf16* ap = pw2a + (long)kt * 4096 + mtoff + la;
#pragma unroll
        for (int mt = 0; mt < 4; ++mt)
            acc[mt] = mm(*(const bf16x8*)(ap + mt * 512), f0, acc[mt]);
    }
    __syncthreads();
#pragma unroll
    for (int mt = 0; mt < 4; ++mt) {
        int ch = chb + mt * 16 + q * 4;
        float4 bb = *(const float4*)(b2a + ch);
        bf16x4 sk = hs[mt];
        bf16x4 o;
        o[0] = (__bf16)(acc[mt][0] + bb.x + (float)sk[0]);
        o[1] = (__bf16)(acc[mt][1] + bb.y + (float)sk[1]);
        o[2] = (__bf16)(acc[mt][2] + bb.z + (float)sk[2]);
        o[3] = (__bf16)(acc[mt][3] + bb.w + (float)sk[3]);
        skipreg[mt] = o;
        *(bf16x4*)(L + l16 * LSTR + ch) = o;
    }
    __syncthreads();

    // ---- p2: t2 = silu(h2 @ W1b + b1b) -> LDS ----
#pragma unroll
    for (int mt = 0; mt < 4; ++mt) acc[mt] = (f32x4)(0.f);
#pragma unroll
    for (int kt = 0; kt < 4; ++kt) {
        int koff = kt * 32 + q * 8;
        bf16x8 f0 = *(const bf16x8*)(L + l16 * LSTR + koff);
        const __bf16* ap = pw1b + (long)kt * 4096 + mtoff + la;
#pragma unroll
        for (int mt = 0; mt < 4; ++mt)
            acc[mt] = mm(*(const bf16x8*)(ap + mt * 512), f0, acc[mt]);
    }
    __syncthreads();
#pragma unroll
    for (int mt = 0; mt < 4; ++mt) {
        int ch = chb + mt * 16 + q * 4;
        float4 bb = *(const float4*)(b1b + ch);
        bf16x4 o;
        o[0] = (__bf16)silu_f(acc[mt][0] + bb.x);
        o[1] = (__bf16)silu_f(acc[mt][1] + bb.y);
        o[2] = (__bf16)silu_f(acc[mt][2] + bb.z);
        o[3] = (__bf16)silu_f(acc[mt][3] + bb.w);
        *(bf16x4*)(L + l16 * LSTR + ch) = o;
    }
    __syncthreads();

    // ---- p3: x = t2 @ W2b + b2b + h2 + gskip -> global ----
#pragma unroll
    for (int mt = 0; mt < 4; ++mt) acc[mt] = (f32x4)(0.f);
#pragma unroll
    for (int kt = 0; kt < 4; ++kt) {
        int koff = kt * 32 + q * 8;
        bf16x8 f0 = *(const bf16x8*)(L + l16 * LSTR + koff);
        const __bf16* ap = pw2b + (long)kt * 4096 + mtoff + la;
#pragma unroll
        for (int mt = 0; mt < 4; ++mt)
            acc[mt] = mm(*(const bf16x8*)(ap + mt * 512), f0, acc[mt]);
    }
    long node = nb + l16;
#pragma unroll
    for (int mt = 0; mt < 4; ++mt) {
        int ch = chb + mt * 16 + q * 4;
        float4 bb = *(const float4*)(b2b + ch);
        bf16x4 sk = skipreg[mt];
        bf16x4 g = gk[mt];
        bf16x4 o;
        o[0] = (__bf16)(acc[mt][0] + bb.x + (float)sk[0] + (float)g[0]);
        o[1] = (__bf16)(acc[mt][1] + bb.y + (float)sk[1] + (float)g[1]);
        o[2] = (__bf16)(acc[mt][2] + bb.z + (float)sk[2] + (float)g[2]);
        o[3] = (__bf16)(acc[mt][3] + bb.w + (float)sk[3] + (float)g[3]);
        *(bf16x4*)(xout + node * 128 + ch) = o;
    }
}

// ---------------------------------------------------------------- K4: attention scores
__global__ __launch_bounds__(256) void k_scores(
    const __bf16* __restrict__ x, const float* __restrict__ aw,
    const float* __restrict__ ab, const float* __restrict__ temp,
    float* __restrict__ scores)
{
    int wave = threadIdx.x >> 6, lane = threadIdx.x & 63;
    int n = blockIdx.x * 4 + wave;
    if (n >= NN) return;
    float x0 = (float)x[(long)n * H + lane];
    float x1 = (float)x[(long)n * H + 64 + lane];
    float T = temp[0];
#pragma unroll
    for (int hh = 0; hh < NHEADS; ++hh) {
        float p = x0 * aw[hh * H + lane] + x1 * aw[hh * H + 64 + lane];
#pragma unroll
        for (int off = 32; off >= 1; off >>= 1) p += __shfl_xor(p, off, 64);
        if (lane == 0) scores[n * NHEADS + hh] = (p + ab[hh]) / T;
    }
}

// ---------------------------------------------------------------- K5: graph offsets
__global__ __launch_bounds__(256) void k_offsets(
    const int* __restrict__ batch, int* __restrict__ gstart)
{
    int n = blockIdx.x * 256 + threadIdx.x;
    if (n >= NN) return;
    int b = batch[n];
    int bp = (n == 0) ? -1 : batch[n - 1];
    for (int g = bp + 1; g <= b; ++g) gstart[g] = n;
    if (n == NN - 1) for (int g = b + 1; g <= NG; ++g) gstart[g] = NN;
}

// ---------------------------------------------------------------- K6: softmax pool
__global__ __launch_bounds__(64) void k_pool(
    const __bf16* __restrict__ x, const float* __restrict__ scores,
    const int* __restrict__ gstart, float* __restrict__ pooled)
{
    int g = blockIdx.x, lane = threadIdx.x;
    int s0 = gstart[g], s1 = gstart[g + 1];
    float m0 = -INFINITY, m1 = -INFINITY, m2 = -INFINITY, m3 = -INFINITY;
    for (int n = s0 + lane; n < s1; n += 64) {
        m0 = fmaxf(m0, scores[n * 4 + 0]); m1 = fmaxf(m1, scores[n * 4 + 1]);
        m2 = fmaxf(m2, scores[n * 4 + 2]); m3 = fmaxf(m3, scores[n * 4 + 3]);
    }
#pragma unroll
    for (int off = 32; off >= 1; off >>= 1) {
        m0 = fmaxf(m0, __shfl_xor(m0, off, 64)); m1 = fmaxf(m1, __shfl_xor(m1, off, 64));
        m2 = fmaxf(m2, __shfl_xor(m2, off, 64)); m3 = fmaxf(m3, __shfl_xor(m3, off, 64));
    }
    float d0 = 0.f, d1 = 0.f, d2 = 0.f, d3 = 0.f;
    for (int n = s0 + lane; n < s1; n += 64) {
        d0 += expf(scores[n * 4 + 0] - m0); d1 += expf(scores[n * 4 + 1] - m1);
        d2 += expf(scores[n * 4 + 2] - m2); d3 += expf(scores[n * 4 + 3] - m3);
    }
#pragma unroll
    for (int off = 32; off >= 1; off >>= 1) {
        d0 += __shfl_xor(d0, off, 64); d1 += __shfl_xor(d1, off, 64);
        d2 += __shfl_xor(d2, off, 64); d3 += __shfl_xor(d3, off, 64);
    }
    float i0 = d0 > 0.f ? 1.f / d0 : 0.f;
    float i1 = d1 > 0.f ? 1.f / d1 : 0.f;
    float i2 = d2 > 0.f ? 1.f / d2 : 0.f;
    float i3 = d3 > 0.f ? 1.f / d3 : 0.f;
    float a0 = 0.f, a1 = 0.f;
    for (int n = s0; n < s1; ++n) {
        float wb = expf(scores[n * 4 + 0] - m0) * i0 + expf(scores[n * 4 + 1] - m1) * i1
                 + expf(scores[n * 4 + 2] - m2) * i2 + expf(scores[n * 4 + 3] - m3) * i3;
        wb *= 0.25f;
        a0 += wb * (float)x[(long)n * H + lane];
        a1 += wb * (float)x[(long)n * H + 64 + lane];
    }
    pooled[g * H + lane] = a0;
    pooled[g * H + 64 + lane] = a1;
}

// ---------------------------------------------------------------- K7: FFN readout
__global__ __launch_bounds__(128) void k_ffn(
    const float* __restrict__ pooled,
    const float* __restrict__ W1, const float* __restrict__ B1,
    const float* __restrict__ W2, const float* __restrict__ B2,
    const float* __restrict__ W3, const float* __restrict__ B3,
    float* __restrict__ out)
{
    __shared__ float p[H], t1[H], t2[H], red[H];
    int g = blockIdx.x, c = threadIdx.x;
    p[c] = pooled[g * H + c];
    __syncthreads();
    float acc = 0.f;
    for (int k = 0; k < H; ++k) acc += p[k] * W1[k * H + c];
    t1[c] = silu_f(acc + B1[c]);
    __syncthreads();
    acc = 0.f;
    for (int k = 0; k < H; ++k) acc += t1[k] * W2[k * H + c];
    t2[c] = silu_f(acc + B2[c]);
    __syncthreads();
    red[c] = t2[c] * W3[c];
    __syncthreads();
    for (int off = 64; off >= 1; off >>= 1) {
        if (c < off) red[c] += red[c + off];
        __syncthreads();
    }
    if (c == 0) out[g] = red[0] + B3[0];
}

// ---------------------------------------------------------------- launch
extern "C" void kernel_launch(void* const* d_in, const int* in_sizes, int n_in,
                              void* d_out, int out_size, void* d_ws, size_t ws_size,
                              hipStream_t stream)
{
    const int*   atom   = (const int*)d_in[0];
    const int*   hc     = (const int*)d_in[1];
    const int*   deg    = (const int*)d_in[2];
    const int*   hyb    = (const int*)d_in[3];
    const int*   target = (const int*)d_in[4];
    const int*   src    = (const int*)d_in[5];
    const int*   batch  = (const int*)d_in[6];
    const float* Ea     = (const float*)d_in[7];
    const float* Eh     = (const float*)d_in[8];
    const float* Ed     = (const float*)d_in[9];
    const float* Ey     = (const float*)d_in[10];
    const float* projW  = (const float*)d_in[11];
    const float* projB  = (const float*)d_in[12];
    const float* sInW   = (const float*)d_in[13];
    const float* sInB   = (const float*)d_in[14];
    const float* mW1    = (const float*)d_in[15];
    const float* mB1    = (const float*)d_in[16];
    const float* mW2    = (const float*)d_in[17];
    const float* mB2    = (const float*)d_in[18];
    const float* sSkW   = (const float*)d_in[19];
    const float* sSkB   = (const float*)d_in[20];
    const float* attnW  = (const float*)d_in[21];
    const float* attnB  = (const float*)d_in[22];
    const float* temp   = (const float*)d_in[23];
    const float* fW1    = (const float*)d_in[24];
    const float* fB1    = (const float*)d_in[25];
    const float* fW2    = (const float*)d_in[26];
    const float* fB2    = (const float*)d_in[27];
    const float* fW3    = (const float*)d_in[28];
    const float* fB3    = (const float*)d_in[29];
    float* out = (float*)d_out;

    char* w = (char*)d_ws;
    auto take = [&](size_t bytes) { void* p = (void*)w; w += (bytes + 255) & ~(size_t)255; return p; };
    __bf16* x      = (__bf16*)take(2L * NNP * H);
    __bf16* agg    = (__bf16*)take(2L * 3 * NNP * H);
    __bf16* pproj  = (__bf16*)take(2L * 256 * H);
    __bf16* pin    = (__bf16*)take(2L * 3 * 512 * H);
    __bf16* psk    = (__bf16*)take(2L * 3 * 512 * H);
    __bf16* pw1    = (__bf16*)take(2L * 6 * 128 * H);
    __bf16* pw2    = (__bf16*)take(2L * 6 * 128 * H);
    __bf16* embb   = (__bf16*)take(2L * 8000);
    float*  scores = (float*)take(4L * NN * NHEADS);
    float*  pooled = (float*)take(4L * NG * H);
    int*    gstart = (int*)take(4L * (NG + 1));
    int*    csr_start = (int*)take(4L * (NROWS + 1));
    unsigned int*   binreg = (unsigned int*)take(4L * NBIN * CAPB);   // 12 MB
    unsigned short* esrc   = (unsigned short*)take(2L * NE);
    // gbincur + brealc in ONE contiguous allocation (one memset covers both)
    int*    gbincur = (int*)take(4L * 2 * NBIN);
    int*    brealc  = gbincur + NBIN;

    // ---- fused weight pack + emb convert (weights restored each call) ----
    k_packall<<<(630592 + 255) / 256, 256, 0, stream>>>(
        projW, pproj, sInW, pin, sSkW, psk, mW1, pw1, mW2, pw2,
        Ea, Eh, Ed, Ey, embb);

    // ---- CSR build: write-combined binning -> per-bin finalize ----
    hipMemsetAsync(gbincur, 0, sizeof(int) * 2 * NBIN, stream);
    k_binA<<<ABLK, 256, 0, stream>>>(target, src, gbincur, brealc, binreg);
    k_fill2b<<<NBIN, 512, 0, stream>>>(binreg, gbincur, brealc, csr_start, esrc);

    k_embed_m<<<NNP / 128, 256, 0, stream>>>(atom, hc, deg, hyb, embb, pproj, projB, x);
    k_offsets<<<(NN + 255) / 256, 256, 0, stream>>>(batch, gstart);

    for (int l = 0; l < NL; ++l) {
        k_gather<<<NROWS / 16, 256, 0, stream>>>(esrc, csr_start,
            (const uint4*)x, (uint4*)agg);
        k_layer<<<NNP / 32, 256, 0, stream>>>(x, agg,
            pin + (long)l * 512 * H, sInB + l * H,
            psk + (long)l * 512 * H, sSkB + l * H,
            pw1 + (long)(l * NMLP + 0) * 128 * H, mB1 + (long)(l * NMLP + 0) * H,
            pw2 + (long)(l * NMLP + 0) * 128 * H, mB2 + (long)(l * NMLP + 0) * H,
            pw1 + (long)(l * NMLP + 1) * 128 * H, mB1 + (long)(l * NMLP + 1) * H,
            pw2 + (long)(l * NMLP + 1) * 128 * H, mB2 + (long)(l * NMLP + 1) * H,
            x);
    }

    k_scores<<<NN / 4, 256, 0, stream>>>(x, attnW, attnB, temp, scores);
    k_pool<<<NG, 64, 0, stream>>>(x, scores, gstart, pooled);
    k_ffn<<<NG, 128, 0, stream>>>(pooled, fW1, fB1, fW2, fB2, fW3, fB3, out);
}

// Round 12
// 658.048 us; speedup vs baseline: 20.6327x; 1.0589x over previous
//
#include <hip/hip_runtime.h>
#include <math.h>

#define NN      50000
#define NNP     50048          // padded nodes = 391*128
#define NE      2400000
#define NHOPS   3
#define NG      2048
#define H       128
#define EMBD    64
#define NL      3
#define NMLP    2
#define NHEADS  4
#define NROWS   (NHOPS * NN)   // 150000
#define BINSH   9              // 512 rows per coarse bin
#define NBIN    293            // ceil(150016/512)
#define CAPB    12288          // per-bin region capacity (mean ~9.7k incl pad)
#define ABLK    1024           // binning blocks: 4/CU by LDS
#define DEPTH   32             // LDS circular buffer depth per bin
#define STG     6144           // fill2b per-half stage capacity (mean ~4096)
#define LSTR    136
#define SENT    0xFFFFFFFFu

typedef __bf16 bf16x8 __attribute__((ext_vector_type(8)));
typedef __bf16 bf16x4 __attribute__((ext_vector_type(4)));
typedef float  f32x4  __attribute__((ext_vector_type(4)));

__device__ __forceinline__ float silu_f(float v) { return v / (1.0f + expf(-v)); }

__device__ __forceinline__ f32x4 mm(bf16x8 a, bf16x8 b, f32x4 c) {
    return __builtin_amdgcn_mfma_f32_16x16x32_bf16(a, b, c, 0, 0, 0);
}

__device__ __forceinline__ float blo(unsigned v) { return __builtin_bit_cast(float, v << 16); }
__device__ __forceinline__ float bhi(unsigned v) { return __builtin_bit_cast(float, v & 0xffff0000u); }
__device__ __forceinline__ unsigned pk2(float a, float b) {
    unsigned short ua = __builtin_bit_cast(unsigned short, (__bf16)a);
    unsigned short ub = __builtin_bit_cast(unsigned short, (__bf16)b);
    return (unsigned)ua | ((unsigned)ub << 16);
}

// ---------------------------------------------------------------- fused weight pack + emb convert
__device__ __forceinline__ void packw_elem(
    const float* __restrict__ W, __bf16* __restrict__ out, int K, long idx)
{
    long per = (long)K * 128;
    long mat = idx / per, e = idx - mat * per;
    int j = (int)(e & 7), n16 = (int)((e >> 3) & 15), q = (int)((e >> 7) & 3),
        mt = (int)((e >> 9) & 7), kt = (int)(e >> 12);
    int k = kt * 32 + q * 8 + j, n = mt * 16 + n16;
    out[idx] = (__bf16)W[mat * per + (long)k * 128 + n];
}

__global__ __launch_bounds__(256) void k_packall(
    const float* __restrict__ projW, __bf16* __restrict__ pproj,
    const float* __restrict__ sInW,  __bf16* __restrict__ pin,
    const float* __restrict__ sSkW,  __bf16* __restrict__ psk,
    const float* __restrict__ mW1,   __bf16* __restrict__ pw1,
    const float* __restrict__ mW2,   __bf16* __restrict__ pw2,
    const float* __restrict__ Ea, const float* __restrict__ Eh,
    const float* __restrict__ Ed, const float* __restrict__ Ey,
    __bf16* __restrict__ embb)
{
    long tid = (long)blockIdx.x * 256 + threadIdx.x;
    if (tid < 32768) { packw_elem(projW, pproj, 256, tid); return; }
    tid -= 32768;
    if (tid < 196608) { packw_elem(sInW, pin, 512, tid); return; }
    tid -= 196608;
    if (tid < 196608) { packw_elem(sSkW, psk, 512, tid); return; }
    tid -= 196608;
    if (tid < 98304) { packw_elem(mW1, pw1, 128, tid); return; }
    tid -= 98304;
    if (tid < 98304) { packw_elem(mW2, pw2, 128, tid); return; }
    tid -= 98304;
    if (tid < 8000) {
        int t = (int)tid;
        float v;
        if (t < 6400) v = Ea[t];
        else if (t < 6976) v = Eh[t - 6400];
        else if (t < 7488) v = Ed[t - 6976];
        else v = Ey[t - 7488];
        embb[t] = (__bf16)v;
    }
}

// ---------------------------------------------------------------- K0: embed + project + silu (MFMA)
__global__ __launch_bounds__(256) void k_embed_m(
    const int* __restrict__ atom, const int* __restrict__ hc,
    const int* __restrict__ deg,  const int* __restrict__ hyb,
    const __bf16* __restrict__ emb, const __bf16* __restrict__ pw,
    const float* __restrict__ pb, __bf16* __restrict__ x)
{
    const int lane = threadIdx.x & 63, wid = threadIdx.x >> 6;
    const int q = lane >> 4, l16 = lane & 15;
    const int nb = blockIdx.x * 128 + wid * 32;
    int ia[2][4];
#pragma unroll
    for (int nt = 0; nt < 2; ++nt) {
        int n = nb + nt * 16 + l16;
        if (n >= NN) n = NN - 1;
        ia[nt][0] = atom[n]; ia[nt][1] = hc[n]; ia[nt][2] = deg[n]; ia[nt][3] = hyb[n];
    }
    f32x4 acc[2][8];
#pragma unroll
    for (int nt = 0; nt < 2; ++nt)
#pragma unroll
        for (int mt = 0; mt < 8; ++mt) acc[nt][mt] = (f32x4)(0.f);
    const int tb[4] = {0, 6400, 6976, 7488};
    for (int kt = 0; kt < 8; ++kt) {
        int t = kt >> 1;
        int koff = (kt & 1) * 32 + q * 8;
        bf16x8 bfrag[2];
#pragma unroll
        for (int nt = 0; nt < 2; ++nt)
            bfrag[nt] = *(const bf16x8*)(emb + tb[t] + (long)ia[nt][t] * 64 + koff);
        const __bf16* ap = pw + (long)kt * 4096 + lane * 8;
#pragma unroll
        for (int mt = 0; mt < 8; ++mt) {
            bf16x8 a = *(const bf16x8*)(ap + mt * 512);
            acc[0][mt] = mm(a, bfrag[0], acc[0][mt]);
            acc[1][mt] = mm(a, bfrag[1], acc[1][mt]);
        }
    }
#pragma unroll
    for (int nt = 0; nt < 2; ++nt) {
        long node = nb + nt * 16 + l16;
#pragma unroll
        for (int mt = 0; mt < 8; ++mt) {
            int ch = mt * 16 + q * 4;
            float4 bb = *(const float4*)(pb + ch);
            bf16x4 o;
            o[0] = (__bf16)silu_f(acc[nt][mt][0] + bb.x);
            o[1] = (__bf16)silu_f(acc[nt][mt][1] + bb.y);
            o[2] = (__bf16)silu_f(acc[nt][mt][2] + bb.z);
            o[3] = (__bf16)silu_f(acc[nt][mt][3] + bb.w);
            *(bf16x4*)(x + node * 128 + ch) = o;
        }
    }
}

// ---------------------------------------------------------------- CSR pass A: LDS write-combined binning
__global__ __launch_bounds__(256) void k_binA(
    const int* __restrict__ target, const int* __restrict__ src,
    int* __restrict__ gbincur, int* __restrict__ brealc,
    unsigned int* __restrict__ binreg)
{
    __shared__ unsigned int buf[NBIN][DEPTH];
    __shared__ int cnt[NBIN];
    __shared__ int flushed[NBIN];
    const int tid = threadIdx.x;
    for (int i = tid; i < NBIN; i += 256) { cnt[i] = 0; flushed[i] = 0; }
    __syncthreads();
    const int per = (NE + ABLK - 1) / ABLK;   // 2344
    const int e0 = blockIdx.x * per;
    const int e1 = (e0 + per < NE) ? e0 + per : NE;
    for (int base = e0; base < e1; base += 256) {
        int e = base + tid;
        if (e < e1) {
            int s = src[e];
            if (s >= 2 * NN) s -= 2 * NN; else if (s >= NN) s -= NN;
            int t = target[e];
            int bin = t >> BINSH;
            unsigned val = (unsigned)s | ((unsigned)(t & ((1 << BINSH) - 1)) << 16);
            int slot = atomicAdd(&cnt[bin], 1);
            buf[bin][slot & (DEPTH - 1)] = val;
        }
        __syncthreads();
        for (int b = tid; b < NBIN; b += 256) {
            while (cnt[b] - flushed[b] >= 16) {
                int pos = atomicAdd(&gbincur[b], 16);
                if (pos + 16 <= CAPB) {
                    uint4* d4 = (uint4*)(binreg + (long)b * CAPB + pos);
                    const uint4* s4 = (const uint4*)&buf[b][flushed[b] & (DEPTH - 1)];
                    d4[0] = s4[0]; d4[1] = s4[1]; d4[2] = s4[2]; d4[3] = s4[3];
                }
                flushed[b] += 16;
            }
        }
        __syncthreads();
    }
    for (int b = tid; b < NBIN; b += 256) {
        int lvl = cnt[b] - flushed[b];
        if (cnt[b] > 0) atomicAdd(&brealc[b], cnt[b]);
        if (lvl > 0) {
            int pad = (lvl + 3) & ~3;
            int pos = atomicAdd(&gbincur[b], pad);
            for (int i = 0; i < pad; i += 4) {
                uint4 v;
                v.x = (i + 0 < lvl) ? buf[b][(flushed[b] + i + 0) & (DEPTH - 1)] : SENT;
                v.y = (i + 1 < lvl) ? buf[b][(flushed[b] + i + 1) & (DEPTH - 1)] : SENT;
                v.z = (i + 2 < lvl) ? buf[b][(flushed[b] + i + 2) & (DEPTH - 1)] : SENT;
                v.w = (i + 3 < lvl) ? buf[b][(flushed[b] + i + 3) & (DEPTH - 1)] : SENT;
                if (pos + i + 4 <= CAPB)
                    *(uint4*)(binreg + (long)b * CAPB + pos + i) = v;
            }
        }
    }
}

// ---------------------------------------------------------------- CSR pass B: per-HALF-bin LDS finalize
// 2 blocks per bin; each filter-stages its 256-row half. half1 base derives
// from breal - own (no extra scan).
__global__ __launch_bounds__(512) void k_fill2b(
    const unsigned int* __restrict__ binreg, const int* __restrict__ gbincur,
    const int* __restrict__ brealc, int* __restrict__ csr_start,
    unsigned short* __restrict__ esrc)
{
    __shared__ unsigned int stage[STG];
    __shared__ int pc[512], rcnt[256], scn[256], cur[256];
    __shared__ int nstage;
    const int blk = blockIdx.x;
    const int b = blk >> 1, half = blk & 1;
    const int tid = threadIdx.x;
    int pv = (tid < NBIN) ? brealc[tid] : 0;
    if (pv < 0) pv = 0;
    pc[tid] = pv;
    if (tid == 0) nstage = 0;
    if (tid < 256) rcnt[tid] = 0;
    __syncthreads();
    for (int off = 1; off < 512; off <<= 1) {
        int t = (tid >= off) ? pc[tid - off] : 0;
        __syncthreads();
        pc[tid] += t;
        __syncthreads();
    }
    const int bbase = (b == 0) ? 0 : pc[b - 1];
    const int breal = pc[b] - bbase;
    int total = gbincur[b];
    if (total > CAPB) total = CAPB;
    if (total < 0) total = 0;
    const unsigned int* seg = binreg + (long)b * CAPB;
    for (int i = tid; i < total; i += 512) {
        unsigned pk = seg[i];
        if (pk == SENT) continue;
        int tl = (pk >> 16) & 511;
        if ((tl >> 8) == half) {
            int p = atomicAdd(&nstage, 1);
            if (p < STG) stage[p] = pk;
            atomicAdd(&rcnt[tl & 255], 1);
        }
    }
    __syncthreads();
    int own = nstage; if (own > STG) own = STG;
    const int base0 = bbase + (half ? (breal - own) : 0);
    if (tid < 256) scn[tid] = rcnt[tid];
    __syncthreads();
    for (int off = 1; off < 256; off <<= 1) {
        int t = (tid >= off && tid < 256) ? scn[tid - off] : 0;
        __syncthreads();
        if (tid < 256) scn[tid] += t;
        __syncthreads();
    }
    if (tid < 256) {
        int v = rcnt[tid];
        int rb = base0 + scn[tid] - v;
        cur[tid] = rb;
        int row = b * 512 + half * 256 + tid;
        if (row <= NROWS) csr_start[row] = rb;
    }
    __syncthreads();
    for (int i = tid; i < own; i += 512) {
        unsigned pk = stage[i];
        int pos = atomicAdd(&cur[(pk >> 16) & 255], 1);
        if (pos >= 0 && pos < NE) esrc[pos] = (unsigned short)(pk & 0xffffu);
    }
}

// ---------------------------------------------------------------- K1: CSR gather, 4 rows/wave, uint4 loads
__global__ __launch_bounds__(256) void k_gather(
    const unsigned short* __restrict__ esrc, const int* __restrict__ csr_start,
    const uint4* __restrict__ x8, uint4* __restrict__ agg8)
{
    int row = blockIdx.x * 16 + (threadIdx.x >> 4);
    int lane = threadIdx.x & 63;
    int l4 = lane & 15, qw = lane >> 4;
    int e0 = csr_start[row], e1 = csr_start[row + 1];
    if ((unsigned)e0 > NE || (unsigned)e1 > NE || e1 < e0) { e0 = 0; e1 = 0; }
    int nch = (e1 - e0 + 15) >> 4;
    int n0 = __shfl(nch, 0, 64), n1 = __shfl(nch, 16, 64);
    int n2 = __shfl(nch, 32, 64), n3 = __shfl(nch, 48, 64);
    int nmax = max(max(n0, n1), max(n2, n3));
    float a0 = 0.f, a1 = 0.f, a2 = 0.f, a3 = 0.f, a4 = 0.f, a5 = 0.f, a6 = 0.f, a7 = 0.f;
    const int sb = qw << 4;
    for (int c = 0; c < nmax; ++c) {
        int base = e0 + c * 16;
        int rem = e1 - base;
        int pre = (l4 < rem) ? (int)esrc[base + l4] : 0;
        int m = rem < 16 ? (rem < 0 ? 0 : rem) : 16;
        int j = 0;
        for (; j + 3 < m; j += 4) {
            int sA = __shfl(pre, sb + j, 64);
            int sB = __shfl(pre, sb + j + 1, 64);
            int sC = __shfl(pre, sb + j + 2, 64);
            int sD = __shfl(pre, sb + j + 3, 64);
            uint4 v0 = x8[(long)sA * 16 + l4];
            uint4 v1 = x8[(long)sB * 16 + l4];
            uint4 v2 = x8[(long)sC * 16 + l4];
            uint4 v3 = x8[(long)sD * 16 + l4];
            a0 += blo(v0.x) + blo(v1.x) + blo(v2.x) + blo(v3.x);
            a1 += bhi(v0.x) + bhi(v1.x) + bhi(v2.x) + bhi(v3.x);
            a2 += blo(v0.y) + blo(v1.y) + blo(v2.y) + blo(v3.y);
            a3 += bhi(v0.y) + bhi(v1.y) + bhi(v2.y) + bhi(v3.y);
            a4 += blo(v0.z) + blo(v1.z) + blo(v2.z) + blo(v3.z);
            a5 += bhi(v0.z) + bhi(v1.z) + bhi(v2.z) + bhi(v3.z);
            a6 += blo(v0.w) + blo(v1.w) + blo(v2.w) + blo(v3.w);
            a7 += bhi(v0.w) + bhi(v1.w) + bhi(v2.w) + bhi(v3.w);
        }
        for (; j < m; ++j) {
            int sA = __shfl(pre, sb + j, 64);
            uint4 v0 = x8[(long)sA * 16 + l4];
            a0 += blo(v0.x); a1 += bhi(v0.x); a2 += blo(v0.y); a3 += bhi(v0.y);
            a4 += blo(v0.z); a5 += bhi(v0.z); a6 += blo(v0.w); a7 += bhi(v0.w);
        }
    }
    int hop = row / NN, node = row - hop * NN;
    uint4 o;
    o.x = pk2(a0, a1); o.y = pk2(a2, a3); o.z = pk2(a4, a5); o.w = pk2(a6, a7);
    agg8[((long)hop * NNP + node) * 16 + l4] = o;
}

// ---------------------------------------------------------------- K2: FUSED layer, channel-split, 128-thread blocks
// One wave pair per block (16 nodes, 64 ch/wave). 3128 blocks; VGPR~64 allows
// up to 8 waves/SIMD -> ~2x R10 residency.
__global__ __launch_bounds__(128) void k_layer(
    const __bf16* __restrict__ x, const __bf16* __restrict__ agg,
    const __bf16* __restrict__ pwin, const float* __restrict__ bin,
    const __bf16* __restrict__ pwsk, const float* __restrict__ bsk,
    const __bf16* __restrict__ pw1a, const float* __restrict__ b1a,
    const __bf16* __restrict__ pw2a, const float* __restrict__ b2a,
    const __bf16* __restrict__ pw1b, const float* __restrict__ b1b,
    const __bf16* __restrict__ pw2b, const float* __restrict__ b2b,
    __bf16* __restrict__ xout)
{
    __shared__ __bf16 L[16 * LSTR];
    const int lane = threadIdx.x & 63, half = threadIdx.x >> 6;
    const int q = lane >> 4, l16 = lane & 15;
    const int nb = blockIdx.x * 16;
    const int mtoff = half * 4 * 512;
    const int chb = half * 64;
    const int la = lane * 8;
    const long r0 = (long)(nb + l16) * 128;
    const __bf16* planes[4] = {x, agg, agg + (long)NNP * 128, agg + 2L * NNP * 128};

    // ---- shell phase: K=512, B-ring depth 8 ----
    bf16x8 ring[8];
#pragma unroll
    for (int k = 0; k < 8; ++k)
        ring[k] = *(const bf16x8*)(planes[k >> 2] + (k & 3) * 32 + q * 8 + r0);
    f32x4 aci[4], acs[4];
#pragma unroll
    for (int mt = 0; mt < 4; ++mt) { aci[mt] = (f32x4)(0.f); acs[mt] = (f32x4)(0.f); }
#pragma unroll
    for (int kt = 0; kt < 16; ++kt) {
        bf16x8 b0 = ring[kt & 7];
        if (kt < 8) {
            int k2 = kt + 8;
            ring[kt & 7] = *(const bf16x8*)(planes[k2 >> 2] + (k2 & 3) * 32 + q * 8 + r0);
        }
        const __bf16* aip = pwin + (long)kt * 4096 + mtoff + la;
        const __bf16* asp = pwsk + (long)kt * 4096 + mtoff + la;
#pragma unroll
        for (int mt = 0; mt < 4; ++mt) {
            aci[mt] = mm(*(const bf16x8*)(aip + mt * 512), b0, aci[mt]);
            acs[mt] = mm(*(const bf16x8*)(asp + mt * 512), b0, acs[mt]);
        }
    }
    bf16x4 gk[4];
    bf16x4 hs[4];
#pragma unroll
    for (int mt = 0; mt < 4; ++mt) {
        int ch = chb + mt * 16 + q * 4;
        float4 bi = *(const float4*)(bin + ch);
        float4 bs = *(const float4*)(bsk + ch);
        bf16x4 oh, og;
        oh[0] = (__bf16)silu_f(aci[mt][0] + bi.x);
        oh[1] = (__bf16)silu_f(aci[mt][1] + bi.y);
        oh[2] = (__bf16)silu_f(aci[mt][2] + bi.z);
        oh[3] = (__bf16)silu_f(aci[mt][3] + bi.w);
        og[0] = (__bf16)(acs[mt][0] + bs.x);
        og[1] = (__bf16)(acs[mt][1] + bs.y);
        og[2] = (__bf16)(acs[mt][2] + bs.z);
        og[3] = (__bf16)(acs[mt][3] + bs.w);
        hs[mt] = oh; gk[mt] = og;
        *(bf16x4*)(L + l16 * LSTR + ch) = oh;
    }
    __syncthreads();

    f32x4 acc[4];
    bf16x4 skipreg[4];

    // ---- p0: t1 = silu(h @ W1a + b1a) -> LDS ----
#pragma unroll
    for (int mt = 0; mt < 4; ++mt) acc[mt] = (f32x4)(0.f);
#pragma unroll
    for (int kt = 0; kt < 4; ++kt) {
        int koff = kt * 32 + q * 8;
        bf16x8 f0 = *(const bf16x8*)(L + l16 * LSTR + koff);
        const __bf16* ap = pw1a + (long)kt * 4096 + mtoff + la;
#pragma unroll
        for (int mt = 0; mt < 4; ++mt)
            acc[mt] = mm(*(const bf16x8*)(ap + mt * 512), f0, acc[mt]);
    }
    __syncthreads();
#pragma unroll
    for (int mt = 0; mt < 4; ++mt) {
        int ch = chb + mt * 16 + q * 4;
        float4 bb = *(const float4*)(b1a + ch);
        bf16x4 o;
        o[0] = (__bf16)silu_f(acc[mt][0] + bb.x);
        o[1] = (__bf16)silu_f(acc[mt][1] + bb.y);
        o[2] = (__bf16)silu_f(acc[mt][2] + bb.z);
        o[3] = (__bf16)silu_f(acc[mt][3] + bb.w);
        *(bf16x4*)(L + l16 * LSTR + ch) = o;
    }
    __syncthreads();

    // ---- p1: h2 = t1 @ W2a + b2a + h -> LDS + skipreg ----
#pragma unroll
    for (int mt = 0; mt < 4; ++mt) acc[mt] = (f32x4)(0.f);
#pragma unroll
    for (int kt = 0; kt < 4; ++kt) {
        int koff = kt * 32 + q * 8;
        bf16x8 f0 = *(const bf16x8*)(L + l16 * LSTR + koff);
        const __bf16* ap = pw2a + (long)kt * 4096 + mtoff + la;
#pragma unroll
        for (int mt = 0; mt < 4; ++mt)
            acc[mt] = mm(*(const bf16x8*)(ap + mt * 512), f0, acc[mt]);
    }
    __syncthreads();
#pragma unroll
    for (int mt = 0; mt < 4; ++mt) {
        int ch = chb + mt * 16 + q * 4;
        float4 bb = *(const float4*)(b2a + ch);
        bf16x4 sk = hs[mt];
        bf16x4 o;
        o[0] = (__bf16)(acc[mt][0] + bb.x + (float)sk[0]);
        o[1] = (__bf16)(acc[mt][1] + bb.y + (float)sk[1]);
        o[2] = (__bf16)(acc[mt][2] + bb.z + (float)sk[2]);
        o[3] = (__bf16)(acc[mt][3] + bb.w + (float)sk[3]);
        skipreg[mt] = o;
        *(bf16x4*)(L + l16 * LSTR + ch) = o;
    }
    __syncthreads();

    // ---- p2: t2 = silu(h2 @ W1b + b1b) -> LDS ----
#pragma unroll
    for (int mt = 0; mt < 4; ++mt) acc[mt] = (f32x4)(0.f);
#pragma unroll
    for (int kt = 0; kt < 4; ++kt) {
        int koff = kt * 32 + q * 8;
        bf16x8 f0 = *(const bf16x8*)(L + l16 * LSTR + koff);
        const __bf16* ap = pw1b + (long)kt * 4096 + mtoff + la;
#pragma unroll
        for (int mt = 0; mt < 4; ++mt)
            acc[mt] = mm(*(const bf16x8*)(ap + mt * 512), f0, acc[mt]);
    }
    __syncthreads();
#pragma unroll
    for (int mt = 0; mt < 4; ++mt) {
        int ch = chb + mt * 16 + q * 4;
        float4 bb = *(const float4*)(b1b + ch);
        bf16x4 o;
        o[0] = (__bf16)silu_f(acc[mt][0] + bb.x);
        o[1] = (__bf16)silu_f(acc[mt][1] + bb.y);
        o[2] = (__bf16)silu_f(acc[mt][2] + bb.z);
        o[3] = (__bf16)silu_f(acc[mt][3] + bb.w);
        *(bf16x4*)(L + l16 * LSTR + ch) = o;
    }
    __syncthreads();

    // ---- p3: x = t2 @ W2b + b2b + h2 + gskip -> global ----
#pragma unroll
    for (int mt = 0; mt < 4; ++mt) acc[mt] = (f32x4)(0.f);
#pragma unroll
    for (int kt = 0; kt < 4; ++kt) {
        int koff = kt * 32 + q * 8;
        bf16x8 f0 = *(const bf16x8*)(L + l16 * LSTR + koff);
        const __bf16* ap = pw2b + (long)kt * 4096 + mtoff + la;
#pragma unroll
        for (int mt = 0; mt < 4; ++mt)
            acc[mt] = mm(*(const bf16x8*)(ap + mt * 512), f0, acc[mt]);
    }
    long node = nb + l16;
#pragma unroll
    for (int mt = 0; mt < 4; ++mt) {
        int ch = chb + mt * 16 + q * 4;
        float4 bb = *(const float4*)(b2b + ch);
        bf16x4 sk = skipreg[mt];
        bf16x4 g = gk[mt];
        bf16x4 o;
        o[0] = (__bf16)(acc[mt][0] + bb.x + (float)sk[0] + (float)g[0]);
        o[1] = (__bf16)(acc[mt][1] + bb.y + (float)sk[1] + (float)g[1]);
        o[2] = (__bf16)(acc[mt][2] + bb.z + (float)sk[2] + (float)g[2]);
        o[3] = (__bf16)(acc[mt][3] + bb.w + (float)sk[3] + (float)g[3]);
        *(bf16x4*)(xout + node * 128 + ch) = o;
    }
}

// ---------------------------------------------------------------- K4: attention scores
__global__ __launch_bounds__(256) void k_scores(
    const __bf16* __restrict__ x, const float* __restrict__ aw,
    const float* __restrict__ ab, const float* __restrict__ temp,
    float* __restrict__ scores)
{
    int wave = threadIdx.x >> 6, lane = threadIdx.x & 63;
    int n = blockIdx.x * 4 + wave;
    if (n >= NN) return;
    float x0 = (float)x[(long)n * H + lane];
    float x1 = (float)x[(long)n * H + 64 + lane];
    float T = temp[0];
#pragma unroll
    for (int hh = 0; hh < NHEADS; ++hh) {
        float p = x0 * aw[hh * H + lane] + x1 * aw[hh * H + 64 + lane];
#pragma unroll
        for (int off = 32; off >= 1; off >>= 1) p += __shfl_xor(p, off, 64);
        if (lane == 0) scores[n * NHEADS + hh] = (p + ab[hh]) / T;
    }
}

// ---------------------------------------------------------------- K5: graph offsets
__global__ __launch_bounds__(256) void k_offsets(
    const int* __restrict__ batch, int* __restrict__ gstart)
{
    int n = blockIdx.x * 256 + threadIdx.x;
    if (n >= NN) return;
    int b = batch[n];
    int bp = (n == 0) ? -1 : batch[n - 1];
    for (int g = bp + 1; g <= b; ++g) gstart[g] = n;
    if (n == NN - 1) for (int g = b + 1; g <= NG; ++g) gstart[g] = NN;
}

// ---------------------------------------------------------------- K6: softmax pool
__global__ __launch_bounds__(64) void k_pool(
    const __bf16* __restrict__ x, const float* __restrict__ scores,
    const int* __restrict__ gstart, float* __restrict__ pooled)
{
    int g = blockIdx.x, lane = threadIdx.x;
    int s0 = gstart[g], s1 = gstart[g + 1];
    float m0 = -INFINITY, m1 = -INFINITY, m2 = -INFINITY, m3 = -INFINITY;
    for (int n = s0 + lane; n < s1; n += 64) {
        m0 = fmaxf(m0, scores[n * 4 + 0]); m1 = fmaxf(m1, scores[n * 4 + 1]);
        m2 = fmaxf(m2, scores[n * 4 + 2]); m3 = fmaxf(m3, scores[n * 4 + 3]);
    }
#pragma unroll
    for (int off = 32; off >= 1; off >>= 1) {
        m0 = fmaxf(m0, __shfl_xor(m0, off, 64)); m1 = fmaxf(m1, __shfl_xor(m1, off, 64));
        m2 = fmaxf(m2, __shfl_xor(m2, off, 64)); m3 = fmaxf(m3, __shfl_xor(m3, off, 64));
    }
    float d0 = 0.f, d1 = 0.f, d2 = 0.f, d3 = 0.f;
    for (int n = s0 + lane; n < s1; n += 64) {
        d0 += expf(scores[n * 4 + 0] - m0); d1 += expf(scores[n * 4 + 1] - m1);
        d2 += expf(scores[n * 4 + 2] - m2); d3 += expf(scores[n * 4 + 3] - m3);
    }
#pragma unroll
    for (int off = 32; off >= 1; off >>= 1) {
        d0 += __shfl_xor(d0, off, 64); d1 += __shfl_xor(d1, off, 64);
        d2 += __shfl_xor(d2, off, 64); d3 += __shfl_xor(d3, off, 64);
    }
    float i0 = d0 > 0.f ? 1.f / d0 : 0.f;
    float i1 = d1 > 0.f ? 1.f / d1 : 0.f;
    float i2 = d2 > 0.f ? 1.f / d2 : 0.f;
    float i3 = d3 > 0.f ? 1.f / d3 : 0.f;
    float a0 = 0.f, a1 = 0.f;
    for (int n = s0; n < s1; ++n) {
        float wb = expf(scores[n * 4 + 0] - m0) * i0 + expf(scores[n * 4 + 1] - m1) * i1
                 + expf(scores[n * 4 + 2] - m2) * i2 + expf(scores[n * 4 + 3] - m3) * i3;
        wb *= 0.25f;
        a0 += wb * (float)x[(long)n * H + lane];
        a1 += wb * (float)x[(long)n * H + 64 + lane];
    }
    pooled[g * H + lane] = a0;
    pooled[g * H + 64 + lane] = a1;
}

// ---------------------------------------------------------------- K7: FFN readout
__global__ __launch_bounds__(128) void k_ffn(
    const float* __restrict__ pooled,
    const float* __restrict__ W1, const float* __restrict__ B1,
    const float* __restrict__ W2, const float* __restrict__ B2,
    const float* __restrict__ W3, const float* __restrict__ B3,
    float* __restrict__ out)
{
    __shared__ float p[H], t1[H], t2[H], red[H];
    int g = blockIdx.x, c = threadIdx.x;
    p[c] = pooled[g * H + c];
    __syncthreads();
    float acc = 0.f;
    for (int k = 0; k < H; ++k) acc += p[k] * W1[k * H + c];
    t1[c] = silu_f(acc + B1[c]);
    __syncthreads();
    acc = 0.f;
    for (int k = 0; k < H; ++k) acc += t1[k] * W2[k * H + c];
    t2[c] = silu_f(acc + B2[c]);
    __syncthreads();
    red[c] = t2[c] * W3[c];
    __syncthreads();
    for (int off = 64; off >= 1; off >>= 1) {
        if (c < off) red[c] += red[c + off];
        __syncthreads();
    }
    if (c == 0) out[g] = red[0] + B3[0];
}

// ---------------------------------------------------------------- launch
extern "C" void kernel_launch(void* const* d_in, const int* in_sizes, int n_in,
                              void* d_out, int out_size, void* d_ws, size_t ws_size,
                              hipStream_t stream)
{
    const int*   atom   = (const int*)d_in[0];
    const int*   hc     = (const int*)d_in[1];
    const int*   deg    = (const int*)d_in[2];
    const int*   hyb    = (const int*)d_in[3];
    const int*   target = (const int*)d_in[4];
    const int*   src    = (const int*)d_in[5];
    const int*   batch  = (const int*)d_in[6];
    const float* Ea     = (const float*)d_in[7];
    const float* Eh     = (const float*)d_in[8];
    const float* Ed     = (const float*)d_in[9];
    const float* Ey     = (const float*)d_in[10];
    const float* projW  = (const float*)d_in[11];
    const float* projB  = (const float*)d_in[12];
    const float* sInW   = (const float*)d_in[13];
    const float* sInB   = (const float*)d_in[14];
    const float* mW1    = (const float*)d_in[15];
    const float* mB1    = (const float*)d_in[16];
    const float* mW2    = (const float*)d_in[17];
    const float* mB2    = (const float*)d_in[18];
    const float* sSkW   = (const float*)d_in[19];
    const float* sSkB   = (const float*)d_in[20];
    const float* attnW  = (const float*)d_in[21];
    const float* attnB  = (const float*)d_in[22];
    const float* temp   = (const float*)d_in[23];
    const float* fW1    = (const float*)d_in[24];
    const float* fB1    = (const float*)d_in[25];
    const float* fW2    = (const float*)d_in[26];
    const float* fB2    = (const float*)d_in[27];
    const float* fW3    = (const float*)d_in[28];
    const float* fB3    = (const float*)d_in[29];
    float* out = (float*)d_out;

    char* w = (char*)d_ws;
    auto take = [&](size_t bytes) { void* p = (void*)w; w += (bytes + 255) & ~(size_t)255; return p; };
    __bf16* x      = (__bf16*)take(2L * NNP * H);
    __bf16* agg    = (__bf16*)take(2L * 3 * NNP * H);
    __bf16* pproj  = (__bf16*)take(2L * 256 * H);
    __bf16* pin    = (__bf16*)take(2L * 3 * 512 * H);
    __bf16* psk    = (__bf16*)take(2L * 3 * 512 * H);
    __bf16* pw1    = (__bf16*)take(2L * 6 * 128 * H);
    __bf16* pw2    = (__bf16*)take(2L * 6 * 128 * H);
    __bf16* embb   = (__bf16*)take(2L * 8000);
    float*  scores = (float*)take(4L * NN * NHEADS);
    float*  pooled = (float*)take(4L * NG * H);
    int*    gstart = (int*)take(4L * (NG + 1));
    int*    csr_start = (int*)take(4L * (NROWS + 1));
    unsigned int*   binreg = (unsigned int*)take(4L * NBIN * CAPB);   // 14.4 MB
    unsigned short* esrc   = (unsigned short*)take(2L * NE);
    // gbincur + brealc in ONE contiguous allocation (one memset covers both)
    int*    gbincur = (int*)take(4L * 2 * NBIN);
    int*    brealc  = gbincur + NBIN;

    // ---- fused weight pack + emb convert (weights restored each call) ----
    k_packall<<<(630592 + 255) / 256, 256, 0, stream>>>(
        projW, pproj, sInW, pin, sSkW, psk, mW1, pw1, mW2, pw2,
        Ea, Eh, Ed, Ey, embb);

    // ---- CSR build: write-combined binning -> per-half-bin finalize ----
    hipMemsetAsync(gbincur, 0, sizeof(int) * 2 * NBIN, stream);
    k_binA<<<ABLK, 256, 0, stream>>>(target, src, gbincur, brealc, binreg);
    k_fill2b<<<2 * NBIN, 512, 0, stream>>>(binreg, gbincur, brealc, csr_start, esrc);

    k_embed_m<<<NNP / 128, 256, 0, stream>>>(atom, hc, deg, hyb, embb, pproj, projB, x);
    k_offsets<<<(NN + 255) / 256, 256, 0, stream>>>(batch, gstart);

    for (int l = 0; l < NL; ++l) {
        k_gather<<<NROWS / 16, 256, 0, stream>>>(esrc, csr_start,
            (const uint4*)x, (uint4*)agg);
        k_layer<<<NNP / 16, 128, 0, stream>>>(x, agg,
            pin + (long)l * 512 * H, sInB + l * H,
            psk + (long)l * 512 * H, sSkB + l * H,
            pw1 + (long)(l * NMLP + 0) * 128 * H, mB1 + (long)(l * NMLP + 0) * H,
            pw2 + (long)(l * NMLP + 0) * 128 * H, mB2 + (long)(l * NMLP + 0) * H,
            pw1 + (long)(l * NMLP + 1) * 128 * H, mB1 + (long)(l * NMLP + 1) * H,
            pw2 + (long)(l * NMLP + 1) * 128 * H, mB2 + (long)(l * NMLP + 1) * H,
            x);
    }

    k_scores<<<NN / 4, 256, 0, stream>>>(x, attnW, attnB, temp, scores);
    k_pool<<<NG, 64, 0, stream>>>(x, scores, gstart, pooled);
    k_ffn<<<NG, 128, 0, stream>>>(pooled, fW1, fB1, fW2, fB2, fW3, fB3, out);
}